// Round 1
// baseline (6283.652 us; speedup 1.0000x reference)
//
#include <hip/hip_runtime.h>
#include <math.h>

#define CCH 128
#define G3  384
#define BN_EPS 1e-5f

// ---------------- small prep kernels ----------------

__global__ void bnprep_kernel(const float* __restrict__ g, const float* __restrict__ b,
                              const float* __restrict__ m, const float* __restrict__ v,
                              float* __restrict__ sc, float* __restrict__ sh)
{
    int idx = blockIdx.x * 128 + threadIdx.x;   // 8*128 total
    float s = g[idx] / sqrtf(v[idx] + BN_EPS);
    sc[idx] = s;
    sh[idx] = b[idx] - m[idx] * s;
}

// v_s = Wsrc^T a_src (folded with bn2 scale, plus c0 = sum(shift*v)), v_d = Wdst^T a_dst
__global__ __launch_bounds__(128) void matvec_prep_kernel(
    const float* __restrict__ Wsrc, const float* __restrict__ Wdst,
    const float* __restrict__ asrc, const float* __restrict__ adst,
    const float* __restrict__ bnsc, const float* __restrict__ bnsh,
    float* __restrict__ vsp, float* __restrict__ vd, float* __restrict__ c0)
{
    __shared__ float red[2];
    int s = blockIdx.x >> 1, which = blockIdx.x & 1;
    int k = threadIdx.x;
    const float* W = (which ? Wdst : Wsrc) + s * CCH * CCH;
    const float* a = (which ? adst : asrc) + s * CCH;
    float acc = 0.f;
    for (int j = 0; j < CCH; ++j) acc += W[j * CCH + k] * a[j];
    if (which) {
        vd[s * CCH + k] = acc;
    } else {
        int l = 2 + 3 * s;   // bn index of the stage's input bn
        vsp[s * CCH + k] = acc * bnsc[l * CCH + k];
        float p = bnsh[l * CCH + k] * acc;
        for (int o = 32; o; o >>= 1) p += __shfl_down(p, o);
        if ((k & 63) == 0) red[k >> 6] = p;
        __syncthreads();
        if (k == 0) c0[s] = red[0] + red[1];
    }
}

// starts[s] = lower_bound(batch, s); batch sorted. s in [0, nseg]
__global__ void bounds_kernel(const int* __restrict__ batch, int n, int nseg, int* __restrict__ starts)
{
    int s = blockIdx.x * 256 + threadIdx.x;
    if (s > nseg) return;
    int lo = 0, hi = n;
    while (lo < hi) {
        int mid = (lo + hi) >> 1;
        if (batch[mid] < s) lo = mid + 1; else hi = mid;
    }
    starts[s] = lo;
}

// ---------------- GEMM: Y[M x Nout] = X[M x 128] @ W[Nout x 128]^T (+bias)(+elu) ----------------
// grid: (ceil(M/32), Nout/64), block 256.

__global__ __launch_bounds__(256, 3) void gemm128(
    const float* __restrict__ X, const float* __restrict__ W,
    const float* __restrict__ bias, float* __restrict__ Y,
    int M, int Nout, int act)
{
    __shared__ float Ws[64 * 132];
    __shared__ float Xs[32 * 132];
    const int tid = threadIdx.x;
    const int rb = blockIdx.x * 32;
    const int cb = blockIdx.y * 64;

#pragma unroll
    for (int it = 0; it < 8; ++it) {          // stage 64x128 W tile
        int idx = tid + it * 256;
        int jl = idx >> 5, k4 = (idx & 31) << 2;
        float4 wv = *(const float4*)&W[(size_t)(cb + jl) * CCH + k4];
        *(float4*)&Ws[jl * 132 + k4] = wv;
    }
#pragma unroll
    for (int it = 0; it < 4; ++it) {          // stage 32x128 X tile
        int idx = tid + it * 256;
        int r = idx >> 5, k4 = (idx & 31) << 2;
        int grow = rb + r;
        float4 xv = make_float4(0.f, 0.f, 0.f, 0.f);
        if (grow < M) xv = *(const float4*)&X[(size_t)grow * CCH + k4];
        *(float4*)&Xs[r * 132 + k4] = xv;
    }
    __syncthreads();

    const int colg = tid & 31;     // 32 col groups, cols colg and colg+32
    const int rowg = tid >> 5;     // 8 row groups, 4 rows each
    float acc[4][2] = {{0.f,0.f},{0.f,0.f},{0.f,0.f},{0.f,0.f}};
    const float* xsb = &Xs[(rowg * 4) * 132];
    const float* ws0 = &Ws[colg * 132];
    const float* ws1 = &Ws[(colg + 32) * 132];
#pragma unroll 8
    for (int k = 0; k < CCH; k += 4) {
        float4 w0 = *(const float4*)&ws0[k];
        float4 w1 = *(const float4*)&ws1[k];
#pragma unroll
        for (int ri = 0; ri < 4; ++ri) {
            float4 x = *(const float4*)&xsb[ri * 132 + k];
            acc[ri][0] += x.x*w0.x + x.y*w0.y + x.z*w0.z + x.w*w0.w;
            acc[ri][1] += x.x*w1.x + x.y*w1.y + x.z*w1.z + x.w*w1.w;
        }
    }

#pragma unroll
    for (int ri = 0; ri < 4; ++ri) {
        int row = rb + rowg * 4 + ri;
        if (row >= M) continue;
#pragma unroll
        for (int ci = 0; ci < 2; ++ci) {
            int j = cb + colg + 32 * ci;
            float v = acc[ri][ci];
            if (bias) v += bias[j];
            if (act == 1) v = (v > 0.f) ? v : expm1f(v);   // elu
            Y[(size_t)row * Nout + j] = v;
        }
    }
}

// ---------------- SpMM: Y[r] += val * X[c], atomic scatter. 32 lanes (float4) per edge ----------------
__global__ __launch_bounds__(256) void spmm_kernel(
    const int* __restrict__ rows, const int* __restrict__ cols, const float* __restrict__ val,
    const float* __restrict__ Xin, float* __restrict__ Y, int E)
{
    int gid = blockIdx.x * 256 + threadIdx.x;
    int e = gid >> 5;
    if (e >= E) return;
    int lane = (gid & 31) << 2;
    int r = rows[e], c = cols[e];
    float v = val[e];
    const float4 xv = *(const float4*)&Xin[(size_t)c * CCH + lane];
    float* yp = &Y[(size_t)r * CCH + lane];
    unsafeAtomicAdd(yp + 0, v * xv.x);
    unsafeAtomicAdd(yp + 1, v * xv.y);
    unsafeAtomicAdd(yp + 2, v * xv.z);
    unsafeAtomicAdd(yp + 3, v * xv.w);
}

// x = relu(bn((spmm_out + b)))  in-place, float4
__global__ __launch_bounds__(256) void gcn_eltwise_kernel(
    float* __restrict__ Xio, const float* __restrict__ bvec,
    const float* __restrict__ sc, const float* __restrict__ sh, int n)
{
    int idx = blockIdx.x * 256 + threadIdx.x;     // float4 index
    if (idx >= n * 32) return;
    int c4 = idx & 31;
    float4 t = ((const float4*)Xio)[idx];
    float4 bb = ((const float4*)bvec)[c4];
    float4 s4 = ((const float4*)sc)[c4];
    float4 h4 = ((const float4*)sh)[c4];
    t.x = fmaxf((t.x + bb.x) * s4.x + h4.x, 0.f);
    t.y = fmaxf((t.y + bb.y) * s4.y + h4.y, 0.f);
    t.z = fmaxf((t.z + bb.z) * s4.z + h4.z, 0.f);
    t.w = fmaxf((t.w + bb.w) * s4.w + h4.w, 0.f);
    ((float4*)Xio)[idx] = t;
}

// ---------------- pooling stage kernels ----------------

// per segment: raw add-pool -> bn2-fold -> relu -> bn3 -> mean; also ad[t] = mean . v_d
__global__ __launch_bounds__(128) void pool_kernel(
    const float* __restrict__ X, const int* __restrict__ starts,
    const float* __restrict__ sc2, const float* __restrict__ sh2,
    const float* __restrict__ sc3, const float* __restrict__ sh3,
    const float* __restrict__ vd, float* __restrict__ mean, float* __restrict__ ad)
{
    __shared__ float red[2];
    int t = blockIdx.x;
    int c = threadIdx.x;
    int st = starts[t], en = starts[t + 1];
    float sum = 0.f;
    for (int i = st; i < en; ++i) sum += X[(size_t)i * CCH + c];
    float cnt = (float)(en - st);
    float poolb = fmaxf(sum * sc2[c] + cnt * sh2[c], 0.f);
    float mv = poolb * sc3[c] + sh3[c];
    mean[(size_t)t * CCH + c] = mv;
    float p = mv * vd[c];
    for (int o = 32; o; o >>= 1) p += __shfl_down(p, o);
    if ((c & 63) == 0) red[c >> 6] = p;
    __syncthreads();
    if (c == 0) ad[t] = red[0] + red[1];
}

// per-row score: s_i = x_i . vsp + c0   (wave per row)
__global__ __launch_bounds__(256) void scores_kernel(
    const float* __restrict__ X, const float* __restrict__ vsp, const float* __restrict__ c0p,
    float* __restrict__ s, int n)
{
    int gid = blockIdx.x * 256 + threadIdx.x;
    int row = gid >> 6;
    if (row >= n) return;
    int lane = (gid & 63) << 1;
    float2 xv = *(const float2*)&X[(size_t)row * CCH + lane];
    float2 vv = *(const float2*)&vsp[lane];
    float p = xv.x * vv.x + xv.y * vv.y;
    for (int o = 32; o; o >>= 1) p += __shfl_down(p, o);
    if ((gid & 63) == 0) s[row] = p + c0p[0];
}

// per segment: softmax over leaky(s_i + ad_t), weighted pool of raw x, bn2-fold
__global__ __launch_bounds__(128) void attnpool_kernel(
    const float* __restrict__ X, const float* __restrict__ sarr, const float* __restrict__ ad,
    const int* __restrict__ starts, const float* __restrict__ sc2, const float* __restrict__ sh2,
    float* __restrict__ upool)
{
    __shared__ float red[2];
    int t = blockIdx.x;
    int c = threadIdx.x;
    int st = starts[t], en = starts[t + 1];
    if (en == st) { upool[(size_t)t * CCH + c] = 0.f; return; }
    float adt = ad[t];
    float lm = -3.0e38f;
    for (int i = st + c; i < en; i += 128) {
        float a = sarr[i] + adt;
        a = a > 0.f ? a : 0.01f * a;
        lm = fmaxf(lm, a);
    }
    for (int o = 32; o; o >>= 1) lm = fmaxf(lm, __shfl_down(lm, o));
    if ((c & 63) == 0) red[c >> 6] = lm;
    __syncthreads();
    float m = fmaxf(red[0], red[1]);
    float u = 0.f, den = 0.f;
    for (int i = st; i < en; ++i) {
        float a = sarr[i] + adt;
        a = a > 0.f ? a : 0.01f * a;
        float e = __expf(a - m);
        den += e;
        u += e * X[(size_t)i * CCH + c];
    }
    upool[(size_t)t * CCH + c] = (u / den) * sc2[c] + sh2[c];
}

// GRU combine + relu + bn(base+2)
__global__ __launch_bounds__(256) void gru_kernel(
    const float* __restrict__ giM, const float* __restrict__ ghM, const float* __restrict__ mean,
    const float* __restrict__ sc4, const float* __restrict__ sh4,
    float* __restrict__ out, int total)   // total = nseg*CCH
{
    int idx = blockIdx.x * 256 + threadIdx.x;
    if (idx >= total) return;
    int t = idx >> 7, c = idx & 127;
    size_t b = (size_t)t * G3;
    float ir = giM[b + c],  iz = giM[b + 128 + c], inn = giM[b + 256 + c];
    float hr = ghM[b + c],  hz = ghM[b + 128 + c], hn  = ghM[b + 256 + c];
    float r = 1.f / (1.f + __expf(-(ir + hr)));
    float z = 1.f / (1.f + __expf(-(iz + hz)));
    float nn = tanhf(inn + r * hn);
    float h = (1.f - z) * nn + z * mean[idx];
    h = fmaxf(h, 0.f);
    out[idx] = h * sc4[c] + sh4[c];
}

// predictor: relu(mol @ pW1^T + pb1) @ pW2^T + pb2, one block (64 thr) per molecule
__global__ __launch_bounds__(64) void pred_kernel(
    const float* __restrict__ mol, const float* __restrict__ pW1, const float* __restrict__ pb1,
    const float* __restrict__ pW2, const float* __restrict__ pb2, float* __restrict__ out)
{
    __shared__ float row[CCH];
    int m = blockIdx.x;
    int j = threadIdx.x;
    row[j] = mol[(size_t)m * CCH + j];
    row[j + 64] = mol[(size_t)m * CCH + 64 + j];
    __syncthreads();
    float h = pb1[j];
#pragma unroll
    for (int k = 0; k < CCH; ++k) h += row[k] * pW1[j * CCH + k];
    h = fmaxf(h, 0.f);
    float p = h * pW2[j];
    for (int o = 32; o; o >>= 1) p += __shfl_down(p, o);
    if (j == 0) out[m] = p + pb2[0];
}

// ---------------- host ----------------

static void run_stage(const float* Xf, int n, const int* starts, int nseg,
                      int bnb, int gi, float* outbuf,
                      float* mean, float* upool, float* gbuf, float* giM, float* ghM,
                      float* scores, float* ad,
                      const float* bnsc, const float* bnsh,
                      const float* vsp, const float* vd, const float* c0,
                      const float* gat_Wsrc, const float* gat_bias,
                      const float* gru_Wih, const float* gru_Whh,
                      const float* gru_bih, const float* gru_bhh,
                      hipStream_t stream)
{
    pool_kernel<<<nseg, 128, 0, stream>>>(Xf, starts,
        bnsc + bnb * CCH, bnsh + bnb * CCH, bnsc + (bnb + 1) * CCH, bnsh + (bnb + 1) * CCH,
        vd + gi * CCH, mean, ad);
    scores_kernel<<<(n * 64 + 255) / 256, 256, 0, stream>>>(Xf, vsp + gi * CCH, c0 + gi, scores, n);
    attnpool_kernel<<<nseg, 128, 0, stream>>>(Xf, scores, ad, starts,
        bnsc + bnb * CCH, bnsh + bnb * CCH, upool);
    dim3 g1((nseg + 31) / 32, CCH / 64);
    gemm128<<<g1, 256, 0, stream>>>(upool, gat_Wsrc + gi * CCH * CCH, gat_bias + gi * CCH,
                                    gbuf, nseg, CCH, 1 /*elu*/);
    dim3 g2((nseg + 31) / 32, G3 / 64);
    gemm128<<<g2, 256, 0, stream>>>(gbuf, gru_Wih + gi * G3 * CCH, gru_bih + gi * G3, giM, nseg, G3, 0);
    gemm128<<<g2, 256, 0, stream>>>(mean, gru_Whh + gi * G3 * CCH, gru_bhh + gi * G3, ghM, nseg, G3, 0);
    gru_kernel<<<(nseg * CCH + 255) / 256, 256, 0, stream>>>(giM, ghM, mean,
        bnsc + (bnb + 2) * CCH, bnsh + (bnb + 2) * CCH, outbuf, nseg * CCH);
}

extern "C" void kernel_launch(void* const* d_in, const int* in_sizes, int n_in,
                              void* d_out, int out_size, void* d_ws, size_t ws_size,
                              hipStream_t stream)
{
    (void)n_in; (void)ws_size;
    const float* node_attr      = (const float*)d_in[0];
    const int*   adj_index      = (const int*)  d_in[1];
    const float* adj_value      = (const float*)d_in[2];
    const int*   tt_node_batch  = (const int*)  d_in[3];
    const int*   tt_graph_batch = (const int*)  d_in[4];
    const float* W_gcn    = (const float*)d_in[5];
    const float* b_gcn    = (const float*)d_in[6];
    const float* bn_gamma = (const float*)d_in[7];
    const float* bn_beta  = (const float*)d_in[8];
    const float* bn_mean  = (const float*)d_in[9];
    const float* bn_var   = (const float*)d_in[10];
    const float* gat_Wsrc = (const float*)d_in[11];
    const float* gat_Wdst = (const float*)d_in[12];
    const float* gat_asrc = (const float*)d_in[13];
    const float* gat_adst = (const float*)d_in[14];
    const float* gat_bias = (const float*)d_in[15];
    const float* gru_Wih  = (const float*)d_in[16];
    const float* gru_Whh  = (const float*)d_in[17];
    const float* gru_bih  = (const float*)d_in[18];
    const float* gru_bhh  = (const float*)d_in[19];
    const float* pW1 = (const float*)d_in[20];
    const float* pb1 = (const float*)d_in[21];
    const float* pW2 = (const float*)d_in[22];
    const float* pb2 = (const float*)d_in[23];

    const int E    = in_sizes[2];
    const int N    = in_sizes[3];
    const int NTT  = in_sizes[4];
    const int NMOL = out_size;

    const int* adj_rows = adj_index;
    const int* adj_cols = adj_index + E;

    // ---- workspace carve ----
    char* wsb = (char*)d_ws;
    size_t off = 0;
    auto carve = [&](size_t bytes) -> char* {
        char* p = wsb + off;
        off = (off + bytes + 255) & ~(size_t)255;
        return p;
    };
    float* A    = (float*)carve((size_t)N * CCH * 4);
    float* B    = (float*)carve((size_t)N * CCH * 4);
    float* tt   = (float*)carve((size_t)NTT * CCH * 4);
    float* mol  = (float*)carve((size_t)NMOL * CCH * 4);
    float* ad   = (float*)carve((size_t)NTT * 4);
    int* starts_tt  = (int*)carve((size_t)(NTT + 1) * 4);
    int* starts_mol = (int*)carve((size_t)(NMOL + 1) * 4);
    float* bnsc = (float*)carve(8 * CCH * 4);
    float* bnsh = (float*)carve(8 * CCH * 4);
    float* vsp  = (float*)carve(2 * CCH * 4);
    float* vd   = (float*)carve(2 * CCH * 4);
    float* c0   = (float*)carve(2 * 4);

    // stage temporaries overlay inside B (free after GCN):
    // 3*NTT*C + 2*NTT*384 + N = 23.24M floats <= 25.6M floats
    float* mean   = B;
    float* upool  = B + (size_t)NTT * CCH;
    float* gbuf   = B + (size_t)2 * NTT * CCH;
    float* giM    = B + (size_t)3 * NTT * CCH;
    float* ghM    = giM + (size_t)NTT * G3;
    float* scores = ghM + (size_t)NTT * G3;

    // ---- prep ----
    bnprep_kernel<<<8, 128, 0, stream>>>(bn_gamma, bn_beta, bn_mean, bn_var, bnsc, bnsh);
    matvec_prep_kernel<<<4, 128, 0, stream>>>(gat_Wsrc, gat_Wdst, gat_asrc, gat_adst,
                                              bnsc, bnsh, vsp, vd, c0);
    bounds_kernel<<<(NTT + 1 + 255) / 256, 256, 0, stream>>>(tt_node_batch, N, NTT, starts_tt);
    bounds_kernel<<<(NMOL + 1 + 255) / 256, 256, 0, stream>>>(tt_graph_batch, NTT, NMOL, starts_mol);

    // ---- GCN x2: t1 = x @ W^T ; y = A_sp @ t1 ; x = relu(bn(y + b)) ----
    for (int l = 0; l < 2; ++l) {
        const float* xin = (l == 0) ? node_attr : A;
        dim3 gg((N + 31) / 32, CCH / 64);
        gemm128<<<gg, 256, 0, stream>>>(xin, W_gcn + l * CCH * CCH, nullptr, B, N, CCH, 0);
        hipMemsetAsync(A, 0, (size_t)N * CCH * 4, stream);
        spmm_kernel<<<(E * 32 + 255) / 256, 256, 0, stream>>>(adj_rows, adj_cols, adj_value, B, A, E);
        gcn_eltwise_kernel<<<(N * 32 + 255) / 256, 256, 0, stream>>>(A, b_gcn + l * CCH,
            bnsc + l * CCH, bnsh + l * CCH, N);
    }

    // ---- tt stage: N -> NTT ----
    run_stage(A, N, starts_tt, NTT, 2, 0, tt,
              mean, upool, gbuf, giM, ghM, scores, ad,
              bnsc, bnsh, vsp, vd, c0,
              gat_Wsrc, gat_bias, gru_Wih, gru_Whh, gru_bih, gru_bhh, stream);

    // ---- mol stage: NTT -> NMOL ----
    run_stage(tt, NTT, starts_mol, NMOL, 5, 1, mol,
              mean, upool, gbuf, giM, ghM, scores, ad,
              bnsc, bnsh, vsp, vd, c0,
              gat_Wsrc, gat_bias, gru_Wih, gru_Whh, gru_bih, gru_bhh, stream);

    // ---- predictor ----
    pred_kernel<<<NMOL, 64, 0, stream>>>(mol, pW1, pb1, pW2, pb2, (float*)d_out);
}

// Round 2
// 1252.531 us; speedup vs baseline: 5.0168x; 5.0168x over previous
//
#include <hip/hip_runtime.h>
#include <math.h>

#define CCH 128
#define G3  384
#define BN_EPS 1e-5f

// ---------------- small prep kernels ----------------

__global__ void bnprep_kernel(const float* __restrict__ g, const float* __restrict__ b,
                              const float* __restrict__ m, const float* __restrict__ v,
                              float* __restrict__ sc, float* __restrict__ sh)
{
    int idx = blockIdx.x * 128 + threadIdx.x;   // 8*128 total
    float s = g[idx] / sqrtf(v[idx] + BN_EPS);
    sc[idx] = s;
    sh[idx] = b[idx] - m[idx] * s;
}

// v_s = Wsrc^T a_src (folded with bn2 scale, plus c0 = sum(shift*v)), v_d = Wdst^T a_dst
__global__ __launch_bounds__(128) void matvec_prep_kernel(
    const float* __restrict__ Wsrc, const float* __restrict__ Wdst,
    const float* __restrict__ asrc, const float* __restrict__ adst,
    const float* __restrict__ bnsc, const float* __restrict__ bnsh,
    float* __restrict__ vsp, float* __restrict__ vd, float* __restrict__ c0)
{
    __shared__ float red[2];
    int s = blockIdx.x >> 1, which = blockIdx.x & 1;
    int k = threadIdx.x;
    const float* W = (which ? Wdst : Wsrc) + s * CCH * CCH;
    const float* a = (which ? adst : asrc) + s * CCH;
    float acc = 0.f;
    for (int j = 0; j < CCH; ++j) acc += W[j * CCH + k] * a[j];
    if (which) {
        vd[s * CCH + k] = acc;
    } else {
        int l = 2 + 3 * s;   // bn index of the stage's input bn
        vsp[s * CCH + k] = acc * bnsc[l * CCH + k];
        float p = bnsh[l * CCH + k] * acc;
        for (int o = 32; o; o >>= 1) p += __shfl_down(p, o);
        if ((k & 63) == 0) red[k >> 6] = p;
        __syncthreads();
        if (k == 0) c0[s] = red[0] + red[1];
    }
}

// starts[s] = lower_bound(batch, s); batch sorted. s in [0, nseg]
__global__ void bounds_kernel(const int* __restrict__ batch, int n, int nseg, int* __restrict__ starts)
{
    int s = blockIdx.x * 256 + threadIdx.x;
    if (s > nseg) return;
    int lo = 0, hi = n;
    while (lo < hi) {
        int mid = (lo + hi) >> 1;
        if (batch[mid] < s) lo = mid + 1; else hi = mid;
    }
    starts[s] = lo;
}

// ---------------- CSR build: histogram -> scan -> scatter ----------------

__global__ __launch_bounds__(256) void hist_kernel(const int* __restrict__ rows,
                                                   int* __restrict__ counts, int E)
{
    int e = blockIdx.x * 256 + threadIdx.x;
    if (e < E) atomicAdd(&counts[rows[e]], 1);
}

// block b reduces counts[b*1024 .. b*1024+1024) -> bsum[b]
__global__ __launch_bounds__(256) void scan_reduce_kernel(const int* __restrict__ counts,
                                                          int* __restrict__ bsum, int n)
{
    __shared__ int lds[4];
    int t = threadIdx.x;
    int base = blockIdx.x * 1024 + t * 4;
    int s = 0;
#pragma unroll
    for (int i = 0; i < 4; ++i) {
        int idx = base + i;
        if (idx < n) s += counts[idx];
    }
    for (int o = 32; o; o >>= 1) s += __shfl_down(s, o);
    if ((t & 63) == 0) lds[t >> 6] = s;
    __syncthreads();
    if (t == 0) bsum[blockIdx.x] = lds[0] + lds[1] + lds[2] + lds[3];
}

// single block: exclusive scan of bsum[nb] (nb <= 256); also writes row_ptr[n]=E
__global__ __launch_bounds__(256) void scan_top_kernel(int* __restrict__ bsum, int nb,
                                                       int* __restrict__ row_ptr, int n, int E)
{
    __shared__ int tmp[256];
    int t = threadIdx.x;
    int v = (t < nb) ? bsum[t] : 0;
    tmp[t] = v;
    __syncthreads();
    for (int o = 1; o < 256; o <<= 1) {
        int u = (t >= o) ? tmp[t - o] : 0;
        __syncthreads();
        tmp[t] += u;
        __syncthreads();
    }
    if (t < nb) bsum[t] = tmp[t] - v;   // exclusive
    if (t == 0) row_ptr[n] = E;
}

// block b: exclusive scan of its 1024 counts, + bsum[b]; writes row_ptr[i] and cursor[i]
__global__ __launch_bounds__(256) void scan_down_kernel(const int* __restrict__ counts,
                                                        const int* __restrict__ bsum,
                                                        int* __restrict__ row_ptr,
                                                        int* __restrict__ cursor, int n)
{
    __shared__ int tmp[256];
    int t = threadIdx.x;
    int base = blockIdx.x * 1024 + t * 4;
    int v0 = 0, v1 = 0, v2 = 0, v3 = 0;
    if (base + 0 < n) v0 = counts[base + 0];
    if (base + 1 < n) v1 = counts[base + 1];
    if (base + 2 < n) v2 = counts[base + 2];
    if (base + 3 < n) v3 = counts[base + 3];
    int ts = v0 + v1 + v2 + v3;
    tmp[t] = ts;
    __syncthreads();
    for (int o = 1; o < 256; o <<= 1) {
        int u = (t >= o) ? tmp[t - o] : 0;
        __syncthreads();
        tmp[t] += u;
        __syncthreads();
    }
    int off = bsum[blockIdx.x] + tmp[t] - ts;   // exclusive across block + chip
    int p0 = off, p1 = off + v0, p2 = p1 + v1, p3 = p2 + v2;
    if (base + 0 < n) { row_ptr[base + 0] = p0; cursor[base + 0] = p0; }
    if (base + 1 < n) { row_ptr[base + 1] = p1; cursor[base + 1] = p1; }
    if (base + 2 < n) { row_ptr[base + 2] = p2; cursor[base + 2] = p2; }
    if (base + 3 < n) { row_ptr[base + 3] = p3; cursor[base + 3] = p3; }
}

__global__ __launch_bounds__(256) void scatter_kernel(const int* __restrict__ rows,
                                                      const int* __restrict__ cols,
                                                      const float* __restrict__ val,
                                                      int* __restrict__ cursor,
                                                      int* __restrict__ ccol,
                                                      float* __restrict__ cval, int E)
{
    int e = blockIdx.x * 256 + threadIdx.x;
    if (e >= E) return;
    int r = rows[e];
    int p = atomicAdd(&cursor[r], 1);
    ccol[p] = cols[e];
    cval[p] = val[e];
}

// ---------------- GEMM: Y[M x Nout] = X[M x 128] @ W[Nout x 128]^T (+bias)(+elu) ----------------
// grid: (ceil(M/32), Nout/64), block 256.

__global__ __launch_bounds__(256, 3) void gemm128(
    const float* __restrict__ X, const float* __restrict__ W,
    const float* __restrict__ bias, float* __restrict__ Y,
    int M, int Nout, int act)
{
    __shared__ float Ws[64 * 132];
    __shared__ float Xs[32 * 132];
    const int tid = threadIdx.x;
    const int rb = blockIdx.x * 32;
    const int cb = blockIdx.y * 64;

#pragma unroll
    for (int it = 0; it < 8; ++it) {          // stage 64x128 W tile
        int idx = tid + it * 256;
        int jl = idx >> 5, k4 = (idx & 31) << 2;
        float4 wv = *(const float4*)&W[(size_t)(cb + jl) * CCH + k4];
        *(float4*)&Ws[jl * 132 + k4] = wv;
    }
#pragma unroll
    for (int it = 0; it < 4; ++it) {          // stage 32x128 X tile
        int idx = tid + it * 256;
        int r = idx >> 5, k4 = (idx & 31) << 2;
        int grow = rb + r;
        float4 xv = make_float4(0.f, 0.f, 0.f, 0.f);
        if (grow < M) xv = *(const float4*)&X[(size_t)grow * CCH + k4];
        *(float4*)&Xs[r * 132 + k4] = xv;
    }
    __syncthreads();

    const int colg = tid & 31;     // 32 col groups, cols colg and colg+32
    const int rowg = tid >> 5;     // 8 row groups, 4 rows each
    float acc[4][2] = {{0.f,0.f},{0.f,0.f},{0.f,0.f},{0.f,0.f}};
    const float* xsb = &Xs[(rowg * 4) * 132];
    const float* ws0 = &Ws[colg * 132];
    const float* ws1 = &Ws[(colg + 32) * 132];
#pragma unroll 8
    for (int k = 0; k < CCH; k += 4) {
        float4 w0 = *(const float4*)&ws0[k];
        float4 w1 = *(const float4*)&ws1[k];
#pragma unroll
        for (int ri = 0; ri < 4; ++ri) {
            float4 x = *(const float4*)&xsb[ri * 132 + k];
            acc[ri][0] += x.x*w0.x + x.y*w0.y + x.z*w0.z + x.w*w0.w;
            acc[ri][1] += x.x*w1.x + x.y*w1.y + x.z*w1.z + x.w*w1.w;
        }
    }

#pragma unroll
    for (int ri = 0; ri < 4; ++ri) {
        int row = rb + rowg * 4 + ri;
        if (row >= M) continue;
#pragma unroll
        for (int ci = 0; ci < 2; ++ci) {
            int j = cb + colg + 32 * ci;
            float v = acc[ri][ci];
            if (bias) v += bias[j];
            if (act == 1) v = (v > 0.f) ? v : expm1f(v);   // elu
            Y[(size_t)row * Nout + j] = v;
        }
    }
}

// ---------------- SpMM (CSR gather): 32 lanes per row, fused bias+bn+relu ----------------
__global__ __launch_bounds__(256) void spmm_csr_kernel(
    const int* __restrict__ row_ptr, const int* __restrict__ ccol, const float* __restrict__ cval,
    const float* __restrict__ Xin, float* __restrict__ Y,
    const float* __restrict__ bvec, const float* __restrict__ sc, const float* __restrict__ sh,
    int Nrow)
{
    int gid = blockIdx.x * 256 + threadIdx.x;
    int row = gid >> 5;
    if (row >= Nrow) return;
    int l4 = (gid & 31) << 2;
    int st = row_ptr[row], en = row_ptr[row + 1];
    float4 acc = make_float4(0.f, 0.f, 0.f, 0.f);
    for (int j = st; j < en; ++j) {
        int c = ccol[j];
        float v = cval[j];
        float4 x = *(const float4*)&Xin[(size_t)c * CCH + l4];
        acc.x += v * x.x; acc.y += v * x.y; acc.z += v * x.z; acc.w += v * x.w;
    }
    float4 bb = *(const float4*)&bvec[l4];
    float4 s4 = *(const float4*)&sc[l4];
    float4 h4 = *(const float4*)&sh[l4];
    float4 o;
    o.x = fmaxf((acc.x + bb.x) * s4.x + h4.x, 0.f);
    o.y = fmaxf((acc.y + bb.y) * s4.y + h4.y, 0.f);
    o.z = fmaxf((acc.z + bb.z) * s4.z + h4.z, 0.f);
    o.w = fmaxf((acc.w + bb.w) * s4.w + h4.w, 0.f);
    *(float4*)&Y[(size_t)row * CCH + l4] = o;
}

// ---------------- pooling stage kernels ----------------

// per segment: raw add-pool -> bn2-fold -> relu -> bn3 -> mean; also ad[t] = mean . v_d
__global__ __launch_bounds__(128) void pool_kernel(
    const float* __restrict__ X, const int* __restrict__ starts,
    const float* __restrict__ sc2, const float* __restrict__ sh2,
    const float* __restrict__ sc3, const float* __restrict__ sh3,
    const float* __restrict__ vd, float* __restrict__ mean, float* __restrict__ ad)
{
    __shared__ float red[2];
    int t = blockIdx.x;
    int c = threadIdx.x;
    int st = starts[t], en = starts[t + 1];
    float sum = 0.f;
    for (int i = st; i < en; ++i) sum += X[(size_t)i * CCH + c];
    float cnt = (float)(en - st);
    float poolb = fmaxf(sum * sc2[c] + cnt * sh2[c], 0.f);
    float mv = poolb * sc3[c] + sh3[c];
    mean[(size_t)t * CCH + c] = mv;
    float p = mv * vd[c];
    for (int o = 32; o; o >>= 1) p += __shfl_down(p, o);
    if ((c & 63) == 0) red[c >> 6] = p;
    __syncthreads();
    if (c == 0) ad[t] = red[0] + red[1];
}

// per-row score: s_i = x_i . vsp + c0   (wave per row)
__global__ __launch_bounds__(256) void scores_kernel(
    const float* __restrict__ X, const float* __restrict__ vsp, const float* __restrict__ c0p,
    float* __restrict__ s, int n)
{
    int gid = blockIdx.x * 256 + threadIdx.x;
    int row = gid >> 6;
    if (row >= n) return;
    int lane = (gid & 63) << 1;
    float2 xv = *(const float2*)&X[(size_t)row * CCH + lane];
    float2 vv = *(const float2*)&vsp[lane];
    float p = xv.x * vv.x + xv.y * vv.y;
    for (int o = 32; o; o >>= 1) p += __shfl_down(p, o);
    if ((gid & 63) == 0) s[row] = p + c0p[0];
}

// per segment: softmax over leaky(s_i + ad_t), weighted pool of raw x, bn2-fold
__global__ __launch_bounds__(128) void attnpool_kernel(
    const float* __restrict__ X, const float* __restrict__ sarr, const float* __restrict__ ad,
    const int* __restrict__ starts, const float* __restrict__ sc2, const float* __restrict__ sh2,
    float* __restrict__ upool)
{
    __shared__ float red[2];
    int t = blockIdx.x;
    int c = threadIdx.x;
    int st = starts[t], en = starts[t + 1];
    if (en == st) { upool[(size_t)t * CCH + c] = 0.f; return; }
    float adt = ad[t];
    float lm = -3.0e38f;
    for (int i = st + c; i < en; i += 128) {
        float a = sarr[i] + adt;
        a = a > 0.f ? a : 0.01f * a;
        lm = fmaxf(lm, a);
    }
    for (int o = 32; o; o >>= 1) lm = fmaxf(lm, __shfl_down(lm, o));
    if ((c & 63) == 0) red[c >> 6] = lm;
    __syncthreads();
    float m = fmaxf(red[0], red[1]);
    float u = 0.f, den = 0.f;
    for (int i = st; i < en; ++i) {
        float a = sarr[i] + adt;
        a = a > 0.f ? a : 0.01f * a;
        float e = __expf(a - m);
        den += e;
        u += e * X[(size_t)i * CCH + c];
    }
    upool[(size_t)t * CCH + c] = (u / den) * sc2[c] + sh2[c];
}

// GRU combine + relu + bn(base+2)
__global__ __launch_bounds__(256) void gru_kernel(
    const float* __restrict__ giM, const float* __restrict__ ghM, const float* __restrict__ mean,
    const float* __restrict__ sc4, const float* __restrict__ sh4,
    float* __restrict__ out, int total)   // total = nseg*CCH
{
    int idx = blockIdx.x * 256 + threadIdx.x;
    if (idx >= total) return;
    int t = idx >> 7, c = idx & 127;
    size_t b = (size_t)t * G3;
    float ir = giM[b + c],  iz = giM[b + 128 + c], inn = giM[b + 256 + c];
    float hr = ghM[b + c],  hz = ghM[b + 128 + c], hn  = ghM[b + 256 + c];
    float r = 1.f / (1.f + __expf(-(ir + hr)));
    float z = 1.f / (1.f + __expf(-(iz + hz)));
    float nn = tanhf(inn + r * hn);
    float h = (1.f - z) * nn + z * mean[idx];
    h = fmaxf(h, 0.f);
    out[idx] = h * sc4[c] + sh4[c];
}

// predictor: relu(mol @ pW1^T + pb1) @ pW2^T + pb2, one block (64 thr) per molecule
__global__ __launch_bounds__(64) void pred_kernel(
    const float* __restrict__ mol, const float* __restrict__ pW1, const float* __restrict__ pb1,
    const float* __restrict__ pW2, const float* __restrict__ pb2, float* __restrict__ out)
{
    __shared__ float row[CCH];
    int m = blockIdx.x;
    int j = threadIdx.x;
    row[j] = mol[(size_t)m * CCH + j];
    row[j + 64] = mol[(size_t)m * CCH + 64 + j];
    __syncthreads();
    float h = pb1[j];
#pragma unroll
    for (int k = 0; k < CCH; ++k) h += row[k] * pW1[j * CCH + k];
    h = fmaxf(h, 0.f);
    float p = h * pW2[j];
    for (int o = 32; o; o >>= 1) p += __shfl_down(p, o);
    if (j == 0) out[m] = p + pb2[0];
}

// ---------------- host ----------------

static void run_stage(const float* Xf, int n, const int* starts, int nseg,
                      int bnb, int gi, float* outbuf,
                      float* mean, float* upool, float* gbuf, float* giM, float* ghM,
                      float* scores, float* ad,
                      const float* bnsc, const float* bnsh,
                      const float* vsp, const float* vd, const float* c0,
                      const float* gat_Wsrc, const float* gat_bias,
                      const float* gru_Wih, const float* gru_Whh,
                      const float* gru_bih, const float* gru_bhh,
                      hipStream_t stream)
{
    pool_kernel<<<nseg, 128, 0, stream>>>(Xf, starts,
        bnsc + bnb * CCH, bnsh + bnb * CCH, bnsc + (bnb + 1) * CCH, bnsh + (bnb + 1) * CCH,
        vd + gi * CCH, mean, ad);
    scores_kernel<<<(n * 64 + 255) / 256, 256, 0, stream>>>(Xf, vsp + gi * CCH, c0 + gi, scores, n);
    attnpool_kernel<<<nseg, 128, 0, stream>>>(Xf, scores, ad, starts,
        bnsc + bnb * CCH, bnsh + bnb * CCH, upool);
    dim3 g1((nseg + 31) / 32, CCH / 64);
    gemm128<<<g1, 256, 0, stream>>>(upool, gat_Wsrc + gi * CCH * CCH, gat_bias + gi * CCH,
                                    gbuf, nseg, CCH, 1 /*elu*/);
    dim3 g2((nseg + 31) / 32, G3 / 64);
    gemm128<<<g2, 256, 0, stream>>>(gbuf, gru_Wih + gi * G3 * CCH, gru_bih + gi * G3, giM, nseg, G3, 0);
    gemm128<<<g2, 256, 0, stream>>>(mean, gru_Whh + gi * G3 * CCH, gru_bhh + gi * G3, ghM, nseg, G3, 0);
    gru_kernel<<<(nseg * CCH + 255) / 256, 256, 0, stream>>>(giM, ghM, mean,
        bnsc + (bnb + 2) * CCH, bnsh + (bnb + 2) * CCH, outbuf, nseg * CCH);
}

extern "C" void kernel_launch(void* const* d_in, const int* in_sizes, int n_in,
                              void* d_out, int out_size, void* d_ws, size_t ws_size,
                              hipStream_t stream)
{
    (void)n_in; (void)ws_size;
    const float* node_attr      = (const float*)d_in[0];
    const int*   adj_index      = (const int*)  d_in[1];
    const float* adj_value      = (const float*)d_in[2];
    const int*   tt_node_batch  = (const int*)  d_in[3];
    const int*   tt_graph_batch = (const int*)  d_in[4];
    const float* W_gcn    = (const float*)d_in[5];
    const float* b_gcn    = (const float*)d_in[6];
    const float* bn_gamma = (const float*)d_in[7];
    const float* bn_beta  = (const float*)d_in[8];
    const float* bn_mean  = (const float*)d_in[9];
    const float* bn_var   = (const float*)d_in[10];
    const float* gat_Wsrc = (const float*)d_in[11];
    const float* gat_Wdst = (const float*)d_in[12];
    const float* gat_asrc = (const float*)d_in[13];
    const float* gat_adst = (const float*)d_in[14];
    const float* gat_bias = (const float*)d_in[15];
    const float* gru_Wih  = (const float*)d_in[16];
    const float* gru_Whh  = (const float*)d_in[17];
    const float* gru_bih  = (const float*)d_in[18];
    const float* gru_bhh  = (const float*)d_in[19];
    const float* pW1 = (const float*)d_in[20];
    const float* pb1 = (const float*)d_in[21];
    const float* pW2 = (const float*)d_in[22];
    const float* pb2 = (const float*)d_in[23];

    const int E    = in_sizes[2];
    const int N    = in_sizes[3];
    const int NTT  = in_sizes[4];
    const int NMOL = out_size;

    const int* adj_rows = adj_index;
    const int* adj_cols = adj_index + E;

    // ---- workspace carve ----
    char* wsb = (char*)d_ws;
    size_t off = 0;
    auto carve = [&](size_t bytes) -> char* {
        char* p = wsb + off;
        off = (off + bytes + 255) & ~(size_t)255;
        return p;
    };
    float* A    = (float*)carve((size_t)N * CCH * 4);
    float* B    = (float*)carve((size_t)N * CCH * 4);
    float* tt   = (float*)carve((size_t)NTT * CCH * 4);
    float* mol  = (float*)carve((size_t)NMOL * CCH * 4);
    float* ad   = (float*)carve((size_t)NTT * 4);
    int* starts_tt  = (int*)carve((size_t)(NTT + 1) * 4);
    int* starts_mol = (int*)carve((size_t)(NMOL + 1) * 4);
    float* bnsc = (float*)carve(8 * CCH * 4);
    float* bnsh = (float*)carve(8 * CCH * 4);
    float* vsp  = (float*)carve(2 * CCH * 4);
    float* vd   = (float*)carve(2 * CCH * 4);
    float* c0   = (float*)carve(2 * 4);
    // CSR
    int*   counts  = (int*)carve((size_t)N * 4);       // reused as scatter cursor
    int*   row_ptr = (int*)carve((size_t)(N + 1) * 4);
    int*   bsum    = (int*)carve(256 * 4);
    int*   ccol    = (int*)carve((size_t)E * 4);
    float* cval    = (float*)carve((size_t)E * 4);

    // stage temporaries overlay inside B (free after GCN):
    // 3*NTT*C + 2*NTT*384 + N = 23.24M floats <= 25.6M floats
    float* mean   = B;
    float* upool  = B + (size_t)NTT * CCH;
    float* gbuf   = B + (size_t)2 * NTT * CCH;
    float* giM    = B + (size_t)3 * NTT * CCH;
    float* ghM    = giM + (size_t)NTT * G3;
    float* scores = ghM + (size_t)NTT * G3;

    // ---- prep ----
    bnprep_kernel<<<8, 128, 0, stream>>>(bn_gamma, bn_beta, bn_mean, bn_var, bnsc, bnsh);
    matvec_prep_kernel<<<4, 128, 0, stream>>>(gat_Wsrc, gat_Wdst, gat_asrc, gat_adst,
                                              bnsc, bnsh, vsp, vd, c0);
    bounds_kernel<<<(NTT + 1 + 255) / 256, 256, 0, stream>>>(tt_node_batch, N, NTT, starts_tt);
    bounds_kernel<<<(NMOL + 1 + 255) / 256, 256, 0, stream>>>(tt_graph_batch, NTT, NMOL, starts_mol);

    // ---- CSR build (once; shared by both GCN layers) ----
    const int nblk = (N + 1023) / 1024;
    hipMemsetAsync(counts, 0, (size_t)N * 4, stream);
    hist_kernel<<<(E + 255) / 256, 256, 0, stream>>>(adj_rows, counts, E);
    scan_reduce_kernel<<<nblk, 256, 0, stream>>>(counts, bsum, N);
    scan_top_kernel<<<1, 256, 0, stream>>>(bsum, nblk, row_ptr, N, E);
    scan_down_kernel<<<nblk, 256, 0, stream>>>(counts, bsum, row_ptr, counts, N);
    scatter_kernel<<<(E + 255) / 256, 256, 0, stream>>>(adj_rows, adj_cols, adj_value,
                                                        counts, ccol, cval, E);

    // ---- GCN x2: t1 = x @ W^T ; y = A_sp @ t1 ; x = relu(bn(y + b)) [fused] ----
    for (int l = 0; l < 2; ++l) {
        const float* xin = (l == 0) ? node_attr : A;
        dim3 gg((N + 31) / 32, CCH / 64);
        gemm128<<<gg, 256, 0, stream>>>(xin, W_gcn + l * CCH * CCH, nullptr, B, N, CCH, 0);
        spmm_csr_kernel<<<((size_t)N * 32 + 255) / 256, 256, 0, stream>>>(
            row_ptr, ccol, cval, B, A, b_gcn + l * CCH, bnsc + l * CCH, bnsh + l * CCH, N);
    }

    // ---- tt stage: N -> NTT ----
    run_stage(A, N, starts_tt, NTT, 2, 0, tt,
              mean, upool, gbuf, giM, ghM, scores, ad,
              bnsc, bnsh, vsp, vd, c0,
              gat_Wsrc, gat_bias, gru_Wih, gru_Whh, gru_bih, gru_bhh, stream);

    // ---- mol stage: NTT -> NMOL ----
    run_stage(tt, NTT, starts_mol, NMOL, 5, 1, mol,
              mean, upool, gbuf, giM, ghM, scores, ad,
              bnsc, bnsh, vsp, vd, c0,
              gat_Wsrc, gat_bias, gru_Wih, gru_Whh, gru_bih, gru_bhh, stream);

    // ---- predictor ----
    pred_kernel<<<NMOL, 64, 0, stream>>>(mol, pW1, pb1, pW2, pb2, (float*)d_out);
}

// Round 3
// 925.815 us; speedup vs baseline: 6.7872x; 1.3529x over previous
//
#include <hip/hip_runtime.h>
#include <math.h>

#define CCH 128
#define G3  384
#define BN_EPS 1e-5f

typedef __bf16 bf16;
typedef __bf16 bf16x2 __attribute__((ext_vector_type(2)));
typedef __bf16 bf16x4 __attribute__((ext_vector_type(4)));
typedef __bf16 bf16x8 __attribute__((ext_vector_type(8)));
typedef float f32x4 __attribute__((ext_vector_type(4)));

// ---------------- small prep kernels ----------------

__global__ void bnprep_kernel(const float* __restrict__ g, const float* __restrict__ b,
                              const float* __restrict__ m, const float* __restrict__ v,
                              float* __restrict__ sc, float* __restrict__ sh)
{
    int idx = blockIdx.x * 128 + threadIdx.x;   // 8*128 total
    float s = g[idx] / sqrtf(v[idx] + BN_EPS);
    sc[idx] = s;
    sh[idx] = b[idx] - m[idx] * s;
}

// v_s = Wsrc^T a_src (folded with bn2 scale, plus c0 = sum(shift*v)), v_d = Wdst^T a_dst
__global__ __launch_bounds__(128) void matvec_prep_kernel(
    const float* __restrict__ Wsrc, const float* __restrict__ Wdst,
    const float* __restrict__ asrc, const float* __restrict__ adst,
    const float* __restrict__ bnsc, const float* __restrict__ bnsh,
    float* __restrict__ vsp, float* __restrict__ vd, float* __restrict__ c0)
{
    __shared__ float red[2];
    int s = blockIdx.x >> 1, which = blockIdx.x & 1;
    int k = threadIdx.x;
    const float* W = (which ? Wdst : Wsrc) + s * CCH * CCH;
    const float* a = (which ? adst : asrc) + s * CCH;
    float acc = 0.f;
    for (int j = 0; j < CCH; ++j) acc += W[j * CCH + k] * a[j];
    if (which) {
        vd[s * CCH + k] = acc;
    } else {
        int l = 2 + 3 * s;   // bn index of the stage's input bn
        vsp[s * CCH + k] = acc * bnsc[l * CCH + k];
        float p = bnsh[l * CCH + k] * acc;
        for (int o = 32; o; o >>= 1) p += __shfl_down(p, o);
        if ((k & 63) == 0) red[k >> 6] = p;
        __syncthreads();
        if (k == 0) c0[s] = red[0] + red[1];
    }
}

// starts[s] = lower_bound(batch, s); batch sorted. s in [0, nseg]
__global__ void bounds_kernel(const int* __restrict__ batch, int n, int nseg, int* __restrict__ starts)
{
    int s = blockIdx.x * 256 + threadIdx.x;
    if (s > nseg) return;
    int lo = 0, hi = n;
    while (lo < hi) {
        int mid = (lo + hi) >> 1;
        if (batch[mid] < s) lo = mid + 1; else hi = mid;
    }
    starts[s] = lo;
}

// ---------------- CSR build: histogram -> scan -> scatter ----------------

__global__ __launch_bounds__(256) void hist_kernel(const int* __restrict__ rows,
                                                   int* __restrict__ counts, int E)
{
    int e = blockIdx.x * 256 + threadIdx.x;
    if (e < E) atomicAdd(&counts[rows[e]], 1);
}

__global__ __launch_bounds__(256) void scan_reduce_kernel(const int* __restrict__ counts,
                                                          int* __restrict__ bsum, int n)
{
    __shared__ int lds[4];
    int t = threadIdx.x;
    int base = blockIdx.x * 1024 + t * 4;
    int s = 0;
#pragma unroll
    for (int i = 0; i < 4; ++i) {
        int idx = base + i;
        if (idx < n) s += counts[idx];
    }
    for (int o = 32; o; o >>= 1) s += __shfl_down(s, o);
    if ((t & 63) == 0) lds[t >> 6] = s;
    __syncthreads();
    if (t == 0) bsum[blockIdx.x] = lds[0] + lds[1] + lds[2] + lds[3];
}

__global__ __launch_bounds__(256) void scan_top_kernel(int* __restrict__ bsum, int nb,
                                                       int* __restrict__ row_ptr, int n, int E)
{
    __shared__ int tmp[256];
    int t = threadIdx.x;
    int v = (t < nb) ? bsum[t] : 0;
    tmp[t] = v;
    __syncthreads();
    for (int o = 1; o < 256; o <<= 1) {
        int u = (t >= o) ? tmp[t - o] : 0;
        __syncthreads();
        tmp[t] += u;
        __syncthreads();
    }
    if (t < nb) bsum[t] = tmp[t] - v;   // exclusive
    if (t == 0) row_ptr[n] = E;
}

__global__ __launch_bounds__(256) void scan_down_kernel(const int* __restrict__ counts,
                                                        const int* __restrict__ bsum,
                                                        int* __restrict__ row_ptr,
                                                        int* __restrict__ cursor, int n)
{
    __shared__ int tmp[256];
    int t = threadIdx.x;
    int base = blockIdx.x * 1024 + t * 4;
    int v0 = 0, v1 = 0, v2 = 0, v3 = 0;
    if (base + 0 < n) v0 = counts[base + 0];
    if (base + 1 < n) v1 = counts[base + 1];
    if (base + 2 < n) v2 = counts[base + 2];
    if (base + 3 < n) v3 = counts[base + 3];
    int ts = v0 + v1 + v2 + v3;
    tmp[t] = ts;
    __syncthreads();
    for (int o = 1; o < 256; o <<= 1) {
        int u = (t >= o) ? tmp[t - o] : 0;
        __syncthreads();
        tmp[t] += u;
        __syncthreads();
    }
    int off = bsum[blockIdx.x] + tmp[t] - ts;
    int p0 = off, p1 = off + v0, p2 = p1 + v1, p3 = p2 + v2;
    if (base + 0 < n) { row_ptr[base + 0] = p0; cursor[base + 0] = p0; }
    if (base + 1 < n) { row_ptr[base + 1] = p1; cursor[base + 1] = p1; }
    if (base + 2 < n) { row_ptr[base + 2] = p2; cursor[base + 2] = p2; }
    if (base + 3 < n) { row_ptr[base + 3] = p3; cursor[base + 3] = p3; }
}

__global__ __launch_bounds__(256) void scatter_kernel(const int* __restrict__ rows,
                                                      const int* __restrict__ cols,
                                                      const float* __restrict__ val,
                                                      int* __restrict__ cursor,
                                                      int* __restrict__ ccol,
                                                      float* __restrict__ cval, int E)
{
    int e = blockIdx.x * 256 + threadIdx.x;
    if (e >= E) return;
    int r = rows[e];
    int p = atomicAdd(&cursor[r], 1);
    ccol[p] = cols[e];
    cval[p] = val[e];
}

// ---------------- MFMA GEMM: Y[M x Nout] = X[M x 128] @ W[Nout x 128]^T (+bias)(+elu) ----
// 128x128 block tile, K=128 staged once. grid: (ceil(M/128), Nout/128), block 256 (4 waves 2x2).
// LDS layout [row][k] bf16, stride 136 (272 B: 16B-aligned, breaks the 64-bank power-of-2 stride).

template<int IN_BF16, int OUT_BF16, int ACT>
__global__ __launch_bounds__(256, 2) void gemm_mfma(
    const void* __restrict__ Xv, const float* __restrict__ W,
    const float* __restrict__ bias, void* __restrict__ Yv, int M, int Nout)
{
    __shared__ bf16 Xs[128 * 136];
    __shared__ bf16 Ws[128 * 136];
    const int tid = threadIdx.x;
    const int rb = blockIdx.x * 128;
    const int cb = blockIdx.y * 128;

    // stage W tile (cols always full: Nout % 128 == 0)
#pragma unroll
    for (int i = 0; i < 16; ++i) {
        int c = tid + i * 256;                 // 4-elem chunk id
        int r = c >> 5, k4 = (c & 31) << 2;
        float4 wv = *(const float4*)&W[(size_t)(cb + r) * CCH + k4];
        bf16x4 o = { (bf16)wv.x, (bf16)wv.y, (bf16)wv.z, (bf16)wv.w };
        *(bf16x4*)&Ws[r * 136 + k4] = o;
    }
    // stage X tile
#pragma unroll
    for (int i = 0; i < 16; ++i) {
        int c = tid + i * 256;
        int r = c >> 5, k4 = (c & 31) << 2;
        int grow = rb + r;
        bf16x4 o = {};
        if (grow < M) {
            if (IN_BF16) {
                o = *(const bf16x4*)&((const bf16*)Xv)[(size_t)grow * CCH + k4];
            } else {
                float4 xv = *(const float4*)&((const float*)Xv)[(size_t)grow * CCH + k4];
                o[0] = (bf16)xv.x; o[1] = (bf16)xv.y; o[2] = (bf16)xv.z; o[3] = (bf16)xv.w;
            }
        }
        *(bf16x4*)&Xs[r * 136 + k4] = o;
    }
    __syncthreads();

    const int w = tid >> 6, lane = tid & 63;
    const int col16 = lane & 15, quad = lane >> 4;
    const int wm = (w & 1) * 64, wn = (w >> 1) * 64;

    f32x4 acc[4][4] = {};
#pragma unroll
    for (int kk = 0; kk < 4; ++kk) {
        bf16x8 af[4], bfr[4];
#pragma unroll
        for (int mi = 0; mi < 4; ++mi)
            af[mi] = *(const bf16x8*)&Xs[(wm + mi * 16 + col16) * 136 + kk * 32 + quad * 8];
#pragma unroll
        for (int ni = 0; ni < 4; ++ni)
            bfr[ni] = *(const bf16x8*)&Ws[(wn + ni * 16 + col16) * 136 + kk * 32 + quad * 8];
#pragma unroll
        for (int mi = 0; mi < 4; ++mi)
#pragma unroll
            for (int ni = 0; ni < 4; ++ni)
                acc[mi][ni] = __builtin_amdgcn_mfma_f32_16x16x32_bf16(af[mi], bfr[ni], acc[mi][ni], 0, 0, 0);
    }

    // epilogue: D row = quad*4 + reg, col = lane&15 (per m89-verified mapping)
#pragma unroll
    for (int mi = 0; mi < 4; ++mi) {
#pragma unroll
        for (int r = 0; r < 4; ++r) {
            int row = rb + wm + mi * 16 + quad * 4 + r;
            if (row >= M) continue;
#pragma unroll
            for (int ni = 0; ni < 4; ++ni) {
                int col = cb + wn + ni * 16 + col16;
                float v = acc[mi][ni][r];
                if (bias) v += bias[col];
                if (ACT == 1) v = v > 0.f ? v : expm1f(v);   // elu
                if (OUT_BF16) ((bf16*)Yv)[(size_t)row * Nout + col] = (bf16)v;
                else          ((float*)Yv)[(size_t)row * Nout + col] = v;
            }
        }
    }
}

// ---------------- SpMM (CSR gather, bf16 in/out): 32 lanes per row, fused bias+bn+relu ----
__global__ __launch_bounds__(256) void spmm_csr_kernel(
    const int* __restrict__ row_ptr, const int* __restrict__ ccol, const float* __restrict__ cval,
    const bf16* __restrict__ Xin, bf16* __restrict__ Y,
    const float* __restrict__ bvec, const float* __restrict__ sc, const float* __restrict__ sh,
    int Nrow)
{
    int gid = blockIdx.x * 256 + threadIdx.x;
    int row = gid >> 5;
    if (row >= Nrow) return;
    int l4 = (gid & 31) << 2;
    int st = row_ptr[row], en = row_ptr[row + 1];
    float a0 = 0.f, a1 = 0.f, a2 = 0.f, a3 = 0.f;
    for (int j = st; j < en; ++j) {
        int c = ccol[j];
        float v = cval[j];
        bf16x4 x = *(const bf16x4*)&Xin[(size_t)c * CCH + l4];
        a0 += v * (float)x[0]; a1 += v * (float)x[1];
        a2 += v * (float)x[2]; a3 += v * (float)x[3];
    }
    float4 bb = *(const float4*)&bvec[l4];
    float4 s4 = *(const float4*)&sc[l4];
    float4 h4 = *(const float4*)&sh[l4];
    bf16x4 o;
    o[0] = (bf16)fmaxf((a0 + bb.x) * s4.x + h4.x, 0.f);
    o[1] = (bf16)fmaxf((a1 + bb.y) * s4.y + h4.y, 0.f);
    o[2] = (bf16)fmaxf((a2 + bb.z) * s4.z + h4.z, 0.f);
    o[3] = (bf16)fmaxf((a3 + bb.w) * s4.w + h4.w, 0.f);
    *(bf16x4*)&Y[(size_t)row * CCH + l4] = o;
}

// ---------------- pooling stage kernels (bf16 X) ----------------

__global__ __launch_bounds__(128) void pool_kernel(
    const bf16* __restrict__ X, const int* __restrict__ starts,
    const float* __restrict__ sc2, const float* __restrict__ sh2,
    const float* __restrict__ sc3, const float* __restrict__ sh3,
    const float* __restrict__ vd, float* __restrict__ mean, float* __restrict__ ad)
{
    __shared__ float red[2];
    int t = blockIdx.x;
    int c = threadIdx.x;
    int st = starts[t], en = starts[t + 1];
    float sum = 0.f;
    for (int i = st; i < en; ++i) sum += (float)X[(size_t)i * CCH + c];
    float cnt = (float)(en - st);
    float poolb = fmaxf(sum * sc2[c] + cnt * sh2[c], 0.f);
    float mv = poolb * sc3[c] + sh3[c];
    mean[(size_t)t * CCH + c] = mv;
    float p = mv * vd[c];
    for (int o = 32; o; o >>= 1) p += __shfl_down(p, o);
    if ((c & 63) == 0) red[c >> 6] = p;
    __syncthreads();
    if (c == 0) ad[t] = red[0] + red[1];
}

__global__ __launch_bounds__(256) void scores_kernel(
    const bf16* __restrict__ X, const float* __restrict__ vsp, const float* __restrict__ c0p,
    float* __restrict__ s, int n)
{
    int gid = blockIdx.x * 256 + threadIdx.x;
    int row = gid >> 6;
    if (row >= n) return;
    int lane = (gid & 63) << 1;
    bf16x2 xv = *(const bf16x2*)&X[(size_t)row * CCH + lane];
    float2 vv = *(const float2*)&vsp[lane];
    float p = (float)xv[0] * vv.x + (float)xv[1] * vv.y;
    for (int o = 32; o; o >>= 1) p += __shfl_down(p, o);
    if ((gid & 63) == 0) s[row] = p + c0p[0];
}

__global__ __launch_bounds__(128) void attnpool_kernel(
    const bf16* __restrict__ X, const float* __restrict__ sarr, const float* __restrict__ ad,
    const int* __restrict__ starts, const float* __restrict__ sc2, const float* __restrict__ sh2,
    float* __restrict__ upool)
{
    __shared__ float red[2];
    int t = blockIdx.x;
    int c = threadIdx.x;
    int st = starts[t], en = starts[t + 1];
    if (en == st) { upool[(size_t)t * CCH + c] = 0.f; return; }
    float adt = ad[t];
    float lm = -3.0e38f;
    for (int i = st + c; i < en; i += 128) {
        float a = sarr[i] + adt;
        a = a > 0.f ? a : 0.01f * a;
        lm = fmaxf(lm, a);
    }
    for (int o = 32; o; o >>= 1) lm = fmaxf(lm, __shfl_down(lm, o));
    if ((c & 63) == 0) red[c >> 6] = lm;
    __syncthreads();
    float m = fmaxf(red[0], red[1]);
    float u = 0.f, den = 0.f;
    for (int i = st; i < en; ++i) {
        float a = sarr[i] + adt;
        a = a > 0.f ? a : 0.01f * a;
        float e = __expf(a - m);
        den += e;
        u += e * (float)X[(size_t)i * CCH + c];
    }
    upool[(size_t)t * CCH + c] = (u / den) * sc2[c] + sh2[c];
}

// GRU combine + relu + bn(base+2); OUT_BF16 selects output dtype
template<int OUT_BF16>
__global__ __launch_bounds__(256) void gru_kernel(
    const float* __restrict__ giM, const float* __restrict__ ghM, const float* __restrict__ mean,
    const float* __restrict__ sc4, const float* __restrict__ sh4,
    void* __restrict__ out, int total)
{
    int idx = blockIdx.x * 256 + threadIdx.x;
    if (idx >= total) return;
    int t = idx >> 7, c = idx & 127;
    size_t b = (size_t)t * G3;
    float ir = giM[b + c],  iz = giM[b + 128 + c], inn = giM[b + 256 + c];
    float hr = ghM[b + c],  hz = ghM[b + 128 + c], hn  = ghM[b + 256 + c];
    float r = 1.f / (1.f + __expf(-(ir + hr)));
    float z = 1.f / (1.f + __expf(-(iz + hz)));
    float nn = tanhf(inn + r * hn);
    float h = (1.f - z) * nn + z * mean[idx];
    h = fmaxf(h, 0.f);
    float o = h * sc4[c] + sh4[c];
    if (OUT_BF16) ((bf16*)out)[idx] = (bf16)o;
    else          ((float*)out)[idx] = o;
}

// predictor
__global__ __launch_bounds__(64) void pred_kernel(
    const float* __restrict__ mol, const float* __restrict__ pW1, const float* __restrict__ pb1,
    const float* __restrict__ pW2, const float* __restrict__ pb2, float* __restrict__ out)
{
    __shared__ float row[CCH];
    int m = blockIdx.x;
    int j = threadIdx.x;
    row[j] = mol[(size_t)m * CCH + j];
    row[j + 64] = mol[(size_t)m * CCH + 64 + j];
    __syncthreads();
    float h = pb1[j];
#pragma unroll
    for (int k = 0; k < CCH; ++k) h += row[k] * pW1[j * CCH + k];
    h = fmaxf(h, 0.f);
    float p = h * pW2[j];
    for (int o = 32; o; o >>= 1) p += __shfl_down(p, o);
    if (j == 0) out[m] = p + pb2[0];
}

// ---------------- host ----------------

static void run_stage(const bf16* Xf, int n, const int* starts, int nseg,
                      int bnb, int gi, void* outbuf, int out_bf16,
                      float* mean, float* upool, float* gbuf, float* giM, float* ghM,
                      float* scores, float* ad,
                      const float* bnsc, const float* bnsh,
                      const float* vsp, const float* vd, const float* c0,
                      const float* gat_Wsrc, const float* gat_bias,
                      const float* gru_Wih, const float* gru_Whh,
                      const float* gru_bih, const float* gru_bhh,
                      hipStream_t stream)
{
    pool_kernel<<<nseg, 128, 0, stream>>>(Xf, starts,
        bnsc + bnb * CCH, bnsh + bnb * CCH, bnsc + (bnb + 1) * CCH, bnsh + (bnb + 1) * CCH,
        vd + gi * CCH, mean, ad);
    scores_kernel<<<(n * 64 + 255) / 256, 256, 0, stream>>>(Xf, vsp + gi * CCH, c0 + gi, scores, n);
    attnpool_kernel<<<nseg, 128, 0, stream>>>(Xf, scores, ad, starts,
        bnsc + bnb * CCH, bnsh + bnb * CCH, upool);
    dim3 g1((nseg + 127) / 128, 1);
    gemm_mfma<0, 0, 1><<<g1, 256, 0, stream>>>(upool, gat_Wsrc + gi * CCH * CCH,
                                               gat_bias + gi * CCH, gbuf, nseg, CCH);
    dim3 g2((nseg + 127) / 128, 3);
    gemm_mfma<0, 0, 0><<<g2, 256, 0, stream>>>(gbuf, gru_Wih + gi * G3 * CCH,
                                               gru_bih + gi * G3, giM, nseg, G3);
    gemm_mfma<0, 0, 0><<<g2, 256, 0, stream>>>(mean, gru_Whh + gi * G3 * CCH,
                                               gru_bhh + gi * G3, ghM, nseg, G3);
    if (out_bf16)
        gru_kernel<1><<<(nseg * CCH + 255) / 256, 256, 0, stream>>>(giM, ghM, mean,
            bnsc + (bnb + 2) * CCH, bnsh + (bnb + 2) * CCH, outbuf, nseg * CCH);
    else
        gru_kernel<0><<<(nseg * CCH + 255) / 256, 256, 0, stream>>>(giM, ghM, mean,
            bnsc + (bnb + 2) * CCH, bnsh + (bnb + 2) * CCH, outbuf, nseg * CCH);
}

extern "C" void kernel_launch(void* const* d_in, const int* in_sizes, int n_in,
                              void* d_out, int out_size, void* d_ws, size_t ws_size,
                              hipStream_t stream)
{
    (void)n_in; (void)ws_size;
    const float* node_attr      = (const float*)d_in[0];
    const int*   adj_index      = (const int*)  d_in[1];
    const float* adj_value      = (const float*)d_in[2];
    const int*   tt_node_batch  = (const int*)  d_in[3];
    const int*   tt_graph_batch = (const int*)  d_in[4];
    const float* W_gcn    = (const float*)d_in[5];
    const float* b_gcn    = (const float*)d_in[6];
    const float* bn_gamma = (const float*)d_in[7];
    const float* bn_beta  = (const float*)d_in[8];
    const float* bn_mean  = (const float*)d_in[9];
    const float* bn_var   = (const float*)d_in[10];
    const float* gat_Wsrc = (const float*)d_in[11];
    const float* gat_Wdst = (const float*)d_in[12];
    const float* gat_asrc = (const float*)d_in[13];
    const float* gat_adst = (const float*)d_in[14];
    const float* gat_bias = (const float*)d_in[15];
    const float* gru_Wih  = (const float*)d_in[16];
    const float* gru_Whh  = (const float*)d_in[17];
    const float* gru_bih  = (const float*)d_in[18];
    const float* gru_bhh  = (const float*)d_in[19];
    const float* pW1 = (const float*)d_in[20];
    const float* pb1 = (const float*)d_in[21];
    const float* pW2 = (const float*)d_in[22];
    const float* pb2 = (const float*)d_in[23];

    const int E    = in_sizes[2];
    const int N    = in_sizes[3];
    const int NTT  = in_sizes[4];
    const int NMOL = out_size;

    const int* adj_rows = adj_index;
    const int* adj_cols = adj_index + E;

    // ---- workspace carve ----
    char* wsb = (char*)d_ws;
    size_t off = 0;
    auto carve = [&](size_t bytes) -> char* {
        char* p = wsb + off;
        off = (off + bytes + 255) & ~(size_t)255;
        return p;
    };
    bf16* bufB = (bf16*)carve((size_t)N * CCH * 2);    // gemm out -> spmm in
    bf16* bufA = (bf16*)carve((size_t)N * CCH * 2);    // spmm out -> gemm2 in / stage X
    bf16* tt   = (bf16*)carve((size_t)NTT * CCH * 2);
    float* mol  = (float*)carve((size_t)NMOL * CCH * 4);
    float* mean  = (float*)carve((size_t)NTT * CCH * 4);
    float* upool = (float*)carve((size_t)NTT * CCH * 4);
    float* gbuf  = (float*)carve((size_t)NTT * CCH * 4);
    float* giM   = (float*)carve((size_t)NTT * G3 * 4);
    float* ghM   = (float*)carve((size_t)NTT * G3 * 4);
    float* scores = (float*)carve((size_t)N * 4);
    float* ad   = (float*)carve((size_t)NTT * 4);
    int* starts_tt  = (int*)carve((size_t)(NTT + 1) * 4);
    int* starts_mol = (int*)carve((size_t)(NMOL + 1) * 4);
    float* bnsc = (float*)carve(8 * CCH * 4);
    float* bnsh = (float*)carve(8 * CCH * 4);
    float* vsp  = (float*)carve(2 * CCH * 4);
    float* vd   = (float*)carve(2 * CCH * 4);
    float* c0   = (float*)carve(2 * 4);
    int*   counts  = (int*)carve((size_t)N * 4);       // reused as scatter cursor
    int*   row_ptr = (int*)carve((size_t)(N + 1) * 4);
    int*   bsum    = (int*)carve(256 * 4);
    int*   ccol    = (int*)carve((size_t)E * 4);
    float* cval    = (float*)carve((size_t)E * 4);

    // ---- prep ----
    bnprep_kernel<<<8, 128, 0, stream>>>(bn_gamma, bn_beta, bn_mean, bn_var, bnsc, bnsh);
    matvec_prep_kernel<<<4, 128, 0, stream>>>(gat_Wsrc, gat_Wdst, gat_asrc, gat_adst,
                                              bnsc, bnsh, vsp, vd, c0);
    bounds_kernel<<<(NTT + 1 + 255) / 256, 256, 0, stream>>>(tt_node_batch, N, NTT, starts_tt);
    bounds_kernel<<<(NMOL + 1 + 255) / 256, 256, 0, stream>>>(tt_graph_batch, NTT, NMOL, starts_mol);

    // ---- CSR build (once; shared by both GCN layers) ----
    const int nblk = (N + 1023) / 1024;
    hipMemsetAsync(counts, 0, (size_t)N * 4, stream);
    hist_kernel<<<(E + 255) / 256, 256, 0, stream>>>(adj_rows, counts, E);
    scan_reduce_kernel<<<nblk, 256, 0, stream>>>(counts, bsum, N);
    scan_top_kernel<<<1, 256, 0, stream>>>(bsum, nblk, row_ptr, N, E);
    scan_down_kernel<<<nblk, 256, 0, stream>>>(counts, bsum, row_ptr, counts, N);
    scatter_kernel<<<(E + 255) / 256, 256, 0, stream>>>(adj_rows, adj_cols, adj_value,
                                                        counts, ccol, cval, E);

    // ---- GCN x2: B = bf16(x @ W^T) ; A = bf16(relu(bn(A_sp @ B + b))) ----
    dim3 gg((N + 127) / 128, 1);
    gemm_mfma<0, 1, 0><<<gg, 256, 0, stream>>>(node_attr, W_gcn + 0 * CCH * CCH,
                                               nullptr, bufB, N, CCH);
    spmm_csr_kernel<<<((size_t)N * 32 + 255) / 256, 256, 0, stream>>>(
        row_ptr, ccol, cval, bufB, bufA, b_gcn + 0 * CCH, bnsc + 0 * CCH, bnsh + 0 * CCH, N);
    gemm_mfma<1, 1, 0><<<gg, 256, 0, stream>>>(bufA, W_gcn + 1 * CCH * CCH,
                                               nullptr, bufB, N, CCH);
    spmm_csr_kernel<<<((size_t)N * 32 + 255) / 256, 256, 0, stream>>>(
        row_ptr, ccol, cval, bufB, bufA, b_gcn + 1 * CCH, bnsc + 1 * CCH, bnsh + 1 * CCH, N);

    // ---- tt stage: N -> NTT (bf16 out) ----
    run_stage(bufA, N, starts_tt, NTT, 2, 0, tt, 1,
              mean, upool, gbuf, giM, ghM, scores, ad,
              bnsc, bnsh, vsp, vd, c0,
              gat_Wsrc, gat_bias, gru_Wih, gru_Whh, gru_bih, gru_bhh, stream);

    // ---- mol stage: NTT -> NMOL (fp32 out) ----
    run_stage(tt, NTT, starts_mol, NMOL, 5, 1, mol, 0,
              mean, upool, gbuf, giM, ghM, scores, ad,
              bnsc, bnsh, vsp, vd, c0,
              gat_Wsrc, gat_bias, gru_Wih, gru_Whh, gru_bih, gru_bhh, stream);

    // ---- predictor ----
    pred_kernel<<<NMOL, 64, 0, stream>>>(mol, pW1, pb1, pW2, pb2, (float*)d_out);
}

// Round 4
// 797.554 us; speedup vs baseline: 7.8787x; 1.1608x over previous
//
#include <hip/hip_runtime.h>
#include <math.h>

#define CCH 128
#define G3  384
#define BN_EPS 1e-5f

typedef __bf16 bf16;
typedef __bf16 bf16x2 __attribute__((ext_vector_type(2)));
typedef __bf16 bf16x4 __attribute__((ext_vector_type(4)));
typedef __bf16 bf16x8 __attribute__((ext_vector_type(8)));
typedef float f32x4 __attribute__((ext_vector_type(4)));

// ---------------- small prep kernels ----------------

__global__ void bnprep_kernel(const float* __restrict__ g, const float* __restrict__ b,
                              const float* __restrict__ m, const float* __restrict__ v,
                              float* __restrict__ sc, float* __restrict__ sh)
{
    int idx = blockIdx.x * 128 + threadIdx.x;   // 8*128 total
    float s = g[idx] / sqrtf(v[idx] + BN_EPS);
    sc[idx] = s;
    sh[idx] = b[idx] - m[idx] * s;
}

// fp32 -> bf16 weight conversion (n4 = n/4)
__global__ void f2b_kernel(const float* __restrict__ in, bf16* __restrict__ out, int n4)
{
    int i = blockIdx.x * 256 + threadIdx.x;
    if (i >= n4) return;
    float4 v = ((const float4*)in)[i];
    bf16x4 o = { (bf16)v.x, (bf16)v.y, (bf16)v.z, (bf16)v.w };
    ((bf16x4*)out)[i] = o;
}

// v_s = Wsrc^T a_src (folded with bn2 scale, plus c0 = sum(shift*v)), v_d = Wdst^T a_dst
__global__ __launch_bounds__(128) void matvec_prep_kernel(
    const float* __restrict__ Wsrc, const float* __restrict__ Wdst,
    const float* __restrict__ asrc, const float* __restrict__ adst,
    const float* __restrict__ bnsc, const float* __restrict__ bnsh,
    float* __restrict__ vsp, float* __restrict__ vd, float* __restrict__ c0)
{
    __shared__ float red[2];
    int s = blockIdx.x >> 1, which = blockIdx.x & 1;
    int k = threadIdx.x;
    const float* W = (which ? Wdst : Wsrc) + s * CCH * CCH;
    const float* a = (which ? adst : asrc) + s * CCH;
    float acc = 0.f;
    for (int j = 0; j < CCH; ++j) acc += W[j * CCH + k] * a[j];
    if (which) {
        vd[s * CCH + k] = acc;
    } else {
        int l = 2 + 3 * s;   // bn index of the stage's input bn
        vsp[s * CCH + k] = acc * bnsc[l * CCH + k];
        float p = bnsh[l * CCH + k] * acc;
        for (int o = 32; o; o >>= 1) p += __shfl_down(p, o);
        if ((k & 63) == 0) red[k >> 6] = p;
        __syncthreads();
        if (k == 0) c0[s] = red[0] + red[1];
    }
}

// starts[s] = lower_bound(batch, s); batch sorted. s in [0, nseg]
__global__ void bounds_kernel(const int* __restrict__ batch, int n, int nseg, int* __restrict__ starts)
{
    int s = blockIdx.x * 256 + threadIdx.x;
    if (s > nseg) return;
    int lo = 0, hi = n;
    while (lo < hi) {
        int mid = (lo + hi) >> 1;
        if (batch[mid] < s) lo = mid + 1; else hi = mid;
    }
    starts[s] = lo;
}

// ---------------- CSR build: histogram -> scan -> scatter ----------------

__global__ __launch_bounds__(256) void hist_kernel(const int* __restrict__ rows,
                                                   int* __restrict__ counts, int E)
{
    int e = blockIdx.x * 256 + threadIdx.x;
    if (e < E) atomicAdd(&counts[rows[e]], 1);
}

__global__ __launch_bounds__(256) void scan_reduce_kernel(const int* __restrict__ counts,
                                                          int* __restrict__ bsum, int n)
{
    __shared__ int lds[4];
    int t = threadIdx.x;
    int base = blockIdx.x * 1024 + t * 4;
    int s = 0;
#pragma unroll
    for (int i = 0; i < 4; ++i) {
        int idx = base + i;
        if (idx < n) s += counts[idx];
    }
    for (int o = 32; o; o >>= 1) s += __shfl_down(s, o);
    if ((t & 63) == 0) lds[t >> 6] = s;
    __syncthreads();
    if (t == 0) bsum[blockIdx.x] = lds[0] + lds[1] + lds[2] + lds[3];
}

__global__ __launch_bounds__(256) void scan_top_kernel(int* __restrict__ bsum, int nb,
                                                       int* __restrict__ row_ptr, int n, int E)
{
    __shared__ int tmp[256];
    int t = threadIdx.x;
    int v = (t < nb) ? bsum[t] : 0;
    tmp[t] = v;
    __syncthreads();
    for (int o = 1; o < 256; o <<= 1) {
        int u = (t >= o) ? tmp[t - o] : 0;
        __syncthreads();
        tmp[t] += u;
        __syncthreads();
    }
    if (t < nb) bsum[t] = tmp[t] - v;   // exclusive
    if (t == 0) row_ptr[n] = E;
}

__global__ __launch_bounds__(256) void scan_down_kernel(const int* __restrict__ counts,
                                                        const int* __restrict__ bsum,
                                                        int* __restrict__ row_ptr,
                                                        int* __restrict__ cursor, int n)
{
    __shared__ int tmp[256];
    int t = threadIdx.x;
    int base = blockIdx.x * 1024 + t * 4;
    int v0 = 0, v1 = 0, v2 = 0, v3 = 0;
    if (base + 0 < n) v0 = counts[base + 0];
    if (base + 1 < n) v1 = counts[base + 1];
    if (base + 2 < n) v2 = counts[base + 2];
    if (base + 3 < n) v3 = counts[base + 3];
    int ts = v0 + v1 + v2 + v3;
    tmp[t] = ts;
    __syncthreads();
    for (int o = 1; o < 256; o <<= 1) {
        int u = (t >= o) ? tmp[t - o] : 0;
        __syncthreads();
        tmp[t] += u;
        __syncthreads();
    }
    int off = bsum[blockIdx.x] + tmp[t] - ts;
    int p0 = off, p1 = off + v0, p2 = p1 + v1, p3 = p2 + v2;
    if (base + 0 < n) { row_ptr[base + 0] = p0; cursor[base + 0] = p0; }
    if (base + 1 < n) { row_ptr[base + 1] = p1; cursor[base + 1] = p1; }
    if (base + 2 < n) { row_ptr[base + 2] = p2; cursor[base + 2] = p2; }
    if (base + 3 < n) { row_ptr[base + 3] = p3; cursor[base + 3] = p3; }
}

__global__ __launch_bounds__(256) void scatter_kernel(const int* __restrict__ rows,
                                                      const int* __restrict__ cols,
                                                      const float* __restrict__ val,
                                                      int* __restrict__ cursor,
                                                      int2* __restrict__ cpack, int E)
{
    int e = blockIdx.x * 256 + threadIdx.x;
    if (e >= E) return;
    int r = rows[e];
    int p = atomicAdd(&cursor[r], 1);
    int2 pk;
    pk.x = cols[e];
    pk.y = __float_as_int(val[e]);
    cpack[p] = pk;
}

// ---------------- MFMA GEMM: Y[M x Nout] = X[M x 128] @ W[Nout x 128]^T (+bias)(+elu) ----
// W pre-converted to bf16. 128x128 block tile, K=128 staged once.
// grid: (ceil(M/128), Nout/128), block 256 (4 waves 2x2).
// LDS stride 136 bf16 (272 B): 16B-aligned, breaks power-of-2 bank stride.

template<int IN_BF16, int OUT_BF16, int ACT>
__global__ __launch_bounds__(256, 2) void gemm_mfma(
    const void* __restrict__ Xv, const bf16* __restrict__ W,
    const float* __restrict__ bias, void* __restrict__ Yv, int M, int Nout)
{
    __shared__ bf16 Xs[128 * 136];
    __shared__ bf16 Ws[128 * 136];
    const int tid = threadIdx.x;
    const int rb = blockIdx.x * 128;
    const int cb = blockIdx.y * 128;

    // stage W tile (bf16x8, cols always full: Nout % 128 == 0)
#pragma unroll
    for (int i = 0; i < 8; ++i) {
        int c = tid + i * 256;                 // 8-elem chunk id
        int r = c >> 4, k8 = (c & 15) << 3;
        *(bf16x8*)&Ws[r * 136 + k8] = *(const bf16x8*)&W[(size_t)(cb + r) * CCH + k8];
    }
    // stage X tile
    if (IN_BF16) {
#pragma unroll
        for (int i = 0; i < 8; ++i) {
            int c = tid + i * 256;
            int r = c >> 4, k8 = (c & 15) << 3;
            int grow = rb + r;
            bf16x8 o = {};
            if (grow < M) o = *(const bf16x8*)&((const bf16*)Xv)[(size_t)grow * CCH + k8];
            *(bf16x8*)&Xs[r * 136 + k8] = o;
        }
    } else {
#pragma unroll
        for (int i = 0; i < 16; ++i) {
            int c = tid + i * 256;
            int r = c >> 5, k4 = (c & 31) << 2;
            int grow = rb + r;
            bf16x4 o = {};
            if (grow < M) {
                float4 xv = *(const float4*)&((const float*)Xv)[(size_t)grow * CCH + k4];
                o[0] = (bf16)xv.x; o[1] = (bf16)xv.y; o[2] = (bf16)xv.z; o[3] = (bf16)xv.w;
            }
            *(bf16x4*)&Xs[r * 136 + k4] = o;
        }
    }
    __syncthreads();

    const int w = tid >> 6, lane = tid & 63;
    const int col16 = lane & 15, quad = lane >> 4;
    const int wm = (w & 1) * 64, wn = (w >> 1) * 64;

    f32x4 acc[4][4] = {};
#pragma unroll
    for (int kk = 0; kk < 4; ++kk) {
        bf16x8 af[4], bfr[4];
#pragma unroll
        for (int mi = 0; mi < 4; ++mi)
            af[mi] = *(const bf16x8*)&Xs[(wm + mi * 16 + col16) * 136 + kk * 32 + quad * 8];
#pragma unroll
        for (int ni = 0; ni < 4; ++ni)
            bfr[ni] = *(const bf16x8*)&Ws[(wn + ni * 16 + col16) * 136 + kk * 32 + quad * 8];
#pragma unroll
        for (int mi = 0; mi < 4; ++mi)
#pragma unroll
            for (int ni = 0; ni < 4; ++ni)
                acc[mi][ni] = __builtin_amdgcn_mfma_f32_16x16x32_bf16(af[mi], bfr[ni], acc[mi][ni], 0, 0, 0);
    }

    // epilogue: D row = quad*4 + reg, col = lane&15
#pragma unroll
    for (int mi = 0; mi < 4; ++mi) {
#pragma unroll
        for (int r = 0; r < 4; ++r) {
            int row = rb + wm + mi * 16 + quad * 4 + r;
            if (row >= M) continue;
#pragma unroll
            for (int ni = 0; ni < 4; ++ni) {
                int col = cb + wn + ni * 16 + col16;
                float v = acc[mi][ni][r];
                if (bias) v += bias[col];
                if (ACT == 1) v = v > 0.f ? v : expm1f(v);   // elu
                if (OUT_BF16) ((bf16*)Yv)[(size_t)row * Nout + col] = (bf16)v;
                else          ((float*)Yv)[(size_t)row * Nout + col] = v;
            }
        }
    }
}

// ---------------- SpMM (CSR gather): 16 lanes/row x bf16x8, 2-edge unroll, packed edges ----
// fused bias+bn+relu; SCORES: also s[row] = out_row . vsp + c0
template<int SCORES>
__global__ __launch_bounds__(256) void spmm_csr_kernel(
    const int* __restrict__ row_ptr, const int2* __restrict__ cpack,
    const bf16* __restrict__ Xin, bf16* __restrict__ Y,
    const float* __restrict__ bvec, const float* __restrict__ sc, const float* __restrict__ sh,
    const float* __restrict__ vsp, const float* __restrict__ c0p, float* __restrict__ scores,
    int Nrow)
{
    int gid = blockIdx.x * 256 + threadIdx.x;
    int row = gid >> 4;
    if (row >= Nrow) return;
    int l8 = (gid & 15) << 3;
    int st = row_ptr[row], en = row_ptr[row + 1];
    float acc[8] = {};
    int j = st;
    for (; j + 2 <= en; j += 2) {
        int2 p0 = cpack[j];
        int2 p1 = cpack[j + 1];
        bf16x8 x0 = *(const bf16x8*)&Xin[(size_t)p0.x * CCH + l8];
        bf16x8 x1 = *(const bf16x8*)&Xin[(size_t)p1.x * CCH + l8];
        float v0 = __int_as_float(p0.y), v1 = __int_as_float(p1.y);
#pragma unroll
        for (int q = 0; q < 8; ++q) acc[q] += v0 * (float)x0[q] + v1 * (float)x1[q];
    }
    if (j < en) {
        int2 p0 = cpack[j];
        bf16x8 x0 = *(const bf16x8*)&Xin[(size_t)p0.x * CCH + l8];
        float v0 = __int_as_float(p0.y);
#pragma unroll
        for (int q = 0; q < 8; ++q) acc[q] += v0 * (float)x0[q];
    }
    float o[8];
    bf16x8 ov;
#pragma unroll
    for (int q = 0; q < 8; ++q) {
        o[q] = fmaxf((acc[q] + bvec[l8 + q]) * sc[l8 + q] + sh[l8 + q], 0.f);
        ov[q] = (bf16)o[q];
    }
    *(bf16x8*)&Y[(size_t)row * CCH + l8] = ov;
    if (SCORES) {
        float p = 0.f;
#pragma unroll
        for (int q = 0; q < 8; ++q) p += o[q] * vsp[l8 + q];
        for (int d = 8; d; d >>= 1) p += __shfl_down(p, d, 16);
        if ((gid & 15) == 0) scores[row] = p + c0p[0];
    }
}

// ---------------- fused pool + attention pool (per segment) ----------------
// phase1: sum rows -> bn2-fold -> relu -> bn3 -> mean; ad = mean . v_d (block-local)
// phase2: softmax over leaky(scores_i + ad), weighted pool of raw X, bn2-fold
__global__ __launch_bounds__(128) void segstage_kernel(
    const bf16* __restrict__ X, const float* __restrict__ sarr, const int* __restrict__ starts,
    const float* __restrict__ sc2, const float* __restrict__ sh2,
    const float* __restrict__ sc3, const float* __restrict__ sh3,
    const float* __restrict__ vd, float* __restrict__ mean, float* __restrict__ upool)
{
    __shared__ float red[2];
    __shared__ float adsh;
    int t = blockIdx.x;
    int c = threadIdx.x;
    int st = starts[t], en = starts[t + 1];
    float sum = 0.f;
    for (int i = st; i < en; ++i) sum += (float)X[(size_t)i * CCH + c];
    float cnt = (float)(en - st);
    float poolb = fmaxf(sum * sc2[c] + cnt * sh2[c], 0.f);
    float mv = poolb * sc3[c] + sh3[c];
    mean[(size_t)t * CCH + c] = mv;
    float p = mv * vd[c];
    for (int o = 32; o; o >>= 1) p += __shfl_down(p, o);
    if ((c & 63) == 0) red[c >> 6] = p;
    __syncthreads();
    if (c == 0) adsh = red[0] + red[1];
    __syncthreads();
    if (en == st) { upool[(size_t)t * CCH + c] = 0.f; return; }
    float adt = adsh;
    float lm = -3.0e38f;
    for (int i = st + c; i < en; i += 128) {
        float a = sarr[i] + adt;
        a = a > 0.f ? a : 0.01f * a;
        lm = fmaxf(lm, a);
    }
    for (int o = 32; o; o >>= 1) lm = fmaxf(lm, __shfl_down(lm, o));
    if ((c & 63) == 0) red[c >> 6] = lm;
    __syncthreads();
    float m = fmaxf(red[0], red[1]);
    float u = 0.f, den = 0.f;
    for (int i = st; i < en; ++i) {
        float a = sarr[i] + adt;
        a = a > 0.f ? a : 0.01f * a;
        float e = __expf(a - m);
        den += e;
        u += e * (float)X[(size_t)i * CCH + c];
    }
    upool[(size_t)t * CCH + c] = (u / den) * sc2[c] + sh2[c];
}

// GRU combine + relu + bn(base+2); optional fused next-stage scores
template<int OUT_BF16, int SCORES>
__global__ __launch_bounds__(256) void gru_kernel(
    const float* __restrict__ giM, const float* __restrict__ ghM, const float* __restrict__ mean,
    const float* __restrict__ sc4, const float* __restrict__ sh4,
    void* __restrict__ out,
    const float* __restrict__ vsp2, const float* __restrict__ c02, float* __restrict__ scores,
    int total)
{
    __shared__ float sred[4];
    int idx = blockIdx.x * 256 + threadIdx.x;
    bool ok = idx < total;
    int t = idx >> 7, c = idx & 127;
    float o = 0.f;
    if (ok) {
        size_t b = (size_t)t * G3;
        float ir = giM[b + c],  iz = giM[b + 128 + c], inn = giM[b + 256 + c];
        float hr = ghM[b + c],  hz = ghM[b + 128 + c], hn  = ghM[b + 256 + c];
        float r = 1.f / (1.f + __expf(-(ir + hr)));
        float z = 1.f / (1.f + __expf(-(iz + hz)));
        float nn = tanhf(inn + r * hn);
        float h = (1.f - z) * nn + z * mean[idx];
        h = fmaxf(h, 0.f);
        o = h * sc4[c] + sh4[c];
        if (OUT_BF16) ((bf16*)out)[idx] = (bf16)o;
        else          ((float*)out)[idx] = o;
    }
    if (SCORES) {
        float p = ok ? o * vsp2[c] : 0.f;
        for (int d = 32; d; d >>= 1) p += __shfl_down(p, d);
        int w = threadIdx.x >> 6;
        if ((threadIdx.x & 63) == 0) sred[w] = p;
        __syncthreads();
        if (threadIdx.x == 0 && ok)   scores[t] = sred[0] + sred[1] + c02[0];
        if (threadIdx.x == 128 && ok) scores[t] = sred[2] + sred[3] + c02[0];
    }
}

// predictor
__global__ __launch_bounds__(64) void pred_kernel(
    const float* __restrict__ mol, const float* __restrict__ pW1, const float* __restrict__ pb1,
    const float* __restrict__ pW2, const float* __restrict__ pb2, float* __restrict__ out)
{
    __shared__ float row[CCH];
    int m = blockIdx.x;
    int j = threadIdx.x;
    row[j] = mol[(size_t)m * CCH + j];
    row[j + 64] = mol[(size_t)m * CCH + 64 + j];
    __syncthreads();
    float h = pb1[j];
#pragma unroll
    for (int k = 0; k < CCH; ++k) h += row[k] * pW1[j * CCH + k];
    h = fmaxf(h, 0.f);
    float p = h * pW2[j];
    for (int o = 32; o; o >>= 1) p += __shfl_down(p, o);
    if (j == 0) out[m] = p + pb2[0];
}

// ---------------- host ----------------

extern "C" void kernel_launch(void* const* d_in, const int* in_sizes, int n_in,
                              void* d_out, int out_size, void* d_ws, size_t ws_size,
                              hipStream_t stream)
{
    (void)n_in; (void)ws_size;
    const float* node_attr      = (const float*)d_in[0];
    const int*   adj_index      = (const int*)  d_in[1];
    const float* adj_value      = (const float*)d_in[2];
    const int*   tt_node_batch  = (const int*)  d_in[3];
    const int*   tt_graph_batch = (const int*)  d_in[4];
    const float* W_gcn    = (const float*)d_in[5];
    const float* b_gcn    = (const float*)d_in[6];
    const float* bn_gamma = (const float*)d_in[7];
    const float* bn_beta  = (const float*)d_in[8];
    const float* bn_mean  = (const float*)d_in[9];
    const float* bn_var   = (const float*)d_in[10];
    const float* gat_Wsrc = (const float*)d_in[11];
    const float* gat_Wdst = (const float*)d_in[12];
    const float* gat_asrc = (const float*)d_in[13];
    const float* gat_adst = (const float*)d_in[14];
    const float* gat_bias = (const float*)d_in[15];
    const float* gru_Wih  = (const float*)d_in[16];
    const float* gru_Whh  = (const float*)d_in[17];
    const float* gru_bih  = (const float*)d_in[18];
    const float* gru_bhh  = (const float*)d_in[19];
    const float* pW1 = (const float*)d_in[20];
    const float* pb1 = (const float*)d_in[21];
    const float* pW2 = (const float*)d_in[22];
    const float* pb2 = (const float*)d_in[23];

    const int E    = in_sizes[2];
    const int N    = in_sizes[3];
    const int NTT  = in_sizes[4];
    const int NMOL = out_size;

    const int* adj_rows = adj_index;
    const int* adj_cols = adj_index + E;

    // ---- workspace carve ----
    char* wsb = (char*)d_ws;
    size_t off = 0;
    auto carve = [&](size_t bytes) -> char* {
        char* p = wsb + off;
        off = (off + bytes + 255) & ~(size_t)255;
        return p;
    };
    bf16* bufB = (bf16*)carve((size_t)N * CCH * 2);    // gemm out -> spmm in
    bf16* bufA = (bf16*)carve((size_t)N * CCH * 2);    // spmm out -> gemm2 in / stage X
    bf16* tt   = (bf16*)carve((size_t)NTT * CCH * 2);
    float* mol  = (float*)carve((size_t)NMOL * CCH * 4);
    float* mean  = (float*)carve((size_t)NTT * CCH * 4);
    float* upool = (float*)carve((size_t)NTT * CCH * 4);
    float* gbuf  = (float*)carve((size_t)NTT * CCH * 4);
    float* giM   = (float*)carve((size_t)NTT * G3 * 4);
    float* ghM   = (float*)carve((size_t)NTT * G3 * 4);
    float* scores = (float*)carve((size_t)N * 4);
    int* starts_tt  = (int*)carve((size_t)(NTT + 1) * 4);
    int* starts_mol = (int*)carve((size_t)(NMOL + 1) * 4);
    float* bnsc = (float*)carve(8 * CCH * 4);
    float* bnsh = (float*)carve(8 * CCH * 4);
    float* vsp  = (float*)carve(2 * CCH * 4);
    float* vd   = (float*)carve(2 * CCH * 4);
    float* c0   = (float*)carve(2 * 4);
    bf16* Wgcnb = (bf16*)carve((size_t)2 * CCH * CCH * 2);
    bf16* Wsrcb = (bf16*)carve((size_t)2 * CCH * CCH * 2);
    bf16* Wihb  = (bf16*)carve((size_t)2 * G3 * CCH * 2);
    bf16* Whhb  = (bf16*)carve((size_t)2 * G3 * CCH * 2);
    int*   counts  = (int*)carve((size_t)N * 4);       // reused as scatter cursor
    int*   row_ptr = (int*)carve((size_t)(N + 1) * 4);
    int*   bsum    = (int*)carve(256 * 4);
    int2*  cpack   = (int2*)carve((size_t)E * 8);

    // ---- prep ----
    bnprep_kernel<<<8, 128, 0, stream>>>(bn_gamma, bn_beta, bn_mean, bn_var, bnsc, bnsh);
    matvec_prep_kernel<<<4, 128, 0, stream>>>(gat_Wsrc, gat_Wdst, gat_asrc, gat_adst,
                                              bnsc, bnsh, vsp, vd, c0);
    {
        int n4;
        n4 = 2 * CCH * CCH / 4; f2b_kernel<<<(n4 + 255) / 256, 256, 0, stream>>>(W_gcn, Wgcnb, n4);
        n4 = 2 * CCH * CCH / 4; f2b_kernel<<<(n4 + 255) / 256, 256, 0, stream>>>(gat_Wsrc, Wsrcb, n4);
        n4 = 2 * G3 * CCH / 4;  f2b_kernel<<<(n4 + 255) / 256, 256, 0, stream>>>(gru_Wih, Wihb, n4);
        n4 = 2 * G3 * CCH / 4;  f2b_kernel<<<(n4 + 255) / 256, 256, 0, stream>>>(gru_Whh, Whhb, n4);
    }
    bounds_kernel<<<(NTT + 1 + 255) / 256, 256, 0, stream>>>(tt_node_batch, N, NTT, starts_tt);
    bounds_kernel<<<(NMOL + 1 + 255) / 256, 256, 0, stream>>>(tt_graph_batch, NTT, NMOL, starts_mol);

    // ---- CSR build (once; shared by both GCN layers) ----
    const int nblk = (N + 1023) / 1024;
    hipMemsetAsync(counts, 0, (size_t)N * 4, stream);
    hist_kernel<<<(E + 255) / 256, 256, 0, stream>>>(adj_rows, counts, E);
    scan_reduce_kernel<<<nblk, 256, 0, stream>>>(counts, bsum, N);
    scan_top_kernel<<<1, 256, 0, stream>>>(bsum, nblk, row_ptr, N, E);
    scan_down_kernel<<<nblk, 256, 0, stream>>>(counts, bsum, row_ptr, counts, N);
    scatter_kernel<<<(E + 255) / 256, 256, 0, stream>>>(adj_rows, adj_cols, adj_value,
                                                        counts, cpack, E);

    // ---- GCN x2 ----
    dim3 gg((N + 127) / 128, 1);
    const int spmm_blocks = ((size_t)N * 16 + 255) / 256;
    gemm_mfma<0, 1, 0><<<gg, 256, 0, stream>>>(node_attr, Wgcnb, nullptr, bufB, N, CCH);
    spmm_csr_kernel<0><<<spmm_blocks, 256, 0, stream>>>(
        row_ptr, cpack, bufB, bufA, b_gcn, bnsc, bnsh, nullptr, nullptr, nullptr, N);
    gemm_mfma<1, 1, 0><<<gg, 256, 0, stream>>>(bufA, Wgcnb + CCH * CCH, nullptr, bufB, N, CCH);
    // layer-2 spmm also emits tt-stage attention scores
    spmm_csr_kernel<1><<<spmm_blocks, 256, 0, stream>>>(
        row_ptr, cpack, bufB, bufA, b_gcn + CCH, bnsc + CCH, bnsh + CCH,
        vsp, c0, scores, N);

    // ---- tt stage: N -> NTT (bf16 out, fused mol-stage scores) ----
    {
        int bnb = 2, gi = 0, nseg = NTT;
        segstage_kernel<<<nseg, 128, 0, stream>>>(bufA, scores, starts_tt,
            bnsc + bnb * CCH, bnsh + bnb * CCH, bnsc + (bnb + 1) * CCH, bnsh + (bnb + 1) * CCH,
            vd + gi * CCH, mean, upool);
        dim3 g1((nseg + 127) / 128, 1);
        gemm_mfma<0, 0, 1><<<g1, 256, 0, stream>>>(upool, Wsrcb + gi * CCH * CCH,
                                                   gat_bias + gi * CCH, gbuf, nseg, CCH);
        dim3 g2((nseg + 127) / 128, 3);
        gemm_mfma<0, 0, 0><<<g2, 256, 0, stream>>>(gbuf, Wihb + gi * G3 * CCH,
                                                   gru_bih + gi * G3, giM, nseg, G3);
        gemm_mfma<0, 0, 0><<<g2, 256, 0, stream>>>(mean, Whhb + gi * G3 * CCH,
                                                   gru_bhh + gi * G3, ghM, nseg, G3);
        // writes tt (bf16) and scores[0..NTT) for the mol stage (gi=1 fold)
        gru_kernel<1, 1><<<(nseg * CCH + 255) / 256, 256, 0, stream>>>(giM, ghM, mean,
            bnsc + (bnb + 2) * CCH, bnsh + (bnb + 2) * CCH, tt,
            vsp + CCH, c0 + 1, scores, nseg * CCH);
    }

    // ---- mol stage: NTT -> NMOL (fp32 out) ----
    {
        int bnb = 5, gi = 1, nseg = NMOL;
        segstage_kernel<<<nseg, 128, 0, stream>>>(tt, scores, starts_mol,
            bnsc + bnb * CCH, bnsh + bnb * CCH, bnsc + (bnb + 1) * CCH, bnsh + (bnb + 1) * CCH,
            vd + gi * CCH, mean, upool);
        dim3 g1((nseg + 127) / 128, 1);
        gemm_mfma<0, 0, 1><<<g1, 256, 0, stream>>>(upool, Wsrcb + gi * CCH * CCH,
                                                   gat_bias + gi * CCH, gbuf, nseg, CCH);
        dim3 g2((nseg + 127) / 128, 3);
        gemm_mfma<0, 0, 0><<<g2, 256, 0, stream>>>(gbuf, Wihb + gi * G3 * CCH,
                                                   gru_bih + gi * G3, giM, nseg, G3);
        gemm_mfma<0, 0, 0><<<g2, 256, 0, stream>>>(mean, Whhb + gi * G3 * CCH,
                                                   gru_bhh + gi * G3, ghM, nseg, G3);
        gru_kernel<0, 0><<<(nseg * CCH + 255) / 256, 256, 0, stream>>>(giM, ghM, mean,
            bnsc + (bnb + 2) * CCH, bnsh + (bnb + 2) * CCH, mol,
            nullptr, nullptr, nullptr, nseg * CCH);
    }

    // ---- predictor ----
    pred_kernel<<<NMOL, 64, 0, stream>>>(mol, pW1, pb1, pW2, pb2, (float*)d_out);
}

// Round 5
// 688.574 us; speedup vs baseline: 9.1256x; 1.1583x over previous
//
#include <hip/hip_runtime.h>
#include <math.h>

#define CCH 128
#define G3  384
#define BN_EPS 1e-5f
#define BSH 9              // bucket shift: 512 rows/bucket
#define BROWS 512

typedef __bf16 bf16;
typedef __bf16 bf16x2 __attribute__((ext_vector_type(2)));
typedef __bf16 bf16x4 __attribute__((ext_vector_type(4)));
typedef __bf16 bf16x8 __attribute__((ext_vector_type(8)));
typedef float f32x4 __attribute__((ext_vector_type(4)));

// ---------------- small prep kernels ----------------

__global__ void bnprep_kernel(const float* __restrict__ g, const float* __restrict__ b,
                              const float* __restrict__ m, const float* __restrict__ v,
                              float* __restrict__ sc, float* __restrict__ sh)
{
    int idx = blockIdx.x * 128 + threadIdx.x;   // 8*128 total
    float s = g[idx] / sqrtf(v[idx] + BN_EPS);
    sc[idx] = s;
    sh[idx] = b[idx] - m[idx] * s;
}

// fp32 -> bf16 weight conversion (n4 = n/4)
__global__ void f2b_kernel(const float* __restrict__ in, bf16* __restrict__ out, int n4)
{
    int i = blockIdx.x * 256 + threadIdx.x;
    if (i >= n4) return;
    float4 v = ((const float4*)in)[i];
    bf16x4 o = { (bf16)v.x, (bf16)v.y, (bf16)v.z, (bf16)v.w };
    ((bf16x4*)out)[i] = o;
}

// v_s = Wsrc^T a_src (folded with bn2 scale, plus c0 = sum(shift*v)), v_d = Wdst^T a_dst
__global__ __launch_bounds__(128) void matvec_prep_kernel(
    const float* __restrict__ Wsrc, const float* __restrict__ Wdst,
    const float* __restrict__ asrc, const float* __restrict__ adst,
    const float* __restrict__ bnsc, const float* __restrict__ bnsh,
    float* __restrict__ vsp, float* __restrict__ vd, float* __restrict__ c0)
{
    __shared__ float red[2];
    int s = blockIdx.x >> 1, which = blockIdx.x & 1;
    int k = threadIdx.x;
    const float* W = (which ? Wdst : Wsrc) + s * CCH * CCH;
    const float* a = (which ? adst : asrc) + s * CCH;
    float acc = 0.f;
    for (int j = 0; j < CCH; ++j) acc += W[j * CCH + k] * a[j];
    if (which) {
        vd[s * CCH + k] = acc;
    } else {
        int l = 2 + 3 * s;   // bn index of the stage's input bn
        vsp[s * CCH + k] = acc * bnsc[l * CCH + k];
        float p = bnsh[l * CCH + k] * acc;
        for (int o = 32; o; o >>= 1) p += __shfl_down(p, o);
        if ((k & 63) == 0) red[k >> 6] = p;
        __syncthreads();
        if (k == 0) c0[s] = red[0] + red[1];
    }
}

// starts[s] = lower_bound(batch, s); batch sorted. s in [0, nseg]
__global__ void bounds_kernel(const int* __restrict__ batch, int n, int nseg, int* __restrict__ starts)
{
    int s = blockIdx.x * 256 + threadIdx.x;
    if (s > nseg) return;
    int lo = 0, hi = n;
    while (lo < hi) {
        int mid = (lo + hi) >> 1;
        if (batch[mid] < s) lo = mid + 1; else hi = mid;
    }
    starts[s] = lo;
}

// ---------------- CSR build via bucket counting sort ----------------
// buckets of 512 rows; NB = ceil(N/512) <= 512.

__global__ __launch_bounds__(256) void bucket_hist_kernel(const int* __restrict__ rows,
                                                          int* __restrict__ bhist, int E)
{
    __shared__ int h[512];
    int t = threadIdx.x;
    h[t] = 0; h[t + 256] = 0;
    __syncthreads();
    int base = blockIdx.x * 4096;
#pragma unroll
    for (int i = 0; i < 16; ++i) {
        int e = base + i * 256 + t;
        if (e < E) atomicAdd(&h[rows[e] >> BSH], 1);
    }
    __syncthreads();
    if (h[t]) atomicAdd(&bhist[t], h[t]);
    if (h[t + 256]) atomicAdd(&bhist[t + 256], h[t + 256]);
}

// single block: exclusive scan of bhist[512] -> boff (+bcur copy); row_ptr[N]=E
__global__ __launch_bounds__(256) void bucket_scan_kernel(const int* __restrict__ bhist,
                                                          int* __restrict__ boff, int* __restrict__ bcur,
                                                          int* __restrict__ row_ptr, int NB, int N, int E)
{
    __shared__ int h[512], sx[512], wt[4];
    int t = threadIdx.x;
    h[t] = bhist[t]; h[t + 256] = bhist[t + 256];
    __syncthreads();
    int v0 = h[2 * t], v1 = h[2 * t + 1];
    int s = v0 + v1, incl = s;
    for (int o = 1; o < 64; o <<= 1) { int u = __shfl_up(incl, o); if ((t & 63) >= o) incl += u; }
    if ((t & 63) == 63) wt[t >> 6] = incl;
    __syncthreads();
    int woff = 0, w = t >> 6;
    for (int i = 0; i < w; ++i) woff += wt[i];
    int excl = woff + incl - s;
    sx[2 * t] = excl; sx[2 * t + 1] = excl + v0;
    __syncthreads();
    if (t < NB)       { boff[t] = sx[t];       bcur[t] = sx[t]; }
    if (t + 256 < NB) { boff[t + 256] = sx[t + 256]; bcur[t + 256] = sx[t + 256]; }
    if (t == 0) { boff[NB] = E; row_ptr[N] = E; }
}

// each block counting-sorts a 4096-edge chunk by bucket in LDS, flushes contiguous runs
__global__ __launch_bounds__(256) void bucket_bin_kernel(
    const int* __restrict__ rows, const int* __restrict__ cols, const float* __restrict__ val,
    int* __restrict__ bcur, int* __restrict__ brow, int2* __restrict__ bcv, int E)
{
    __shared__ int hist[512], sx[512], cnt[512], gbase[512], wt[4];
    __shared__ int mrow[4096];
    __shared__ int2 mcv[4096];
    int t = threadIdx.x;
    hist[t] = 0; hist[t + 256] = 0; cnt[t] = 0; cnt[t + 256] = 0;
    __syncthreads();
    int base = blockIdx.x * 4096;
    int r[16];
#pragma unroll
    for (int i = 0; i < 16; ++i) {
        int e = base + i * 256 + t;
        r[i] = (e < E) ? rows[e] : -1;
        if (r[i] >= 0) atomicAdd(&hist[r[i] >> BSH], 1);
    }
    __syncthreads();
    int v0 = hist[2 * t], v1 = hist[2 * t + 1];
    int s = v0 + v1, incl = s;
    for (int o = 1; o < 64; o <<= 1) { int u = __shfl_up(incl, o); if ((t & 63) >= o) incl += u; }
    if ((t & 63) == 63) wt[t >> 6] = incl;
    __syncthreads();
    int woff = 0, w = t >> 6;
    for (int i = 0; i < w; ++i) woff += wt[i];
    int excl = woff + incl - s;
    sx[2 * t] = excl; sx[2 * t + 1] = excl + v0;
    __syncthreads();
    for (int b = t; b < 512; b += 256)
        if (hist[b]) gbase[b] = atomicAdd(&bcur[b], hist[b]);
    __syncthreads();
#pragma unroll
    for (int i = 0; i < 16; ++i) {
        if (r[i] < 0) continue;
        int e = base + i * 256 + t;
        int b = r[i] >> BSH;
        int p = atomicAdd(&cnt[b], 1);
        int loc = sx[b] + p;
        mrow[loc] = r[i];
        int2 cv; cv.x = cols[e]; cv.y = __float_as_int(val[e]);
        mcv[loc] = cv;
    }
    __syncthreads();
    int Mv = sx[511] + hist[511];
    for (int loc = t; loc < Mv; loc += 256) {
        int b = mrow[loc] >> BSH;
        int g = gbase[b] + (loc - sx[b]);
        brow[g] = mrow[loc];
        bcv[g]  = mcv[loc];
    }
}

// one block per bucket: row-hist in LDS, scan -> row_ptr, place edges into exact CSR slots
__global__ __launch_bounds__(256) void bucket_place_kernel(
    const int* __restrict__ brow, const int2* __restrict__ bcv,
    const int* __restrict__ boff, int* __restrict__ row_ptr,
    int2* __restrict__ cpack, int N)
{
    __shared__ int rcnt[512], sx[512], wt[4];
    int b = blockIdx.x;
    int t = threadIdx.x;
    rcnt[t] = 0; rcnt[t + 256] = 0;
    __syncthreads();
    int rbase = b << BSH;
    int rn = min(BROWS, N - rbase);
    int lo = boff[b], hi = boff[b + 1];
    for (int p = lo + t; p < hi; p += 256)
        atomicAdd(&rcnt[brow[p] - rbase], 1);
    __syncthreads();
    int v0 = rcnt[2 * t], v1 = rcnt[2 * t + 1];
    int s = v0 + v1, incl = s;
    for (int o = 1; o < 64; o <<= 1) { int u = __shfl_up(incl, o); if ((t & 63) >= o) incl += u; }
    if ((t & 63) == 63) wt[t >> 6] = incl;
    __syncthreads();
    int woff = 0, w = t >> 6;
    for (int i = 0; i < w; ++i) woff += wt[i];
    int excl = woff + incl - s;
    sx[2 * t] = excl; sx[2 * t + 1] = excl + v0;
    __syncthreads();
    if (t < rn)       row_ptr[rbase + t] = lo + sx[t];
    if (t + 256 < rn) row_ptr[rbase + t + 256] = lo + sx[t + 256];
    __syncthreads();
    sx[t] += lo; sx[t + 256] += lo;      // convert to absolute cursors
    __syncthreads();
    for (int p = lo + t; p < hi; p += 256) {
        int r = brow[p];
        int slot = atomicAdd(&sx[r - rbase], 1);
        cpack[slot] = bcv[p];
    }
}

// ---------------- MFMA GEMM: Y[M x Nout] = X[M x 128] @ W[Nout x 128]^T (+bias)(+elu) ----
// W pre-converted to bf16. 128x128 block tile, K=128 staged once.
// grid: (ceil(M/128), Nout/128), block 256 (4 waves 2x2). LDS stride 136 bf16.

template<int IN_BF16, int OUT_BF16, int ACT>
__global__ __launch_bounds__(256, 2) void gemm_mfma(
    const void* __restrict__ Xv, const bf16* __restrict__ W,
    const float* __restrict__ bias, void* __restrict__ Yv, int M, int Nout)
{
    __shared__ bf16 Xs[128 * 136];
    __shared__ bf16 Ws[128 * 136];
    const int tid = threadIdx.x;
    const int rb = blockIdx.x * 128;
    const int cb = blockIdx.y * 128;

#pragma unroll
    for (int i = 0; i < 8; ++i) {
        int c = tid + i * 256;                 // 8-elem chunk id
        int r = c >> 4, k8 = (c & 15) << 3;
        *(bf16x8*)&Ws[r * 136 + k8] = *(const bf16x8*)&W[(size_t)(cb + r) * CCH + k8];
    }
    if (IN_BF16) {
#pragma unroll
        for (int i = 0; i < 8; ++i) {
            int c = tid + i * 256;
            int r = c >> 4, k8 = (c & 15) << 3;
            int grow = rb + r;
            bf16x8 o = {};
            if (grow < M) o = *(const bf16x8*)&((const bf16*)Xv)[(size_t)grow * CCH + k8];
            *(bf16x8*)&Xs[r * 136 + k8] = o;
        }
    } else {
#pragma unroll
        for (int i = 0; i < 16; ++i) {
            int c = tid + i * 256;
            int r = c >> 5, k4 = (c & 31) << 2;
            int grow = rb + r;
            bf16x4 o = {};
            if (grow < M) {
                float4 xv = *(const float4*)&((const float*)Xv)[(size_t)grow * CCH + k4];
                o[0] = (bf16)xv.x; o[1] = (bf16)xv.y; o[2] = (bf16)xv.z; o[3] = (bf16)xv.w;
            }
            *(bf16x4*)&Xs[r * 136 + k4] = o;
        }
    }
    __syncthreads();

    const int w = tid >> 6, lane = tid & 63;
    const int col16 = lane & 15, quad = lane >> 4;
    const int wm = (w & 1) * 64, wn = (w >> 1) * 64;

    f32x4 acc[4][4] = {};
#pragma unroll
    for (int kk = 0; kk < 4; ++kk) {
        bf16x8 af[4], bfr[4];
#pragma unroll
        for (int mi = 0; mi < 4; ++mi)
            af[mi] = *(const bf16x8*)&Xs[(wm + mi * 16 + col16) * 136 + kk * 32 + quad * 8];
#pragma unroll
        for (int ni = 0; ni < 4; ++ni)
            bfr[ni] = *(const bf16x8*)&Ws[(wn + ni * 16 + col16) * 136 + kk * 32 + quad * 8];
#pragma unroll
        for (int mi = 0; mi < 4; ++mi)
#pragma unroll
            for (int ni = 0; ni < 4; ++ni)
                acc[mi][ni] = __builtin_amdgcn_mfma_f32_16x16x32_bf16(af[mi], bfr[ni], acc[mi][ni], 0, 0, 0);
    }

#pragma unroll
    for (int mi = 0; mi < 4; ++mi) {
#pragma unroll
        for (int r = 0; r < 4; ++r) {
            int row = rb + wm + mi * 16 + quad * 4 + r;
            if (row >= M) continue;
#pragma unroll
            for (int ni = 0; ni < 4; ++ni) {
                int col = cb + wn + ni * 16 + col16;
                float v = acc[mi][ni][r];
                if (bias) v += bias[col];
                if (ACT == 1) v = v > 0.f ? v : expm1f(v);   // elu
                if (OUT_BF16) ((bf16*)Yv)[(size_t)row * Nout + col] = (bf16)v;
                else          ((float*)Yv)[(size_t)row * Nout + col] = v;
            }
        }
    }
}

// ---------------- SpMM (CSR gather): 16 lanes/row x bf16x8, 2-edge unroll, packed edges ----
template<int SCORES>
__global__ __launch_bounds__(256) void spmm_csr_kernel(
    const int* __restrict__ row_ptr, const int2* __restrict__ cpack,
    const bf16* __restrict__ Xin, bf16* __restrict__ Y,
    const float* __restrict__ bvec, const float* __restrict__ sc, const float* __restrict__ sh,
    const float* __restrict__ vsp, const float* __restrict__ c0p, float* __restrict__ scores,
    int Nrow)
{
    int gid = blockIdx.x * 256 + threadIdx.x;
    int row = gid >> 4;
    if (row >= Nrow) return;
    int l8 = (gid & 15) << 3;
    int st = row_ptr[row], en = row_ptr[row + 1];
    float acc[8] = {};
    int j = st;
    for (; j + 2 <= en; j += 2) {
        int2 p0 = cpack[j];
        int2 p1 = cpack[j + 1];
        bf16x8 x0 = *(const bf16x8*)&Xin[(size_t)p0.x * CCH + l8];
        bf16x8 x1 = *(const bf16x8*)&Xin[(size_t)p1.x * CCH + l8];
        float v0 = __int_as_float(p0.y), v1 = __int_as_float(p1.y);
#pragma unroll
        for (int q = 0; q < 8; ++q) acc[q] += v0 * (float)x0[q] + v1 * (float)x1[q];
    }
    if (j < en) {
        int2 p0 = cpack[j];
        bf16x8 x0 = *(const bf16x8*)&Xin[(size_t)p0.x * CCH + l8];
        float v0 = __int_as_float(p0.y);
#pragma unroll
        for (int q = 0; q < 8; ++q) acc[q] += v0 * (float)x0[q];
    }
    float o[8];
    bf16x8 ov;
#pragma unroll
    for (int q = 0; q < 8; ++q) {
        o[q] = fmaxf((acc[q] + bvec[l8 + q]) * sc[l8 + q] + sh[l8 + q], 0.f);
        ov[q] = (bf16)o[q];
    }
    *(bf16x8*)&Y[(size_t)row * CCH + l8] = ov;
    if (SCORES) {
        float p = 0.f;
#pragma unroll
        for (int q = 0; q < 8; ++q) p += o[q] * vsp[l8 + q];
        for (int d = 8; d; d >>= 1) p += __shfl_down(p, d, 16);
        if ((gid & 15) == 0) scores[row] = p + c0p[0];
    }
}

// ---------------- fused pool + attention pool (per segment) ----------------
__global__ __launch_bounds__(128) void segstage_kernel(
    const bf16* __restrict__ X, const float* __restrict__ sarr, const int* __restrict__ starts,
    const float* __restrict__ sc2, const float* __restrict__ sh2,
    const float* __restrict__ sc3, const float* __restrict__ sh3,
    const float* __restrict__ vd, float* __restrict__ mean, float* __restrict__ upool)
{
    __shared__ float red[2];
    __shared__ float adsh;
    int t = blockIdx.x;
    int c = threadIdx.x;
    int st = starts[t], en = starts[t + 1];
    float sum = 0.f;
    for (int i = st; i < en; ++i) sum += (float)X[(size_t)i * CCH + c];
    float cnt = (float)(en - st);
    float poolb = fmaxf(sum * sc2[c] + cnt * sh2[c], 0.f);
    float mv = poolb * sc3[c] + sh3[c];
    mean[(size_t)t * CCH + c] = mv;
    float p = mv * vd[c];
    for (int o = 32; o; o >>= 1) p += __shfl_down(p, o);
    if ((c & 63) == 0) red[c >> 6] = p;
    __syncthreads();
    if (c == 0) adsh = red[0] + red[1];
    __syncthreads();
    if (en == st) { upool[(size_t)t * CCH + c] = 0.f; return; }
    float adt = adsh;
    float lm = -3.0e38f;
    for (int i = st + c; i < en; i += 128) {
        float a = sarr[i] + adt;
        a = a > 0.f ? a : 0.01f * a;
        lm = fmaxf(lm, a);
    }
    for (int o = 32; o; o >>= 1) lm = fmaxf(lm, __shfl_down(lm, o));
    if ((c & 63) == 0) red[c >> 6] = lm;
    __syncthreads();
    float m = fmaxf(red[0], red[1]);
    float u = 0.f, den = 0.f;
    for (int i = st; i < en; ++i) {
        float a = sarr[i] + adt;
        a = a > 0.f ? a : 0.01f * a;
        float e = __expf(a - m);
        den += e;
        u += e * (float)X[(size_t)i * CCH + c];
    }
    upool[(size_t)t * CCH + c] = (u / den) * sc2[c] + sh2[c];
}

// GRU combine + relu + bn(base+2); optional fused next-stage scores
template<int OUT_BF16, int SCORES>
__global__ __launch_bounds__(256) void gru_kernel(
    const float* __restrict__ giM, const float* __restrict__ ghM, const float* __restrict__ mean,
    const float* __restrict__ sc4, const float* __restrict__ sh4,
    void* __restrict__ out,
    const float* __restrict__ vsp2, const float* __restrict__ c02, float* __restrict__ scores,
    int total)
{
    __shared__ float sred[4];
    int idx = blockIdx.x * 256 + threadIdx.x;
    bool ok = idx < total;
    int t = idx >> 7, c = idx & 127;
    float o = 0.f;
    if (ok) {
        size_t b = (size_t)t * G3;
        float ir = giM[b + c],  iz = giM[b + 128 + c], inn = giM[b + 256 + c];
        float hr = ghM[b + c],  hz = ghM[b + 128 + c], hn  = ghM[b + 256 + c];
        float r = 1.f / (1.f + __expf(-(ir + hr)));
        float z = 1.f / (1.f + __expf(-(iz + hz)));
        float nn = tanhf(inn + r * hn);
        float h = (1.f - z) * nn + z * mean[idx];
        h = fmaxf(h, 0.f);
        o = h * sc4[c] + sh4[c];
        if (OUT_BF16) ((bf16*)out)[idx] = (bf16)o;
        else          ((float*)out)[idx] = o;
    }
    if (SCORES) {
        float p = ok ? o * vsp2[c] : 0.f;
        for (int d = 32; d; d >>= 1) p += __shfl_down(p, d);
        int w = threadIdx.x >> 6;
        if ((threadIdx.x & 63) == 0) sred[w] = p;
        __syncthreads();
        if (threadIdx.x == 0 && ok)   scores[t] = sred[0] + sred[1] + c02[0];
        if (threadIdx.x == 128 && ok) scores[t] = sred[2] + sred[3] + c02[0];
    }
}

// predictor
__global__ __launch_bounds__(64) void pred_kernel(
    const float* __restrict__ mol, const float* __restrict__ pW1, const float* __restrict__ pb1,
    const float* __restrict__ pW2, const float* __restrict__ pb2, float* __restrict__ out)
{
    __shared__ float row[CCH];
    int m = blockIdx.x;
    int j = threadIdx.x;
    row[j] = mol[(size_t)m * CCH + j];
    row[j + 64] = mol[(size_t)m * CCH + 64 + j];
    __syncthreads();
    float h = pb1[j];
#pragma unroll
    for (int k = 0; k < CCH; ++k) h += row[k] * pW1[j * CCH + k];
    h = fmaxf(h, 0.f);
    float p = h * pW2[j];
    for (int o = 32; o; o >>= 1) p += __shfl_down(p, o);
    if (j == 0) out[m] = p + pb2[0];
}

// ---------------- host ----------------

extern "C" void kernel_launch(void* const* d_in, const int* in_sizes, int n_in,
                              void* d_out, int out_size, void* d_ws, size_t ws_size,
                              hipStream_t stream)
{
    (void)n_in; (void)ws_size;
    const float* node_attr      = (const float*)d_in[0];
    const int*   adj_index      = (const int*)  d_in[1];
    const float* adj_value      = (const float*)d_in[2];
    const int*   tt_node_batch  = (const int*)  d_in[3];
    const int*   tt_graph_batch = (const int*)  d_in[4];
    const float* W_gcn    = (const float*)d_in[5];
    const float* b_gcn    = (const float*)d_in[6];
    const float* bn_gamma = (const float*)d_in[7];
    const float* bn_beta  = (const float*)d_in[8];
    const float* bn_mean  = (const float*)d_in[9];
    const float* bn_var   = (const float*)d_in[10];
    const float* gat_Wsrc = (const float*)d_in[11];
    const float* gat_Wdst = (const float*)d_in[12];
    const float* gat_asrc = (const float*)d_in[13];
    const float* gat_adst = (const float*)d_in[14];
    const float* gat_bias = (const float*)d_in[15];
    const float* gru_Wih  = (const float*)d_in[16];
    const float* gru_Whh  = (const float*)d_in[17];
    const float* gru_bih  = (const float*)d_in[18];
    const float* gru_bhh  = (const float*)d_in[19];
    const float* pW1 = (const float*)d_in[20];
    const float* pb1 = (const float*)d_in[21];
    const float* pW2 = (const float*)d_in[22];
    const float* pb2 = (const float*)d_in[23];

    const int E    = in_sizes[2];
    const int N    = in_sizes[3];
    const int NTT  = in_sizes[4];
    const int NMOL = out_size;
    const int NB   = (N + BROWS - 1) >> BSH;

    const int* adj_rows = adj_index;
    const int* adj_cols = adj_index + E;

    // ---- workspace carve ----
    char* wsb = (char*)d_ws;
    size_t off = 0;
    auto carve = [&](size_t bytes) -> char* {
        char* p = wsb + off;
        off = (off + bytes + 255) & ~(size_t)255;
        return p;
    };
    bf16* bufB = (bf16*)carve((size_t)N * CCH * 2);    // gemm out -> spmm in
    bf16* bufA = (bf16*)carve((size_t)N * CCH * 2);    // spmm out -> gemm2 in / stage X
    bf16* tt   = (bf16*)carve((size_t)NTT * CCH * 2);
    float* mol  = (float*)carve((size_t)NMOL * CCH * 4);
    float* mean  = (float*)carve((size_t)NTT * CCH * 4);
    float* upool = (float*)carve((size_t)NTT * CCH * 4);
    float* gbuf  = (float*)carve((size_t)NTT * CCH * 4);
    float* giM   = (float*)carve((size_t)NTT * G3 * 4);
    float* ghM   = (float*)carve((size_t)NTT * G3 * 4);
    float* scores = (float*)carve((size_t)N * 4);
    int* starts_tt  = (int*)carve((size_t)(NTT + 1) * 4);
    int* starts_mol = (int*)carve((size_t)(NMOL + 1) * 4);
    float* bnsc = (float*)carve(8 * CCH * 4);
    float* bnsh = (float*)carve(8 * CCH * 4);
    float* vsp  = (float*)carve(2 * CCH * 4);
    float* vd   = (float*)carve(2 * CCH * 4);
    float* c0   = (float*)carve(2 * 4);
    bf16* Wgcnb = (bf16*)carve((size_t)2 * CCH * CCH * 2);
    bf16* Wsrcb = (bf16*)carve((size_t)2 * CCH * CCH * 2);
    bf16* Wihb  = (bf16*)carve((size_t)2 * G3 * CCH * 2);
    bf16* Whhb  = (bf16*)carve((size_t)2 * G3 * CCH * 2);
    int*   bhist   = (int*)carve(512 * 4);
    int*   boff    = (int*)carve((size_t)(NB + 1) * 4);
    int*   bcur    = (int*)carve((size_t)NB * 4);
    int*   row_ptr = (int*)carve((size_t)(N + 1) * 4);
    int*   brow    = (int*)carve((size_t)E * 4);
    int2*  bcv     = (int2*)carve((size_t)E * 8);
    int2*  cpack   = (int2*)carve((size_t)E * 8);

    // ---- prep ----
    bnprep_kernel<<<8, 128, 0, stream>>>(bn_gamma, bn_beta, bn_mean, bn_var, bnsc, bnsh);
    matvec_prep_kernel<<<4, 128, 0, stream>>>(gat_Wsrc, gat_Wdst, gat_asrc, gat_adst,
                                              bnsc, bnsh, vsp, vd, c0);
    {
        int n4;
        n4 = 2 * CCH * CCH / 4; f2b_kernel<<<(n4 + 255) / 256, 256, 0, stream>>>(W_gcn, Wgcnb, n4);
        n4 = 2 * CCH * CCH / 4; f2b_kernel<<<(n4 + 255) / 256, 256, 0, stream>>>(gat_Wsrc, Wsrcb, n4);
        n4 = 2 * G3 * CCH / 4;  f2b_kernel<<<(n4 + 255) / 256, 256, 0, stream>>>(gru_Wih, Wihb, n4);
        n4 = 2 * G3 * CCH / 4;  f2b_kernel<<<(n4 + 255) / 256, 256, 0, stream>>>(gru_Whh, Whhb, n4);
    }
    bounds_kernel<<<(NTT + 1 + 255) / 256, 256, 0, stream>>>(tt_node_batch, N, NTT, starts_tt);
    bounds_kernel<<<(NMOL + 1 + 255) / 256, 256, 0, stream>>>(tt_graph_batch, NTT, NMOL, starts_mol);

    // ---- CSR build via bucket counting sort ----
    const int nchunk = (E + 4095) / 4096;
    hipMemsetAsync(bhist, 0, 512 * 4, stream);
    bucket_hist_kernel<<<nchunk, 256, 0, stream>>>(adj_rows, bhist, E);
    bucket_scan_kernel<<<1, 256, 0, stream>>>(bhist, boff, bcur, row_ptr, NB, N, E);
    bucket_bin_kernel<<<nchunk, 256, 0, stream>>>(adj_rows, adj_cols, adj_value,
                                                  bcur, brow, bcv, E);
    bucket_place_kernel<<<NB, 256, 0, stream>>>(brow, bcv, boff, row_ptr, cpack, N);

    // ---- GCN x2 ----
    dim3 gg((N + 127) / 128, 1);
    const int spmm_blocks = ((size_t)N * 16 + 255) / 256;
    gemm_mfma<0, 1, 0><<<gg, 256, 0, stream>>>(node_attr, Wgcnb, nullptr, bufB, N, CCH);
    spmm_csr_kernel<0><<<spmm_blocks, 256, 0, stream>>>(
        row_ptr, cpack, bufB, bufA, b_gcn, bnsc, bnsh, nullptr, nullptr, nullptr, N);
    gemm_mfma<1, 1, 0><<<gg, 256, 0, stream>>>(bufA, Wgcnb + CCH * CCH, nullptr, bufB, N, CCH);
    // layer-2 spmm also emits tt-stage attention scores
    spmm_csr_kernel<1><<<spmm_blocks, 256, 0, stream>>>(
        row_ptr, cpack, bufB, bufA, b_gcn + CCH, bnsc + CCH, bnsh + CCH,
        vsp, c0, scores, N);

    // ---- tt stage: N -> NTT (bf16 out, fused mol-stage scores) ----
    {
        int bnb = 2, gi = 0, nseg = NTT;
        segstage_kernel<<<nseg, 128, 0, stream>>>(bufA, scores, starts_tt,
            bnsc + bnb * CCH, bnsh + bnb * CCH, bnsc + (bnb + 1) * CCH, bnsh + (bnb + 1) * CCH,
            vd + gi * CCH, mean, upool);
        dim3 g1((nseg + 127) / 128, 1);
        gemm_mfma<0, 0, 1><<<g1, 256, 0, stream>>>(upool, Wsrcb + gi * CCH * CCH,
                                                   gat_bias + gi * CCH, gbuf, nseg, CCH);
        dim3 g2((nseg + 127) / 128, 3);
        gemm_mfma<0, 0, 0><<<g2, 256, 0, stream>>>(gbuf, Wihb + gi * G3 * CCH,
                                                   gru_bih + gi * G3, giM, nseg, G3);
        gemm_mfma<0, 0, 0><<<g2, 256, 0, stream>>>(mean, Whhb + gi * G3 * CCH,
                                                   gru_bhh + gi * G3, ghM, nseg, G3);
        gru_kernel<1, 1><<<(nseg * CCH + 255) / 256, 256, 0, stream>>>(giM, ghM, mean,
            bnsc + (bnb + 2) * CCH, bnsh + (bnb + 2) * CCH, tt,
            vsp + CCH, c0 + 1, scores, nseg * CCH);
    }

    // ---- mol stage: NTT -> NMOL (fp32 out) ----
    {
        int bnb = 5, gi = 1, nseg = NMOL;
        segstage_kernel<<<nseg, 128, 0, stream>>>(tt, scores, starts_mol,
            bnsc + bnb * CCH, bnsh + bnb * CCH, bnsc + (bnb + 1) * CCH, bnsh + (bnb + 1) * CCH,
            vd + gi * CCH, mean, upool);
        dim3 g1((nseg + 127) / 128, 1);
        gemm_mfma<0, 0, 1><<<g1, 256, 0, stream>>>(upool, Wsrcb + gi * CCH * CCH,
                                                   gat_bias + gi * CCH, gbuf, nseg, CCH);
        dim3 g2((nseg + 127) / 128, 3);
        gemm_mfma<0, 0, 0><<<g2, 256, 0, stream>>>(gbuf, Wihb + gi * G3 * CCH,
                                                   gru_bih + gi * G3, giM, nseg, G3);
        gemm_mfma<0, 0, 0><<<g2, 256, 0, stream>>>(mean, Whhb + gi * G3 * CCH,
                                                   gru_bhh + gi * G3, ghM, nseg, G3);
        gru_kernel<0, 0><<<(nseg * CCH + 255) / 256, 256, 0, stream>>>(giM, ghM, mean,
            bnsc + (bnb + 2) * CCH, bnsh + (bnb + 2) * CCH, mol,
            nullptr, nullptr, nullptr, nseg * CCH);
    }

    // ---- predictor ----
    pred_kernel<<<NMOL, 64, 0, stream>>>(mol, pW1, pb1, pW2, pb2, (float*)d_out);
}

// Round 6
// 612.366 us; speedup vs baseline: 10.2613x; 1.1244x over previous
//
#include <hip/hip_runtime.h>
#include <math.h>

#define CCH 128
#define G3  384
#define BN_EPS 1e-5f
#define BSH 9              // bucket shift: 512 rows/bucket
#define BROWS 512
#define COLBITS 19         // col < 2^19 (N=200000); row-in-bucket packed above

typedef __bf16 bf16;
typedef __bf16 bf16x2 __attribute__((ext_vector_type(2)));
typedef __bf16 bf16x4 __attribute__((ext_vector_type(4)));
typedef __bf16 bf16x8 __attribute__((ext_vector_type(8)));
typedef float f32x4 __attribute__((ext_vector_type(4)));

// ---------------- fused prep kernel (block-range roles) ----------------
// [0,B1): bn fold  [B1,B2): gat matvec  [B2,B3): bounds tt  [B3,B4): bounds mol
// [B4,B5): zero bhist  [B5,B6): f2b Wgcn  [B6,B7): f2b Wsrc  [B7,B8): f2b Wih  [B8,B9): f2b Whh
__global__ __launch_bounds__(256) void prep_kernel(
    const float* __restrict__ g, const float* __restrict__ b,
    const float* __restrict__ m, const float* __restrict__ v,
    float* __restrict__ bnsc, float* __restrict__ bnsh,
    const float* __restrict__ Wsrc, const float* __restrict__ Wdst,
    const float* __restrict__ asrc, const float* __restrict__ adst,
    float* __restrict__ vsp, float* __restrict__ vd, float* __restrict__ c0,
    const int* __restrict__ tt_node_batch, int N, int NTT, int* __restrict__ starts_tt,
    const int* __restrict__ tt_graph_batch, int NMOL, int* __restrict__ starts_mol,
    int* __restrict__ bhist,
    const float* __restrict__ Wgcn, bf16* __restrict__ Wgcnb,
    bf16* __restrict__ Wsrcb,
    const float* __restrict__ Wih, bf16* __restrict__ Wihb,
    const float* __restrict__ Whh, bf16* __restrict__ Whhb,
    int B1, int B2, int B3, int B4, int B5, int B6, int B7, int B8)
{
    __shared__ float red[2];
    const int bid = blockIdx.x;
    const int tid = threadIdx.x;
    if (bid < B1) {
        int idx = bid * 256 + tid;
        if (idx < 8 * CCH) {
            float s = g[idx] / sqrtf(v[idx] + BN_EPS);
            bnsc[idx] = s;
            bnsh[idx] = b[idx] - m[idx] * s;
        }
    } else if (bid < B2) {
        int s = bid - B1;
        int which = tid >> 7, k = tid & 127;
        const float* W = (which ? Wdst : Wsrc) + s * CCH * CCH;
        const float* a = (which ? adst : asrc) + s * CCH;
        float acc = 0.f;
        for (int j = 0; j < CCH; ++j) acc += W[j * CCH + k] * a[j];
        if (which) {
            vd[s * CCH + k] = acc;
        } else {
            int l = 2 + 3 * s;
            float scl = g[l * CCH + k] / sqrtf(v[l * CCH + k] + BN_EPS);
            float shf = b[l * CCH + k] - m[l * CCH + k] * scl;
            vsp[s * CCH + k] = acc * scl;
            float p = shf * acc;
            for (int o = 32; o; o >>= 1) p += __shfl_down(p, o);
            if ((k & 63) == 0) red[k >> 6] = p;
        }
        __syncthreads();
        if (tid == 0) c0[s] = red[0] + red[1];
    } else if (bid < B3) {
        int s = (bid - B2) * 256 + tid;
        if (s <= NTT) {
            int lo = 0, hi = N;
            while (lo < hi) { int mid = (lo + hi) >> 1; if (tt_node_batch[mid] < s) lo = mid + 1; else hi = mid; }
            starts_tt[s] = lo;
        }
    } else if (bid < B4) {
        int s = (bid - B3) * 256 + tid;
        if (s <= NMOL) {
            int lo = 0, hi = NTT;
            while (lo < hi) { int mid = (lo + hi) >> 1; if (tt_graph_batch[mid] < s) lo = mid + 1; else hi = mid; }
            starts_mol[s] = lo;
        }
    } else if (bid < B5) {
        bhist[tid] = 0; bhist[tid + 256] = 0;
    } else {
        const float* src; bf16* dst; int i0, n4;
        if (bid < B6)      { src = Wgcn; dst = Wgcnb; i0 = (bid - B5) * 256; n4 = 2 * CCH * CCH / 4; }
        else if (bid < B7) { src = Wsrc; dst = Wsrcb; i0 = (bid - B6) * 256; n4 = 2 * CCH * CCH / 4; }
        else if (bid < B8) { src = Wih;  dst = Wihb;  i0 = (bid - B7) * 256; n4 = 2 * G3 * CCH / 4; }
        else               { src = Whh;  dst = Whhb;  i0 = (bid - B8) * 256; n4 = 2 * G3 * CCH / 4; }
        int i = i0 + tid;
        if (i < n4) {
            float4 x = ((const float4*)src)[i];
            bf16x4 o = { (bf16)x.x, (bf16)x.y, (bf16)x.z, (bf16)x.w };
            ((bf16x4*)dst)[i] = o;
        }
    }
}

// ---------------- CSR build via bucket counting sort ----------------

__global__ __launch_bounds__(256) void bucket_hist_kernel(const int* __restrict__ rows,
                                                          int* __restrict__ bhist, int E)
{
    __shared__ int h[512];
    int t = threadIdx.x;
    h[t] = 0; h[t + 256] = 0;
    __syncthreads();
    int base = blockIdx.x * 4096;
#pragma unroll
    for (int i = 0; i < 16; ++i) {
        int e = base + i * 256 + t;
        if (e < E) atomicAdd(&h[rows[e] >> BSH], 1);
    }
    __syncthreads();
    if (h[t]) atomicAdd(&bhist[t], h[t]);
    if (h[t + 256]) atomicAdd(&bhist[t + 256], h[t + 256]);
}

__global__ __launch_bounds__(256) void bucket_scan_kernel(const int* __restrict__ bhist,
                                                          int* __restrict__ boff, int* __restrict__ bcur,
                                                          int* __restrict__ row_ptr, int NB, int N, int E)
{
    __shared__ int h[512], sx[512], wt[4];
    int t = threadIdx.x;
    h[t] = bhist[t]; h[t + 256] = bhist[t + 256];
    __syncthreads();
    int v0 = h[2 * t], v1 = h[2 * t + 1];
    int s = v0 + v1, incl = s;
    for (int o = 1; o < 64; o <<= 1) { int u = __shfl_up(incl, o); if ((t & 63) >= o) incl += u; }
    if ((t & 63) == 63) wt[t >> 6] = incl;
    __syncthreads();
    int woff = 0, w = t >> 6;
    for (int i = 0; i < w; ++i) woff += wt[i];
    int excl = woff + incl - s;
    sx[2 * t] = excl; sx[2 * t + 1] = excl + v0;
    __syncthreads();
    if (t < NB)       { boff[t] = sx[t];       bcur[t] = sx[t]; }
    if (t + 256 < NB) { boff[t + 256] = sx[t + 256]; bcur[t + 256] = sx[t + 256]; }
    if (t == 0) { boff[NB] = E; row_ptr[N] = E; }
}

// counting-sort a 4096-edge chunk by bucket in LDS; flush contiguous runs.
// bcv.x packs col | (row&511)<<COLBITS
__global__ __launch_bounds__(256) void bucket_bin_kernel(
    const int* __restrict__ rows, const int* __restrict__ cols, const float* __restrict__ val,
    int* __restrict__ bcur, int2* __restrict__ bcv, int E)
{
    __shared__ int hist[512], sx[512], cnt[512], gbase[512], wt[4];
    __shared__ int mb[4096];
    __shared__ int2 mcv[4096];
    int t = threadIdx.x;
    hist[t] = 0; hist[t + 256] = 0; cnt[t] = 0; cnt[t + 256] = 0;
    __syncthreads();
    int base = blockIdx.x * 4096;
    int r[16];
#pragma unroll
    for (int i = 0; i < 16; ++i) {
        int e = base + i * 256 + t;
        r[i] = (e < E) ? rows[e] : -1;
        if (r[i] >= 0) atomicAdd(&hist[r[i] >> BSH], 1);
    }
    __syncthreads();
    int v0 = hist[2 * t], v1 = hist[2 * t + 1];
    int s = v0 + v1, incl = s;
    for (int o = 1; o < 64; o <<= 1) { int u = __shfl_up(incl, o); if ((t & 63) >= o) incl += u; }
    if ((t & 63) == 63) wt[t >> 6] = incl;
    __syncthreads();
    int woff = 0, w = t >> 6;
    for (int i = 0; i < w; ++i) woff += wt[i];
    int excl = woff + incl - s;
    sx[2 * t] = excl; sx[2 * t + 1] = excl + v0;
    __syncthreads();
    for (int bb = t; bb < 512; bb += 256)
        if (hist[bb]) gbase[bb] = atomicAdd(&bcur[bb], hist[bb]);
    __syncthreads();
#pragma unroll
    for (int i = 0; i < 16; ++i) {
        if (r[i] < 0) continue;
        int e = base + i * 256 + t;
        int bb = r[i] >> BSH;
        int p = atomicAdd(&cnt[bb], 1);
        int loc = sx[bb] + p;
        mb[loc] = bb;
        int2 cv;
        cv.x = cols[e] | ((r[i] & (BROWS - 1)) << COLBITS);
        cv.y = __float_as_int(val[e]);
        mcv[loc] = cv;
    }
    __syncthreads();
    int Mv = sx[511] + hist[511];
    for (int loc = t; loc < Mv; loc += 256) {
        int bb = mb[loc];
        int gidx = gbase[bb] + (loc - sx[bb]);
        bcv[gidx] = mcv[loc];
    }
}

// one block per bucket: row-hist -> row_ptr; place edges into exact CSR slots (col stripped)
__global__ __launch_bounds__(256) void bucket_place_kernel(
    const int2* __restrict__ bcv, const int* __restrict__ boff, int* __restrict__ row_ptr,
    int2* __restrict__ cpack, int N)
{
    __shared__ int rcnt[512], sx[512], wt[4];
    int b = blockIdx.x;
    int t = threadIdx.x;
    rcnt[t] = 0; rcnt[t + 256] = 0;
    __syncthreads();
    int rbase = b << BSH;
    int rn = min(BROWS, N - rbase);
    int lo = boff[b], hi = boff[b + 1];
    for (int p = lo + t; p < hi; p += 256)
        atomicAdd(&rcnt[((unsigned)bcv[p].x) >> COLBITS], 1);
    __syncthreads();
    int v0 = rcnt[2 * t], v1 = rcnt[2 * t + 1];
    int s = v0 + v1, incl = s;
    for (int o = 1; o < 64; o <<= 1) { int u = __shfl_up(incl, o); if ((t & 63) >= o) incl += u; }
    if ((t & 63) == 63) wt[t >> 6] = incl;
    __syncthreads();
    int woff = 0, w = t >> 6;
    for (int i = 0; i < w; ++i) woff += wt[i];
    int excl = woff + incl - s;
    sx[2 * t] = excl; sx[2 * t + 1] = excl + v0;
    __syncthreads();
    if (t < rn)       row_ptr[rbase + t] = lo + sx[t];
    if (t + 256 < rn) row_ptr[rbase + t + 256] = lo + sx[t + 256];
    __syncthreads();
    sx[t] += lo; sx[t + 256] += lo;
    __syncthreads();
    for (int p = lo + t; p < hi; p += 256) {
        int2 cv = bcv[p];
        int rin = ((unsigned)cv.x) >> COLBITS;
        int slot = atomicAdd(&sx[rin], 1);
        cv.x &= (1 << COLBITS) - 1;
        cpack[slot] = cv;
    }
}

// ---------------- MFMA GEMM: Y[M x Nout] = X[M x 128] @ W[Nout x 128]^T (+bias)(+elu) ----
template<int IN_BF16, int OUT_BF16, int ACT>
__global__ __launch_bounds__(256, 2) void gemm_mfma(
    const void* __restrict__ Xv, const bf16* __restrict__ W,
    const float* __restrict__ bias, void* __restrict__ Yv, int M, int Nout)
{
    __shared__ bf16 Xs[128 * 136];
    __shared__ bf16 Ws[128 * 136];
    const int tid = threadIdx.x;
    const int rb = blockIdx.x * 128;
    const int cb = blockIdx.y * 128;

#pragma unroll
    for (int i = 0; i < 8; ++i) {
        int c = tid + i * 256;
        int r = c >> 4, k8 = (c & 15) << 3;
        *(bf16x8*)&Ws[r * 136 + k8] = *(const bf16x8*)&W[(size_t)(cb + r) * CCH + k8];
    }
    if (IN_BF16) {
#pragma unroll
        for (int i = 0; i < 8; ++i) {
            int c = tid + i * 256;
            int r = c >> 4, k8 = (c & 15) << 3;
            int grow = rb + r;
            bf16x8 o = {};
            if (grow < M) o = *(const bf16x8*)&((const bf16*)Xv)[(size_t)grow * CCH + k8];
            *(bf16x8*)&Xs[r * 136 + k8] = o;
        }
    } else {
#pragma unroll
        for (int i = 0; i < 16; ++i) {
            int c = tid + i * 256;
            int r = c >> 5, k4 = (c & 31) << 2;
            int grow = rb + r;
            bf16x4 o = {};
            if (grow < M) {
                float4 xv = *(const float4*)&((const float*)Xv)[(size_t)grow * CCH + k4];
                o[0] = (bf16)xv.x; o[1] = (bf16)xv.y; o[2] = (bf16)xv.z; o[3] = (bf16)xv.w;
            }
            *(bf16x4*)&Xs[r * 136 + k4] = o;
        }
    }
    __syncthreads();

    const int w = tid >> 6, lane = tid & 63;
    const int col16 = lane & 15, quad = lane >> 4;
    const int wm = (w & 1) * 64, wn = (w >> 1) * 64;

    f32x4 acc[4][4] = {};
#pragma unroll
    for (int kk = 0; kk < 4; ++kk) {
        bf16x8 af[4], bfr[4];
#pragma unroll
        for (int mi = 0; mi < 4; ++mi)
            af[mi] = *(const bf16x8*)&Xs[(wm + mi * 16 + col16) * 136 + kk * 32 + quad * 8];
#pragma unroll
        for (int ni = 0; ni < 4; ++ni)
            bfr[ni] = *(const bf16x8*)&Ws[(wn + ni * 16 + col16) * 136 + kk * 32 + quad * 8];
#pragma unroll
        for (int mi = 0; mi < 4; ++mi)
#pragma unroll
            for (int ni = 0; ni < 4; ++ni)
                acc[mi][ni] = __builtin_amdgcn_mfma_f32_16x16x32_bf16(af[mi], bfr[ni], acc[mi][ni], 0, 0, 0);
    }

#pragma unroll
    for (int mi = 0; mi < 4; ++mi) {
#pragma unroll
        for (int r = 0; r < 4; ++r) {
            int row = rb + wm + mi * 16 + quad * 4 + r;
            if (row >= M) continue;
#pragma unroll
            for (int ni = 0; ni < 4; ++ni) {
                int col = cb + wn + ni * 16 + col16;
                float vv = acc[mi][ni][r];
                if (bias) vv += bias[col];
                if (ACT == 1) vv = vv > 0.f ? vv : expm1f(vv);   // elu
                if (OUT_BF16) ((bf16*)Yv)[(size_t)row * Nout + col] = (bf16)vv;
                else          ((float*)Yv)[(size_t)row * Nout + col] = vv;
            }
        }
    }
}

// dual GEMM (Wih@X0 -> Y0, Whh@X1 -> Y1), fp32 in/out, Nout=G3, grid.y in [0,6)
__global__ __launch_bounds__(256, 2) void gemm_dual(
    const float* __restrict__ X0, const bf16* __restrict__ W0,
    const float* __restrict__ b0, float* __restrict__ Y0,
    const float* __restrict__ X1, const bf16* __restrict__ W1,
    const float* __restrict__ b1, float* __restrict__ Y1, int M)
{
    __shared__ bf16 Xs[128 * 136];
    __shared__ bf16 Ws[128 * 136];
    const int tid = threadIdx.x;
    const int rb = blockIdx.x * 128;
    const int yy = blockIdx.y;
    const float* X; const bf16* W; const float* bias; float* Y; int cb;
    if (yy < 3) { X = X0; W = W0; bias = b0; Y = Y0; cb = yy * 128; }
    else        { X = X1; W = W1; bias = b1; Y = Y1; cb = (yy - 3) * 128; }

#pragma unroll
    for (int i = 0; i < 8; ++i) {
        int c = tid + i * 256;
        int r = c >> 4, k8 = (c & 15) << 3;
        *(bf16x8*)&Ws[r * 136 + k8] = *(const bf16x8*)&W[(size_t)(cb + r) * CCH + k8];
    }
#pragma unroll
    for (int i = 0; i < 16; ++i) {
        int c = tid + i * 256;
        int r = c >> 5, k4 = (c & 31) << 2;
        int grow = rb + r;
        bf16x4 o = {};
        if (grow < M) {
            float4 xv = *(const float4*)&X[(size_t)grow * CCH + k4];
            o[0] = (bf16)xv.x; o[1] = (bf16)xv.y; o[2] = (bf16)xv.z; o[3] = (bf16)xv.w;
        }
        *(bf16x4*)&Xs[r * 136 + k4] = o;
    }
    __syncthreads();

    const int w = tid >> 6, lane = tid & 63;
    const int col16 = lane & 15, quad = lane >> 4;
    const int wm = (w & 1) * 64, wn = (w >> 1) * 64;

    f32x4 acc[4][4] = {};
#pragma unroll
    for (int kk = 0; kk < 4; ++kk) {
        bf16x8 af[4], bfr[4];
#pragma unroll
        for (int mi = 0; mi < 4; ++mi)
            af[mi] = *(const bf16x8*)&Xs[(wm + mi * 16 + col16) * 136 + kk * 32 + quad * 8];
#pragma unroll
        for (int ni = 0; ni < 4; ++ni)
            bfr[ni] = *(const bf16x8*)&Ws[(wn + ni * 16 + col16) * 136 + kk * 32 + quad * 8];
#pragma unroll
        for (int mi = 0; mi < 4; ++mi)
#pragma unroll
            for (int ni = 0; ni < 4; ++ni)
                acc[mi][ni] = __builtin_amdgcn_mfma_f32_16x16x32_bf16(af[mi], bfr[ni], acc[mi][ni], 0, 0, 0);
    }

#pragma unroll
    for (int mi = 0; mi < 4; ++mi) {
#pragma unroll
        for (int r = 0; r < 4; ++r) {
            int row = rb + wm + mi * 16 + quad * 4 + r;
            if (row >= M) continue;
#pragma unroll
            for (int ni = 0; ni < 4; ++ni) {
                int col = cb + wn + ni * 16 + col16;
                Y[(size_t)row * G3 + col] = acc[mi][ni][r] + bias[col];
            }
        }
    }
}

// ---------------- SpMM (CSR gather): 16 lanes/row x bf16x8, 4-edge unroll ----------------
template<int SCORES>
__global__ __launch_bounds__(256) void spmm_csr_kernel(
    const int* __restrict__ row_ptr, const int2* __restrict__ cpack,
    const bf16* __restrict__ Xin, bf16* __restrict__ Y,
    const float* __restrict__ bvec, const float* __restrict__ sc, const float* __restrict__ sh,
    const float* __restrict__ vsp, const float* __restrict__ c0p, float* __restrict__ scores,
    int Nrow)
{
    int gid = blockIdx.x * 256 + threadIdx.x;
    int row = gid >> 4;
    if (row >= Nrow) return;
    int l8 = (gid & 15) << 3;
    int st = row_ptr[row], en = row_ptr[row + 1];
    float acc[8] = {};
    int j = st;
    for (; j + 4 <= en; j += 4) {
        int2 p0 = cpack[j], p1 = cpack[j + 1], p2 = cpack[j + 2], p3 = cpack[j + 3];
        bf16x8 x0 = *(const bf16x8*)&Xin[(size_t)p0.x * CCH + l8];
        bf16x8 x1 = *(const bf16x8*)&Xin[(size_t)p1.x * CCH + l8];
        bf16x8 x2 = *(const bf16x8*)&Xin[(size_t)p2.x * CCH + l8];
        bf16x8 x3 = *(const bf16x8*)&Xin[(size_t)p3.x * CCH + l8];
        float v0 = __int_as_float(p0.y), v1 = __int_as_float(p1.y);
        float v2 = __int_as_float(p2.y), v3 = __int_as_float(p3.y);
#pragma unroll
        for (int q = 0; q < 8; ++q)
            acc[q] += v0 * (float)x0[q] + v1 * (float)x1[q] + v2 * (float)x2[q] + v3 * (float)x3[q];
    }
    if (j + 2 <= en) {
        int2 p0 = cpack[j], p1 = cpack[j + 1];
        bf16x8 x0 = *(const bf16x8*)&Xin[(size_t)p0.x * CCH + l8];
        bf16x8 x1 = *(const bf16x8*)&Xin[(size_t)p1.x * CCH + l8];
        float v0 = __int_as_float(p0.y), v1 = __int_as_float(p1.y);
#pragma unroll
        for (int q = 0; q < 8; ++q) acc[q] += v0 * (float)x0[q] + v1 * (float)x1[q];
        j += 2;
    }
    if (j < en) {
        int2 p0 = cpack[j];
        bf16x8 x0 = *(const bf16x8*)&Xin[(size_t)p0.x * CCH + l8];
        float v0 = __int_as_float(p0.y);
#pragma unroll
        for (int q = 0; q < 8; ++q) acc[q] += v0 * (float)x0[q];
    }
    float o[8];
    bf16x8 ov;
#pragma unroll
    for (int q = 0; q < 8; ++q) {
        o[q] = fmaxf((acc[q] + bvec[l8 + q]) * sc[l8 + q] + sh[l8 + q], 0.f);
        ov[q] = (bf16)o[q];
    }
    *(bf16x8*)&Y[(size_t)row * CCH + l8] = ov;
    if (SCORES) {
        float p = 0.f;
#pragma unroll
        for (int q = 0; q < 8; ++q) p += o[q] * vsp[l8 + q];
        for (int d = 8; d; d >>= 1) p += __shfl_down(p, d, 16);
        if ((gid & 15) == 0) scores[row] = p + c0p[0];
    }
}

// ---------------- fused pool + attention pool (per segment) ----------------
__global__ __launch_bounds__(128) void segstage_kernel(
    const bf16* __restrict__ X, const float* __restrict__ sarr, const int* __restrict__ starts,
    const float* __restrict__ sc2, const float* __restrict__ sh2,
    const float* __restrict__ sc3, const float* __restrict__ sh3,
    const float* __restrict__ vd, float* __restrict__ mean, float* __restrict__ upool)
{
    __shared__ float red[2];
    __shared__ float adsh;
    int t = blockIdx.x;
    int c = threadIdx.x;
    int st = starts[t], en = starts[t + 1];
    float sum = 0.f;
    for (int i = st; i < en; ++i) sum += (float)X[(size_t)i * CCH + c];
    float cnt = (float)(en - st);
    float poolb = fmaxf(sum * sc2[c] + cnt * sh2[c], 0.f);
    float mv = poolb * sc3[c] + sh3[c];
    mean[(size_t)t * CCH + c] = mv;
    float p = mv * vd[c];
    for (int o = 32; o; o >>= 1) p += __shfl_down(p, o);
    if ((c & 63) == 0) red[c >> 6] = p;
    __syncthreads();
    if (c == 0) adsh = red[0] + red[1];
    __syncthreads();
    if (en == st) { upool[(size_t)t * CCH + c] = 0.f; return; }
    float adt = adsh;
    float lm = -3.0e38f;
    for (int i = st + c; i < en; i += 128) {
        float a = sarr[i] + adt;
        a = a > 0.f ? a : 0.01f * a;
        lm = fmaxf(lm, a);
    }
    for (int o = 32; o; o >>= 1) lm = fmaxf(lm, __shfl_down(lm, o));
    if ((c & 63) == 0) red[c >> 6] = lm;
    __syncthreads();
    float m = fmaxf(red[0], red[1]);
    float u = 0.f, den = 0.f;
    for (int i = st; i < en; ++i) {
        float a = sarr[i] + adt;
        a = a > 0.f ? a : 0.01f * a;
        float e = __expf(a - m);
        den += e;
        u += e * (float)X[(size_t)i * CCH + c];
    }
    upool[(size_t)t * CCH + c] = (u / den) * sc2[c] + sh2[c];
}

// GRU combine + relu + bn(base+2); bf16 out + fused next-stage scores (tt stage)
__global__ __launch_bounds__(256) void gru_kernel(
    const float* __restrict__ giM, const float* __restrict__ ghM, const float* __restrict__ mean,
    const float* __restrict__ sc4, const float* __restrict__ sh4,
    bf16* __restrict__ out,
    const float* __restrict__ vsp2, const float* __restrict__ c02, float* __restrict__ scores,
    int total)
{
    __shared__ float sred[4];
    int idx = blockIdx.x * 256 + threadIdx.x;
    bool ok = idx < total;
    int t = idx >> 7, c = idx & 127;
    float o = 0.f;
    if (ok) {
        size_t b = (size_t)t * G3;
        float ir = giM[b + c],  iz = giM[b + 128 + c], inn = giM[b + 256 + c];
        float hr = ghM[b + c],  hz = ghM[b + 128 + c], hn  = ghM[b + 256 + c];
        float r = 1.f / (1.f + __expf(-(ir + hr)));
        float z = 1.f / (1.f + __expf(-(iz + hz)));
        float nn = tanhf(inn + r * hn);
        float h = (1.f - z) * nn + z * mean[idx];
        h = fmaxf(h, 0.f);
        o = h * sc4[c] + sh4[c];
        out[idx] = (bf16)o;
    }
    float p = ok ? o * vsp2[c] : 0.f;
    for (int d = 32; d; d >>= 1) p += __shfl_down(p, d);
    int w = threadIdx.x >> 6;
    if ((threadIdx.x & 63) == 0) sred[w] = p;
    __syncthreads();
    if (threadIdx.x == 0 && ok)   scores[t] = sred[0] + sred[1] + c02[0];
    if (threadIdx.x == 128 && ok) scores[t] = sred[2] + sred[3] + c02[0];
}

// mol-stage GRU + predictor fused: 2 segments per block, no mol materialization
__global__ __launch_bounds__(256) void gru_pred_kernel(
    const float* __restrict__ giM, const float* __restrict__ ghM, const float* __restrict__ mean,
    const float* __restrict__ sc4, const float* __restrict__ sh4,
    const float* __restrict__ pW1, const float* __restrict__ pb1,
    const float* __restrict__ pW2, const float* __restrict__ pb2,
    float* __restrict__ out, int nseg)
{
    __shared__ float row[2][CCH];
    int half = threadIdx.x >> 7;
    int c = threadIdx.x & 127;
    int t = blockIdx.x * 2 + half;
    bool ok = t < nseg;
    float o = 0.f;
    if (ok) {
        size_t b = (size_t)t * G3;
        float ir = giM[b + c],  iz = giM[b + 128 + c], inn = giM[b + 256 + c];
        float hr = ghM[b + c],  hz = ghM[b + 128 + c], hn  = ghM[b + 256 + c];
        float r = 1.f / (1.f + __expf(-(ir + hr)));
        float z = 1.f / (1.f + __expf(-(iz + hz)));
        float nn = tanhf(inn + r * hn);
        float h = (1.f - z) * nn + z * mean[(size_t)t * CCH + c];
        h = fmaxf(h, 0.f);
        o = h * sc4[c] + sh4[c];
    }
    row[half][c] = o;
    __syncthreads();
    if (c < 64 && ok) {
        float h = pb1[c];
#pragma unroll
        for (int k = 0; k < CCH; ++k) h += row[half][k] * pW1[c * CCH + k];
        h = fmaxf(h, 0.f);
        float p = h * pW2[c];
        for (int d = 32; d; d >>= 1) p += __shfl_down(p, d);
        if (c == 0) out[t] = p + pb2[0];
    }
}

// ---------------- host ----------------

extern "C" void kernel_launch(void* const* d_in, const int* in_sizes, int n_in,
                              void* d_out, int out_size, void* d_ws, size_t ws_size,
                              hipStream_t stream)
{
    (void)n_in; (void)ws_size;
    const float* node_attr      = (const float*)d_in[0];
    const int*   adj_index      = (const int*)  d_in[1];
    const float* adj_value      = (const float*)d_in[2];
    const int*   tt_node_batch  = (const int*)  d_in[3];
    const int*   tt_graph_batch = (const int*)  d_in[4];
    const float* W_gcn    = (const float*)d_in[5];
    const float* b_gcn    = (const float*)d_in[6];
    const float* bn_gamma = (const float*)d_in[7];
    const float* bn_beta  = (const float*)d_in[8];
    const float* bn_mean  = (const float*)d_in[9];
    const float* bn_var   = (const float*)d_in[10];
    const float* gat_Wsrc = (const float*)d_in[11];
    const float* gat_Wdst = (const float*)d_in[12];
    const float* gat_asrc = (const float*)d_in[13];
    const float* gat_adst = (const float*)d_in[14];
    const float* gat_bias = (const float*)d_in[15];
    const float* gru_Wih  = (const float*)d_in[16];
    const float* gru_Whh  = (const float*)d_in[17];
    const float* gru_bih  = (const float*)d_in[18];
    const float* gru_bhh  = (const float*)d_in[19];
    const float* pW1 = (const float*)d_in[20];
    const float* pb1 = (const float*)d_in[21];
    const float* pW2 = (const float*)d_in[22];
    const float* pb2 = (const float*)d_in[23];

    const int E    = in_sizes[2];
    const int N    = in_sizes[3];
    const int NTT  = in_sizes[4];
    const int NMOL = out_size;
    const int NB   = (N + BROWS - 1) >> BSH;

    const int* adj_rows = adj_index;
    const int* adj_cols = adj_index + E;

    // ---- workspace carve ----
    char* wsb = (char*)d_ws;
    size_t off = 0;
    auto carve = [&](size_t bytes) -> char* {
        char* p = wsb + off;
        off = (off + bytes + 255) & ~(size_t)255;
        return p;
    };
    bf16* bufB = (bf16*)carve((size_t)N * CCH * 2);
    bf16* bufA = (bf16*)carve((size_t)N * CCH * 2);
    bf16* tt   = (bf16*)carve((size_t)NTT * CCH * 2);
    float* mean  = (float*)carve((size_t)NTT * CCH * 4);
    float* upool = (float*)carve((size_t)NTT * CCH * 4);
    float* gbuf  = (float*)carve((size_t)NTT * CCH * 4);
    float* giM   = (float*)carve((size_t)NTT * G3 * 4);
    float* ghM   = (float*)carve((size_t)NTT * G3 * 4);
    float* scores = (float*)carve((size_t)N * 4);
    int* starts_tt  = (int*)carve((size_t)(NTT + 1) * 4);
    int* starts_mol = (int*)carve((size_t)(NMOL + 1) * 4);
    float* bnsc = (float*)carve(8 * CCH * 4);
    float* bnsh = (float*)carve(8 * CCH * 4);
    float* vsp  = (float*)carve(2 * CCH * 4);
    float* vd   = (float*)carve(2 * CCH * 4);
    float* c0   = (float*)carve(2 * 4);
    bf16* Wgcnb = (bf16*)carve((size_t)2 * CCH * CCH * 2);
    bf16* Wsrcb = (bf16*)carve((size_t)2 * CCH * CCH * 2);
    bf16* Wihb  = (bf16*)carve((size_t)2 * G3 * CCH * 2);
    bf16* Whhb  = (bf16*)carve((size_t)2 * G3 * CCH * 2);
    int*   bhist   = (int*)carve(512 * 4);
    int*   boff    = (int*)carve((size_t)(NB + 1) * 4);
    int*   bcur    = (int*)carve((size_t)NB * 4);
    int*   row_ptr = (int*)carve((size_t)(N + 1) * 4);
    int2*  bcv     = (int2*)carve((size_t)E * 8);
    int2*  cpack   = (int2*)carve((size_t)E * 8);

    // ---- fused prep (bn fold + gat matvec + bounds + zero bhist + weight f2b) ----
    const int B1 = 4;
    const int B2 = B1 + 2;
    const int B3 = B2 + (NTT + 1 + 255) / 256;
    const int B4 = B3 + (NMOL + 1 + 255) / 256;
    const int B5 = B4 + 1;
    const int B6 = B5 + 32;
    const int B7 = B6 + 32;
    const int B8 = B7 + 96;
    const int B9 = B8 + 96;
    prep_kernel<<<B9, 256, 0, stream>>>(
        bn_gamma, bn_beta, bn_mean, bn_var, bnsc, bnsh,
        gat_Wsrc, gat_Wdst, gat_asrc, gat_adst, vsp, vd, c0,
        tt_node_batch, N, NTT, starts_tt,
        tt_graph_batch, NMOL, starts_mol,
        bhist,
        W_gcn, Wgcnb, Wsrcb, gru_Wih, Wihb, gru_Whh, Whhb,
        B1, B2, B3, B4, B5, B6, B7, B8);

    // ---- CSR build via bucket counting sort ----
    const int nchunk = (E + 4095) / 4096;
    bucket_hist_kernel<<<nchunk, 256, 0, stream>>>(adj_rows, bhist, E);
    bucket_scan_kernel<<<1, 256, 0, stream>>>(bhist, boff, bcur, row_ptr, NB, N, E);
    bucket_bin_kernel<<<nchunk, 256, 0, stream>>>(adj_rows, adj_cols, adj_value, bcur, bcv, E);
    bucket_place_kernel<<<NB, 256, 0, stream>>>(bcv, boff, row_ptr, cpack, N);

    // ---- GCN x2 ----
    dim3 gg((N + 127) / 128, 1);
    const int spmm_blocks = ((size_t)N * 16 + 255) / 256;
    gemm_mfma<0, 1, 0><<<gg, 256, 0, stream>>>(node_attr, Wgcnb, nullptr, bufB, N, CCH);
    spmm_csr_kernel<0><<<spmm_blocks, 256, 0, stream>>>(
        row_ptr, cpack, bufB, bufA, b_gcn, bnsc, bnsh, nullptr, nullptr, nullptr, N);
    gemm_mfma<1, 1, 0><<<gg, 256, 0, stream>>>(bufA, Wgcnb + CCH * CCH, nullptr, bufB, N, CCH);
    spmm_csr_kernel<1><<<spmm_blocks, 256, 0, stream>>>(
        row_ptr, cpack, bufB, bufA, b_gcn + CCH, bnsc + CCH, bnsh + CCH,
        vsp, c0, scores, N);

    // ---- tt stage: N -> NTT (bf16 out + fused mol-stage scores) ----
    {
        const int bnb = 2, gi = 0, nseg = NTT;
        segstage_kernel<<<nseg, 128, 0, stream>>>(bufA, scores, starts_tt,
            bnsc + bnb * CCH, bnsh + bnb * CCH, bnsc + (bnb + 1) * CCH, bnsh + (bnb + 1) * CCH,
            vd + gi * CCH, mean, upool);
        dim3 g1((nseg + 127) / 128, 1);
        gemm_mfma<0, 0, 1><<<g1, 256, 0, stream>>>(upool, Wsrcb + gi * CCH * CCH,
                                                   gat_bias + gi * CCH, gbuf, nseg, CCH);
        dim3 g2((nseg + 127) / 128, 6);
        gemm_dual<<<g2, 256, 0, stream>>>(gbuf, Wihb + gi * G3 * CCH, gru_bih + gi * G3, giM,
                                          mean, Whhb + gi * G3 * CCH, gru_bhh + gi * G3, ghM, nseg);
        gru_kernel<<<(nseg * CCH + 255) / 256, 256, 0, stream>>>(giM, ghM, mean,
            bnsc + (bnb + 2) * CCH, bnsh + (bnb + 2) * CCH, tt,
            vsp + CCH, c0 + 1, scores, nseg * CCH);
    }

    // ---- mol stage: NTT -> NMOL (GRU+predictor fused) ----
    {
        const int bnb = 5, gi = 1, nseg = NMOL;
        segstage_kernel<<<nseg, 128, 0, stream>>>(tt, scores, starts_mol,
            bnsc + bnb * CCH, bnsh + bnb * CCH, bnsc + (bnb + 1) * CCH, bnsh + (bnb + 1) * CCH,
            vd + gi * CCH, mean, upool);
        dim3 g1((nseg + 127) / 128, 1);
        gemm_mfma<0, 0, 1><<<g1, 256, 0, stream>>>(upool, Wsrcb + gi * CCH * CCH,
                                                   gat_bias + gi * CCH, gbuf, nseg, CCH);
        dim3 g2((nseg + 127) / 128, 6);
        gemm_dual<<<g2, 256, 0, stream>>>(gbuf, Wihb + gi * G3 * CCH, gru_bih + gi * G3, giM,
                                          mean, Whhb + gi * G3 * CCH, gru_bhh + gi * G3, ghM, nseg);
        gru_pred_kernel<<<(nseg + 1) / 2, 256, 0, stream>>>(giM, ghM, mean,
            bnsc + (bnb + 2) * CCH, bnsh + (bnb + 2) * CCH,
            pW1, pb1, pW2, pb2, (float*)d_out, nseg);
    }
}

// Round 7
// 595.394 us; speedup vs baseline: 10.5538x; 1.0285x over previous
//
#include <hip/hip_runtime.h>
#include <math.h>

#define CCH 128
#define G3  384
#define BN_EPS 1e-5f
#define BSH 9              // bucket shift: 512 rows/bucket
#define BROWS 512
#define COLBITS 19         // col < 2^19 (N=200000); row-in-bucket packed above

typedef __bf16 bf16;
typedef __bf16 bf16x2 __attribute__((ext_vector_type(2)));
typedef __bf16 bf16x4 __attribute__((ext_vector_type(4)));
typedef __bf16 bf16x8 __attribute__((ext_vector_type(8)));
typedef float f32x4 __attribute__((ext_vector_type(4)));

// ---------------- fused prep kernel (block-range roles) ----------------
// [0,B1): bn fold  [B1,B2): gat matvec  [B2,B3): bounds tt  [B3,B4): bounds mol
// [B4,B5): zero bhist  [B5..B9): W repack fp32 -> bf16 MFMA-fragment layout:
//   per 128-row block bi: chunk (kc in 0..15, nrow in 0..127) of 8 bf16 at
//   dst[bi*16384 + (kc*128 + nrow)*8] = W[bi*128+nrow][kc*8 .. +8]
__global__ __launch_bounds__(256) void prep_kernel(
    const float* __restrict__ g, const float* __restrict__ b,
    const float* __restrict__ m, const float* __restrict__ v,
    float* __restrict__ bnsc, float* __restrict__ bnsh,
    const float* __restrict__ Wsrc, const float* __restrict__ Wdst,
    const float* __restrict__ asrc, const float* __restrict__ adst,
    float* __restrict__ vsp, float* __restrict__ vd, float* __restrict__ c0,
    const int* __restrict__ tt_node_batch, int N, int NTT, int* __restrict__ starts_tt,
    const int* __restrict__ tt_graph_batch, int NMOL, int* __restrict__ starts_mol,
    int* __restrict__ bhist,
    const float* __restrict__ Wgcn, bf16* __restrict__ Wgcnb,
    bf16* __restrict__ Wsrcb,
    const float* __restrict__ Wih, bf16* __restrict__ Wihb,
    const float* __restrict__ Whh, bf16* __restrict__ Whhb,
    int B1, int B2, int B3, int B4, int B5, int B6, int B7, int B8)
{
    __shared__ float red[2];
    const int bid = blockIdx.x;
    const int tid = threadIdx.x;
    if (bid < B1) {
        int idx = bid * 256 + tid;
        if (idx < 8 * CCH) {
            float s = g[idx] / sqrtf(v[idx] + BN_EPS);
            bnsc[idx] = s;
            bnsh[idx] = b[idx] - m[idx] * s;
        }
    } else if (bid < B2) {
        int s = bid - B1;
        int which = tid >> 7, k = tid & 127;
        const float* W = (which ? Wdst : Wsrc) + s * CCH * CCH;
        const float* a = (which ? adst : asrc) + s * CCH;
        float acc = 0.f;
        for (int j = 0; j < CCH; ++j) acc += W[j * CCH + k] * a[j];
        if (which) {
            vd[s * CCH + k] = acc;
        } else {
            int l = 2 + 3 * s;
            float scl = g[l * CCH + k] / sqrtf(v[l * CCH + k] + BN_EPS);
            float shf = b[l * CCH + k] - m[l * CCH + k] * scl;
            vsp[s * CCH + k] = acc * scl;
            float p = shf * acc;
            for (int o = 32; o; o >>= 1) p += __shfl_down(p, o);
            if ((k & 63) == 0) red[k >> 6] = p;
        }
        __syncthreads();
        if (tid == 0) c0[s] = red[0] + red[1];
    } else if (bid < B3) {
        int s = (bid - B2) * 256 + tid;
        if (s <= NTT) {
            int lo = 0, hi = N;
            while (lo < hi) { int mid = (lo + hi) >> 1; if (tt_node_batch[mid] < s) lo = mid + 1; else hi = mid; }
            starts_tt[s] = lo;
        }
    } else if (bid < B4) {
        int s = (bid - B3) * 256 + tid;
        if (s <= NMOL) {
            int lo = 0, hi = NTT;
            while (lo < hi) { int mid = (lo + hi) >> 1; if (tt_graph_batch[mid] < s) lo = mid + 1; else hi = mid; }
            starts_mol[s] = lo;
        }
    } else if (bid < B5) {
        bhist[tid] = 0; bhist[tid + 256] = 0;
    } else {
        const float* src; bf16* dst; int u0;
        if (bid < B6)      { src = Wgcn; dst = Wgcnb; u0 = (bid - B5) * 256; }
        else if (bid < B7) { src = Wsrc; dst = Wsrcb; u0 = (bid - B6) * 256; }
        else if (bid < B8) { src = Wih;  dst = Wihb;  u0 = (bid - B7) * 256; }
        else               { src = Whh;  dst = Whhb;  u0 = (bid - B8) * 256; }
        int u = u0 + tid;
        int row = u >> 4, kc = u & 15;
        int bi = row >> 7, nrow = row & 127;
        const float* s = src + (size_t)row * CCH + kc * 8;
        float4 a = *(const float4*)s;
        float4 b4 = *(const float4*)(s + 4);
        bf16x8 o = { (bf16)a.x, (bf16)a.y, (bf16)a.z, (bf16)a.w,
                     (bf16)b4.x, (bf16)b4.y, (bf16)b4.z, (bf16)b4.w };
        *(bf16x8*)&dst[(size_t)bi * 16384 + ((kc * 128 + nrow) << 3)] = o;
    }
}

// ---------------- CSR build via bucket counting sort ----------------

__global__ __launch_bounds__(256) void bucket_hist_kernel(const int* __restrict__ rows,
                                                          int* __restrict__ bhist, int E)
{
    __shared__ int h[512];
    int t = threadIdx.x;
    h[t] = 0; h[t + 256] = 0;
    __syncthreads();
    int base = blockIdx.x * 4096;
#pragma unroll
    for (int i = 0; i < 16; ++i) {
        int e = base + i * 256 + t;
        if (e < E) atomicAdd(&h[rows[e] >> BSH], 1);
    }
    __syncthreads();
    if (h[t]) atomicAdd(&bhist[t], h[t]);
    if (h[t + 256]) atomicAdd(&bhist[t + 256], h[t + 256]);
}

__global__ __launch_bounds__(256) void bucket_scan_kernel(const int* __restrict__ bhist,
                                                          int* __restrict__ boff, int* __restrict__ bcur,
                                                          int* __restrict__ row_ptr, int NB, int N, int E)
{
    __shared__ int h[512], sx[512], wt[4];
    int t = threadIdx.x;
    h[t] = bhist[t]; h[t + 256] = bhist[t + 256];
    __syncthreads();
    int v0 = h[2 * t], v1 = h[2 * t + 1];
    int s = v0 + v1, incl = s;
    for (int o = 1; o < 64; o <<= 1) { int u = __shfl_up(incl, o); if ((t & 63) >= o) incl += u; }
    if ((t & 63) == 63) wt[t >> 6] = incl;
    __syncthreads();
    int woff = 0, w = t >> 6;
    for (int i = 0; i < w; ++i) woff += wt[i];
    int excl = woff + incl - s;
    sx[2 * t] = excl; sx[2 * t + 1] = excl + v0;
    __syncthreads();
    if (t < NB)       { boff[t] = sx[t];       bcur[t] = sx[t]; }
    if (t + 256 < NB) { boff[t + 256] = sx[t + 256]; bcur[t + 256] = sx[t + 256]; }
    if (t == 0) { boff[NB] = E; row_ptr[N] = E; }
}

// counting-sort a 4096-edge chunk by bucket in LDS; flush contiguous runs.
// bcv.x packs col | (row&511)<<COLBITS
__global__ __launch_bounds__(256) void bucket_bin_kernel(
    const int* __restrict__ rows, const int* __restrict__ cols, const float* __restrict__ val,
    int* __restrict__ bcur, int2* __restrict__ bcv, int E)
{
    __shared__ int hist[512], sx[512], cnt[512], gbase[512], wt[4];
    __shared__ int mb[4096];
    __shared__ int2 mcv[4096];
    int t = threadIdx.x;
    hist[t] = 0; hist[t + 256] = 0; cnt[t] = 0; cnt[t + 256] = 0;
    __syncthreads();
    int base = blockIdx.x * 4096;
    int r[16];
#pragma unroll
    for (int i = 0; i < 16; ++i) {
        int e = base + i * 256 + t;
        r[i] = (e < E) ? rows[e] : -1;
        if (r[i] >= 0) atomicAdd(&hist[r[i] >> BSH], 1);
    }
    __syncthreads();
    int v0 = hist[2 * t], v1 = hist[2 * t + 1];
    int s = v0 + v1, incl = s;
    for (int o = 1; o < 64; o <<= 1) { int u = __shfl_up(incl, o); if ((t & 63) >= o) incl += u; }
    if ((t & 63) == 63) wt[t >> 6] = incl;
    __syncthreads();
    int woff = 0, w = t >> 6;
    for (int i = 0; i < w; ++i) woff += wt[i];
    int excl = woff + incl - s;
    sx[2 * t] = excl; sx[2 * t + 1] = excl + v0;
    __syncthreads();
    for (int bb = t; bb < 512; bb += 256)
        if (hist[bb]) gbase[bb] = atomicAdd(&bcur[bb], hist[bb]);
    __syncthreads();
#pragma unroll
    for (int i = 0; i < 16; ++i) {
        if (r[i] < 0) continue;
        int e = base + i * 256 + t;
        int bb = r[i] >> BSH;
        int p = atomicAdd(&cnt[bb], 1);
        int loc = sx[bb] + p;
        mb[loc] = bb;
        int2 cv;
        cv.x = cols[e] | ((r[i] & (BROWS - 1)) << COLBITS);
        cv.y = __float_as_int(val[e]);
        mcv[loc] = cv;
    }
    __syncthreads();
    int Mv = sx[511] + hist[511];
    for (int loc = t; loc < Mv; loc += 256) {
        int bb = mb[loc];
        int gidx = gbase[bb] + (loc - sx[bb]);
        bcv[gidx] = mcv[loc];
    }
}

// one block per bucket: row-hist -> row_ptr; place edges into exact CSR slots (col stripped)
__global__ __launch_bounds__(256) void bucket_place_kernel(
    const int2* __restrict__ bcv, const int* __restrict__ boff, int* __restrict__ row_ptr,
    int2* __restrict__ cpack, int N)
{
    __shared__ int rcnt[512], sx[512], wt[4];
    int b = blockIdx.x;
    int t = threadIdx.x;
    rcnt[t] = 0; rcnt[t + 256] = 0;
    __syncthreads();
    int rbase = b << BSH;
    int rn = min(BROWS, N - rbase);
    int lo = boff[b], hi = boff[b + 1];
    for (int p = lo + t; p < hi; p += 256)
        atomicAdd(&rcnt[((unsigned)bcv[p].x) >> COLBITS], 1);
    __syncthreads();
    int v0 = rcnt[2 * t], v1 = rcnt[2 * t + 1];
    int s = v0 + v1, incl = s;
    for (int o = 1; o < 64; o <<= 1) { int u = __shfl_up(incl, o); if ((t & 63) >= o) incl += u; }
    if ((t & 63) == 63) wt[t >> 6] = incl;
    __syncthreads();
    int woff = 0, w = t >> 6;
    for (int i = 0; i < w; ++i) woff += wt[i];
    int excl = woff + incl - s;
    sx[2 * t] = excl; sx[2 * t + 1] = excl + v0;
    __syncthreads();
    if (t < rn)       row_ptr[rbase + t] = lo + sx[t];
    if (t + 256 < rn) row_ptr[rbase + t + 256] = lo + sx[t + 256];
    __syncthreads();
    sx[t] += lo; sx[t + 256] += lo;
    __syncthreads();
    for (int p = lo + t; p < hi; p += 256) {
        int2 cv = bcv[p];
        int rin = ((unsigned)cv.x) >> COLBITS;
        int slot = atomicAdd(&sx[rin], 1);
        cv.x &= (1 << COLBITS) - 1;
        cpack[slot] = cv;
    }
}

// ---------------- MFMA GEMM: Y[M x Nout] = X[M x 128] @ W[Nout x 128]^T (+bias)(+elu) ----
// Wf is fragment-packed (see prep). X staged in LDS with XOR chunk swizzle:
// chunk (r, kc) at byte offset r*256 + ((kc ^ (r&15))<<4)  -> conflict-free reads & writes.
// grid: (ceil(M/128), Nout/128), block 256 (4 waves 2x2), 4 blocks/CU.

template<int IN_BF16, int OUT_BF16, int ACT>
__global__ __launch_bounds__(256, 4) void gemm_mfma(
    const void* __restrict__ Xv, const bf16* __restrict__ Wf,
    const float* __restrict__ bias, void* __restrict__ Yv, int M, int Nout)
{
    __shared__ bf16 Xs[128 * 128];
    const int tid = threadIdx.x;
    const int rb = blockIdx.x * 128;
    const int cb = blockIdx.y * 128;
    const bf16* Wfb = Wf + (size_t)cb * CCH;   // this col-block's 16384-elem fragment table

    if (IN_BF16) {
#pragma unroll
        for (int i = 0; i < 8; ++i) {
            int c = tid + i * 256;
            int r = c >> 4, kc = c & 15;
            int grow = rb + r;
            bf16x8 o = {};
            if (grow < M) o = *(const bf16x8*)&((const bf16*)Xv)[(size_t)grow * CCH + kc * 8];
            *(bf16x8*)&Xs[(r * 16 + (kc ^ (r & 15))) << 3] = o;
        }
    } else {
#pragma unroll
        for (int i = 0; i < 16; ++i) {
            int c = tid + i * 256;
            int r = c >> 5, sub = c & 31;
            int kc = sub >> 1, half = sub & 1;
            int grow = rb + r;
            bf16x4 o = {};
            if (grow < M) {
                float4 xv = *(const float4*)&((const float*)Xv)[(size_t)grow * CCH + kc * 8 + half * 4];
                o[0] = (bf16)xv.x; o[1] = (bf16)xv.y; o[2] = (bf16)xv.z; o[3] = (bf16)xv.w;
            }
            *(bf16x4*)&Xs[((r * 16 + (kc ^ (r & 15))) << 3) + half * 4] = o;
        }
    }
    __syncthreads();

    const int w = tid >> 6, lane = tid & 63;
    const int col16 = lane & 15, quad = lane >> 4;
    const int wm = (w & 1) * 64, wn = (w >> 1) * 64;

    f32x4 acc[4][4] = {};
#pragma unroll
    for (int kk = 0; kk < 4; ++kk) {
        const int kc = kk * 4 + quad;
        bf16x8 bfr[4], af[4];
#pragma unroll
        for (int ni = 0; ni < 4; ++ni)
            bfr[ni] = *(const bf16x8*)&Wfb[(size_t)((kc * 128 + wn + ni * 16 + col16) << 3)];
#pragma unroll
        for (int mi = 0; mi < 4; ++mi) {
            int r = wm + mi * 16 + col16;
            af[mi] = *(const bf16x8*)&Xs[(r * 16 + (kc ^ col16)) << 3];
        }
#pragma unroll
        for (int mi = 0; mi < 4; ++mi)
#pragma unroll
            for (int ni = 0; ni < 4; ++ni)
                acc[mi][ni] = __builtin_amdgcn_mfma_f32_16x16x32_bf16(af[mi], bfr[ni], acc[mi][ni], 0, 0, 0);
    }

#pragma unroll
    for (int mi = 0; mi < 4; ++mi) {
#pragma unroll
        for (int r = 0; r < 4; ++r) {
            int row = rb + wm + mi * 16 + quad * 4 + r;
            if (row >= M) continue;
#pragma unroll
            for (int ni = 0; ni < 4; ++ni) {
                int col = cb + wn + ni * 16 + col16;
                float vv = acc[mi][ni][r];
                if (bias) vv += bias[col];
                if (ACT == 1) vv = vv > 0.f ? vv : expm1f(vv);   // elu
                if (OUT_BF16) ((bf16*)Yv)[(size_t)row * Nout + col] = (bf16)vv;
                else          ((float*)Yv)[(size_t)row * Nout + col] = vv;
            }
        }
    }
}

// dual GEMM (Wih@X0 -> Y0, Whh@X1 -> Y1), fp32 in/out, Nout=G3, grid.y in [0,6)
__global__ __launch_bounds__(256, 4) void gemm_dual(
    const float* __restrict__ X0, const bf16* __restrict__ W0,
    const float* __restrict__ b0, float* __restrict__ Y0,
    const float* __restrict__ X1, const bf16* __restrict__ W1,
    const float* __restrict__ b1, float* __restrict__ Y1, int M)
{
    __shared__ bf16 Xs[128 * 128];
    const int tid = threadIdx.x;
    const int rb = blockIdx.x * 128;
    const int yy = blockIdx.y;
    const float* X; const bf16* W; const float* bias; float* Y; int cb;
    if (yy < 3) { X = X0; W = W0; bias = b0; Y = Y0; cb = yy * 128; }
    else        { X = X1; W = W1; bias = b1; Y = Y1; cb = (yy - 3) * 128; }
    const bf16* Wfb = W + (size_t)cb * CCH;

#pragma unroll
    for (int i = 0; i < 16; ++i) {
        int c = tid + i * 256;
        int r = c >> 5, sub = c & 31;
        int kc = sub >> 1, half = sub & 1;
        int grow = rb + r;
        bf16x4 o = {};
        if (grow < M) {
            float4 xv = *(const float4*)&X[(size_t)grow * CCH + kc * 8 + half * 4];
            o[0] = (bf16)xv.x; o[1] = (bf16)xv.y; o[2] = (bf16)xv.z; o[3] = (bf16)xv.w;
        }
        *(bf16x4*)&Xs[((r * 16 + (kc ^ (r & 15))) << 3) + half * 4] = o;
    }
    __syncthreads();

    const int w = tid >> 6, lane = tid & 63;
    const int col16 = lane & 15, quad = lane >> 4;
    const int wm = (w & 1) * 64, wn = (w >> 1) * 64;

    f32x4 acc[4][4] = {};
#pragma unroll
    for (int kk = 0; kk < 4; ++kk) {
        const int kc = kk * 4 + quad;
        bf16x8 bfr[4], af[4];
#pragma unroll
        for (int ni = 0; ni < 4; ++ni)
            bfr[ni] = *(const bf16x8*)&Wfb[(size_t)((kc * 128 + wn + ni * 16 + col16) << 3)];
#pragma unroll
        for (int mi = 0; mi < 4; ++mi) {
            int r = wm + mi * 16 + col16;
            af[mi] = *(const bf16x8*)&Xs[(r * 16 + (kc ^ col16)) << 3];
        }
#pragma unroll
        for (int mi = 0; mi < 4; ++mi)
#pragma unroll
            for (int ni = 0; ni < 4; ++ni)
                acc[mi][ni] = __builtin_amdgcn_mfma_f32_16x16x32_bf16(af[mi], bfr[ni], acc[mi][ni], 0, 0, 0);
    }

#pragma unroll
    for (int mi = 0; mi < 4; ++mi) {
#pragma unroll
        for (int r = 0; r < 4; ++r) {
            int row = rb + wm + mi * 16 + quad * 4 + r;
            if (row >= M) continue;
#pragma unroll
            for (int ni = 0; ni < 4; ++ni) {
                int col = cb + wn + ni * 16 + col16;
                Y[(size_t)row * G3 + col] = acc[mi][ni][r] + bias[col];
            }
        }
    }
}

// ---------------- SpMM (CSR gather): 16 lanes/row x bf16x8, 4-edge unroll ----------------
template<int SCORES>
__global__ __launch_bounds__(256) void spmm_csr_kernel(
    const int* __restrict__ row_ptr, const int2* __restrict__ cpack,
    const bf16* __restrict__ Xin, bf16* __restrict__ Y,
    const float* __restrict__ bvec, const float* __restrict__ sc, const float* __restrict__ sh,
    const float* __restrict__ vsp, const float* __restrict__ c0p, float* __restrict__ scores,
    int Nrow)
{
    int gid = blockIdx.x * 256 + threadIdx.x;
    int row = gid >> 4;
    if (row >= Nrow) return;
    int l8 = (gid & 15) << 3;
    int st = row_ptr[row], en = row_ptr[row + 1];
    float acc[8] = {};
    int j = st;
    for (; j + 4 <= en; j += 4) {
        int2 p0 = cpack[j], p1 = cpack[j + 1], p2 = cpack[j + 2], p3 = cpack[j + 3];
        bf16x8 x0 = *(const bf16x8*)&Xin[(size_t)p0.x * CCH + l8];
        bf16x8 x1 = *(const bf16x8*)&Xin[(size_t)p1.x * CCH + l8];
        bf16x8 x2 = *(const bf16x8*)&Xin[(size_t)p2.x * CCH + l8];
        bf16x8 x3 = *(const bf16x8*)&Xin[(size_t)p3.x * CCH + l8];
        float v0 = __int_as_float(p0.y), v1 = __int_as_float(p1.y);
        float v2 = __int_as_float(p2.y), v3 = __int_as_float(p3.y);
#pragma unroll
        for (int q = 0; q < 8; ++q)
            acc[q] += v0 * (float)x0[q] + v1 * (float)x1[q] + v2 * (float)x2[q] + v3 * (float)x3[q];
    }
    if (j + 2 <= en) {
        int2 p0 = cpack[j], p1 = cpack[j + 1];
        bf16x8 x0 = *(const bf16x8*)&Xin[(size_t)p0.x * CCH + l8];
        bf16x8 x1 = *(const bf16x8*)&Xin[(size_t)p1.x * CCH + l8];
        float v0 = __int_as_float(p0.y), v1 = __int_as_float(p1.y);
#pragma unroll
        for (int q = 0; q < 8; ++q) acc[q] += v0 * (float)x0[q] + v1 * (float)x1[q];
        j += 2;
    }
    if (j < en) {
        int2 p0 = cpack[j];
        bf16x8 x0 = *(const bf16x8*)&Xin[(size_t)p0.x * CCH + l8];
        float v0 = __int_as_float(p0.y);
#pragma unroll
        for (int q = 0; q < 8; ++q) acc[q] += v0 * (float)x0[q];
    }
    float o[8];
    bf16x8 ov;
#pragma unroll
    for (int q = 0; q < 8; ++q) {
        o[q] = fmaxf((acc[q] + bvec[l8 + q]) * sc[l8 + q] + sh[l8 + q], 0.f);
        ov[q] = (bf16)o[q];
    }
    *(bf16x8*)&Y[(size_t)row * CCH + l8] = ov;
    if (SCORES) {
        float p = 0.f;
#pragma unroll
        for (int q = 0; q < 8; ++q) p += o[q] * vsp[l8 + q];
        for (int d = 8; d; d >>= 1) p += __shfl_down(p, d, 16);
        if ((gid & 15) == 0) scores[row] = p + c0p[0];
    }
}

// ---------------- fused pool + attention pool (per segment) ----------------
__global__ __launch_bounds__(128) void segstage_kernel(
    const bf16* __restrict__ X, const float* __restrict__ sarr, const int* __restrict__ starts,
    const float* __restrict__ sc2, const float* __restrict__ sh2,
    const float* __restrict__ sc3, const float* __restrict__ sh3,
    const float* __restrict__ vd, float* __restrict__ mean, float* __restrict__ upool)
{
    __shared__ float red[2];
    __shared__ float adsh;
    int t = blockIdx.x;
    int c = threadIdx.x;
    int st = starts[t], en = starts[t + 1];
    float sum = 0.f;
    for (int i = st; i < en; ++i) sum += (float)X[(size_t)i * CCH + c];
    float cnt = (float)(en - st);
    float poolb = fmaxf(sum * sc2[c] + cnt * sh2[c], 0.f);
    float mv = poolb * sc3[c] + sh3[c];
    mean[(size_t)t * CCH + c] = mv;
    float p = mv * vd[c];
    for (int o = 32; o; o >>= 1) p += __shfl_down(p, o);
    if ((c & 63) == 0) red[c >> 6] = p;
    __syncthreads();
    if (c == 0) adsh = red[0] + red[1];
    __syncthreads();
    if (en == st) { upool[(size_t)t * CCH + c] = 0.f; return; }
    float adt = adsh;
    float lm = -3.0e38f;
    for (int i = st + c; i < en; i += 128) {
        float a = sarr[i] + adt;
        a = a > 0.f ? a : 0.01f * a;
        lm = fmaxf(lm, a);
    }
    for (int o = 32; o; o >>= 1) lm = fmaxf(lm, __shfl_down(lm, o));
    if ((c & 63) == 0) red[c >> 6] = lm;
    __syncthreads();
    float m = fmaxf(red[0], red[1]);
    float u = 0.f, den = 0.f;
    for (int i = st; i < en; ++i) {
        float a = sarr[i] + adt;
        a = a > 0.f ? a : 0.01f * a;
        float e = __expf(a - m);
        den += e;
        u += e * (float)X[(size_t)i * CCH + c];
    }
    upool[(size_t)t * CCH + c] = (u / den) * sc2[c] + sh2[c];
}

// GRU combine + relu + bn(base+2); bf16 out + fused next-stage scores (tt stage)
__global__ __launch_bounds__(256) void gru_kernel(
    const float* __restrict__ giM, const float* __restrict__ ghM, const float* __restrict__ mean,
    const float* __restrict__ sc4, const float* __restrict__ sh4,
    bf16* __restrict__ out,
    const float* __restrict__ vsp2, const float* __restrict__ c02, float* __restrict__ scores,
    int total)
{
    __shared__ float sred[4];
    int idx = blockIdx.x * 256 + threadIdx.x;
    bool ok = idx < total;
    int t = idx >> 7, c = idx & 127;
    float o = 0.f;
    if (ok) {
        size_t b = (size_t)t * G3;
        float ir = giM[b + c],  iz = giM[b + 128 + c], inn = giM[b + 256 + c];
        float hr = ghM[b + c],  hz = ghM[b + 128 + c], hn  = ghM[b + 256 + c];
        float r = 1.f / (1.f + __expf(-(ir + hr)));
        float z = 1.f / (1.f + __expf(-(iz + hz)));
        float nn = tanhf(inn + r * hn);
        float h = (1.f - z) * nn + z * mean[idx];
        h = fmaxf(h, 0.f);
        o = h * sc4[c] + sh4[c];
        out[idx] = (bf16)o;
    }
    float p = ok ? o * vsp2[c] : 0.f;
    for (int d = 32; d; d >>= 1) p += __shfl_down(p, d);
    int w = threadIdx.x >> 6;
    if ((threadIdx.x & 63) == 0) sred[w] = p;
    __syncthreads();
    if (threadIdx.x == 0 && ok)   scores[t] = sred[0] + sred[1] + c02[0];
    if (threadIdx.x == 128 && ok) scores[t] = sred[2] + sred[3] + c02[0];
}

// mol-stage GRU + predictor fused: 2 segments per block, no mol materialization
__global__ __launch_bounds__(256) void gru_pred_kernel(
    const float* __restrict__ giM, const float* __restrict__ ghM, const float* __restrict__ mean,
    const float* __restrict__ sc4, const float* __restrict__ sh4,
    const float* __restrict__ pW1, const float* __restrict__ pb1,
    const float* __restrict__ pW2, const float* __restrict__ pb2,
    float* __restrict__ out, int nseg)
{
    __shared__ float row[2][CCH];
    int half = threadIdx.x >> 7;
    int c = threadIdx.x & 127;
    int t = blockIdx.x * 2 + half;
    bool ok = t < nseg;
    float o = 0.f;
    if (ok) {
        size_t b = (size_t)t * G3;
        float ir = giM[b + c],  iz = giM[b + 128 + c], inn = giM[b + 256 + c];
        float hr = ghM[b + c],  hz = ghM[b + 128 + c], hn  = ghM[b + 256 + c];
        float r = 1.f / (1.f + __expf(-(ir + hr)));
        float z = 1.f / (1.f + __expf(-(iz + hz)));
        float nn = tanhf(inn + r * hn);
        float h = (1.f - z) * nn + z * mean[(size_t)t * CCH + c];
        h = fmaxf(h, 0.f);
        o = h * sc4[c] + sh4[c];
    }
    row[half][c] = o;
    __syncthreads();
    if (c < 64 && ok) {
        float h = pb1[c];
#pragma unroll
        for (int k = 0; k < CCH; ++k) h += row[half][k] * pW1[c * CCH + k];
        h = fmaxf(h, 0.f);
        float p = h * pW2[c];
        for (int d = 32; d; d >>= 1) p += __shfl_down(p, d);
        if (c == 0) out[t] = p + pb2[0];
    }
}

// ---------------- host ----------------

extern "C" void kernel_launch(void* const* d_in, const int* in_sizes, int n_in,
                              void* d_out, int out_size, void* d_ws, size_t ws_size,
                              hipStream_t stream)
{
    (void)n_in; (void)ws_size;
    const float* node_attr      = (const float*)d_in[0];
    const int*   adj_index      = (const int*)  d_in[1];
    const float* adj_value      = (const float*)d_in[2];
    const int*   tt_node_batch  = (const int*)  d_in[3];
    const int*   tt_graph_batch = (const int*)  d_in[4];
    const float* W_gcn    = (const float*)d_in[5];
    const float* b_gcn    = (const float*)d_in[6];
    const float* bn_gamma = (const float*)d_in[7];
    const float* bn_beta  = (const float*)d_in[8];
    const float* bn_mean  = (const float*)d_in[9];
    const float* bn_var   = (const float*)d_in[10];
    const float* gat_Wsrc = (const float*)d_in[11];
    const float* gat_Wdst = (const float*)d_in[12];
    const float* gat_asrc = (const float*)d_in[13];
    const float* gat_adst = (const float*)d_in[14];
    const float* gat_bias = (const float*)d_in[15];
    const float* gru_Wih  = (const float*)d_in[16];
    const float* gru_Whh  = (const float*)d_in[17];
    const float* gru_bih  = (const float*)d_in[18];
    const float* gru_bhh  = (const float*)d_in[19];
    const float* pW1 = (const float*)d_in[20];
    const float* pb1 = (const float*)d_in[21];
    const float* pW2 = (const float*)d_in[22];
    const float* pb2 = (const float*)d_in[23];

    const int E    = in_sizes[2];
    const int N    = in_sizes[3];
    const int NTT  = in_sizes[4];
    const int NMOL = out_size;
    const int NB   = (N + BROWS - 1) >> BSH;

    const int* adj_rows = adj_index;
    const int* adj_cols = adj_index + E;

    // ---- workspace carve ----
    char* wsb = (char*)d_ws;
    size_t off = 0;
    auto carve = [&](size_t bytes) -> char* {
        char* p = wsb + off;
        off = (off + bytes + 255) & ~(size_t)255;
        return p;
    };
    bf16* bufB = (bf16*)carve((size_t)N * CCH * 2);
    bf16* bufA = (bf16*)carve((size_t)N * CCH * 2);
    bf16* tt   = (bf16*)carve((size_t)NTT * CCH * 2);
    float* mean  = (float*)carve((size_t)NTT * CCH * 4);
    float* upool = (float*)carve((size_t)NTT * CCH * 4);
    float* gbuf  = (float*)carve((size_t)NTT * CCH * 4);
    float* giM   = (float*)carve((size_t)NTT * G3 * 4);
    float* ghM   = (float*)carve((size_t)NTT * G3 * 4);
    float* scores = (float*)carve((size_t)N * 4);
    int* starts_tt  = (int*)carve((size_t)(NTT + 1) * 4);
    int* starts_mol = (int*)carve((size_t)(NMOL + 1) * 4);
    float* bnsc = (float*)carve(8 * CCH * 4);
    float* bnsh = (float*)carve(8 * CCH * 4);
    float* vsp  = (float*)carve(2 * CCH * 4);
    float* vd   = (float*)carve(2 * CCH * 4);
    float* c0   = (float*)carve(2 * 4);
    bf16* Wgcnb = (bf16*)carve((size_t)2 * CCH * CCH * 2);
    bf16* Wsrcb = (bf16*)carve((size_t)2 * CCH * CCH * 2);
    bf16* Wihb  = (bf16*)carve((size_t)2 * G3 * CCH * 2);
    bf16* Whhb  = (bf16*)carve((size_t)2 * G3 * CCH * 2);
    int*   bhist   = (int*)carve(512 * 4);
    int*   boff    = (int*)carve((size_t)(NB + 1) * 4);
    int*   bcur    = (int*)carve((size_t)NB * 4);
    int*   row_ptr = (int*)carve((size_t)(N + 1) * 4);
    int2*  bcv     = (int2*)carve((size_t)E * 8);
    int2*  cpack   = (int2*)carve((size_t)E * 8);

    // ---- fused prep (bn fold + gat matvec + bounds + zero bhist + W fragment repack) ----
    const int B1 = 4;
    const int B2 = B1 + 2;
    const int B3 = B2 + (NTT + 1 + 255) / 256;
    const int B4 = B3 + (NMOL + 1 + 255) / 256;
    const int B5 = B4 + 1;
    const int B6 = B5 + 16;   // Wgcn: 256 rows * 16 chunks / 256 thr
    const int B7 = B6 + 16;   // Wsrc
    const int B8 = B7 + 48;   // Wih: 768 rows
    const int B9 = B8 + 48;   // Whh
    prep_kernel<<<B9, 256, 0, stream>>>(
        bn_gamma, bn_beta, bn_mean, bn_var, bnsc, bnsh,
        gat_Wsrc, gat_Wdst, gat_asrc, gat_adst, vsp, vd, c0,
        tt_node_batch, N, NTT, starts_tt,
        tt_graph_batch, NMOL, starts_mol,
        bhist,
        W_gcn, Wgcnb, Wsrcb, gru_Wih, Wihb, gru_Whh, Whhb,
        B1, B2, B3, B4, B5, B6, B7, B8);

    // ---- CSR build via bucket counting sort ----
    const int nchunk = (E + 4095) / 4096;
    bucket_hist_kernel<<<nchunk, 256, 0, stream>>>(adj_rows, bhist, E);
    bucket_scan_kernel<<<1, 256, 0, stream>>>(bhist, boff, bcur, row_ptr, NB, N, E);
    bucket_bin_kernel<<<nchunk, 256, 0, stream>>>(adj_rows, adj_cols, adj_value, bcur, bcv, E);
    bucket_place_kernel<<<NB, 256, 0, stream>>>(bcv, boff, row_ptr, cpack, N);

    // ---- GCN x2 ----
    dim3 gg((N + 127) / 128, 1);
    const int spmm_blocks = ((size_t)N * 16 + 255) / 256;
    gemm_mfma<0, 1, 0><<<gg, 256, 0, stream>>>(node_attr, Wgcnb, nullptr, bufB, N, CCH);
    spmm_csr_kernel<0><<<spmm_blocks, 256, 0, stream>>>(
        row_ptr, cpack, bufB, bufA, b_gcn, bnsc, bnsh, nullptr, nullptr, nullptr, N);
    gemm_mfma<1, 1, 0><<<gg, 256, 0, stream>>>(bufA, Wgcnb + CCH * CCH, nullptr, bufB, N, CCH);
    spmm_csr_kernel<1><<<spmm_blocks, 256, 0, stream>>>(
        row_ptr, cpack, bufB, bufA, b_gcn + CCH, bnsc + CCH, bnsh + CCH,
        vsp, c0, scores, N);

    // ---- tt stage: N -> NTT (bf16 out + fused mol-stage scores) ----
    {
        const int bnb = 2, gi = 0, nseg = NTT;
        segstage_kernel<<<nseg, 128, 0, stream>>>(bufA, scores, starts_tt,
            bnsc + bnb * CCH, bnsh + bnb * CCH, bnsc + (bnb + 1) * CCH, bnsh + (bnb + 1) * CCH,
            vd + gi * CCH, mean, upool);
        dim3 g1((nseg + 127) / 128, 1);
        gemm_mfma<0, 0, 1><<<g1, 256, 0, stream>>>(upool, Wsrcb + gi * CCH * CCH,
                                                   gat_bias + gi * CCH, gbuf, nseg, CCH);
        dim3 g2((nseg + 127) / 128, 6);
        gemm_dual<<<g2, 256, 0, stream>>>(gbuf, Wihb + gi * G3 * CCH, gru_bih + gi * G3, giM,
                                          mean, Whhb + gi * G3 * CCH, gru_bhh + gi * G3, ghM, nseg);
        gru_kernel<<<(nseg * CCH + 255) / 256, 256, 0, stream>>>(giM, ghM, mean,
            bnsc + (bnb + 2) * CCH, bnsh + (bnb + 2) * CCH, tt,
            vsp + CCH, c0 + 1, scores, nseg * CCH);
    }

    // ---- mol stage: NTT -> NMOL (GRU+predictor fused) ----
    {
        const int bnb = 5, gi = 1, nseg = NMOL;
        segstage_kernel<<<nseg, 128, 0, stream>>>(tt, scores, starts_mol,
            bnsc + bnb * CCH, bnsh + bnb * CCH, bnsc + (bnb + 1) * CCH, bnsh + (bnb + 1) * CCH,
            vd + gi * CCH, mean, upool);
        dim3 g1((nseg + 127) / 128, 1);
        gemm_mfma<0, 0, 1><<<g1, 256, 0, stream>>>(upool, Wsrcb + gi * CCH * CCH,
                                                   gat_bias + gi * CCH, gbuf, nseg, CCH);
        dim3 g2((nseg + 127) / 128, 6);
        gemm_dual<<<g2, 256, 0, stream>>>(gbuf, Wihb + gi * G3 * CCH, gru_bih + gi * G3, giM,
                                          mean, Whhb + gi * G3 * CCH, gru_bhh + gi * G3, ghM, nseg);
        gru_pred_kernel<<<(nseg + 1) / 2, 256, 0, stream>>>(giM, ghM, mean,
            bnsc + (bnb + 2) * CCH, bnsh + (bnb + 2) * CCH,
            pW1, pb1, pW2, pb2, (float*)d_out, nseg);
    }
}